// Round 3
// baseline (3097.606 us; speedup 1.0000x reference)
//
#include <hip/hip_runtime.h>
#include <hip/hip_bf16.h>

#define N_NODES 8192
#define N_EDGES 65536
#define OUT0_ELEMS ((size_t)N_NODES * 1024)

using bf16 = __hip_bfloat16;

__device__ __forceinline__ float b2f(bf16 x) { return __bfloat162float(x); }
__device__ __forceinline__ bf16 f2b(float x) { return __float2bfloat16(x); }

// dual-dtype load: flag=1 -> buffer holds bf16, flag=0 -> float32
__device__ __forceinline__ float ldf(const void* p, size_t i, int bf)
{
  if (bf) {
    unsigned short u = ((const unsigned short*)p)[i];
    unsigned int x = ((unsigned int)u) << 16;
    float f; __builtin_memcpy(&f, &x, 4); return f;
  }
  return ((const float*)p)[i];
}
// dual-dtype store into the (flat) output buffer
__device__ __forceinline__ void stf(void* p, size_t i, float v, int bf)
{
  if (bf) {
    bf16 t = __float2bfloat16(v);
    unsigned short u; __builtin_memcpy(&u, &t, 2);
    ((unsigned short*)p)[i] = u;
  } else {
    ((float*)p)[i] = v;
  }
}

// Kept so any harness-side reference to the stub symbol still resolves.
__global__ void GNN_27650999451833_kernel() {}

//---------------------------------------------------------------------
// dtype probe: low 16 bits of each u32 word of N(0,1) data.
// bf16-packed -> exponent field clusters near bias; f32 -> uniform mantissa.
//---------------------------------------------------------------------
__global__ void gnn3_detect(const unsigned int* __restrict__ w, int* __restrict__ flag)
{
  __shared__ int cnt;
  if (threadIdx.x == 0) cnt = 0;
  __syncthreads();
  int hits = 0;
  for (int i = threadIdx.x; i < 512; i += 256) {
    unsigned lo = w[i] & 0xFFFFu;
    unsigned ex = (lo >> 7) & 0xFFu;      // bf16 exponent of low half
    if (ex >= 115 && ex <= 130) hits++;   // |v| roughly in [2^-12, 2^4]
  }
  atomicAdd(&cnt, hits);
  __syncthreads();
  if (threadIdx.x == 0) *flag = (cnt >= 256) ? 1 : 0;
}

__global__ void gnn3_zero(int* __restrict__ p, int n)
{
  int i = blockIdx.x * blockDim.x + threadIdx.x;
  if (i < n) p[i] = 0;
}

//---------------------------------------------------------------------
// GEMM 1: P[8192,2048](bf16) = n_f[8192,1024] @ [We[0:1024] | We[1040:2064]]
//---------------------------------------------------------------------
__global__ __launch_bounds__(256)
void gnn3_gemm_P(const void* __restrict__ n_f, const void* __restrict__ We,
                 bf16* __restrict__ P, const int* __restrict__ dflag)
{
  const int bf = *dflag;
  __shared__ float As[16][68];
  __shared__ float Bs[16][68];
  const int tid = threadIdx.x;
  const int tx = tid & 15, ty = tid >> 4;
  const int row0 = blockIdx.y * 64, col0 = blockIdx.x * 64;

  float acc[4][4];
#pragma unroll
  for (int i = 0; i < 4; ++i)
#pragma unroll
    for (int j = 0; j < 4; ++j) acc[i][j] = 0.f;

  for (int k0 = 0; k0 < 1024; k0 += 16) {
    for (int l = tid; l < 1024; l += 256) {
      int r = l >> 4, kk = l & 15;
      As[kk][r] = ldf(n_f, (size_t)(row0 + r) * 1024 + (k0 + kk), bf);
    }
    for (int l = tid; l < 1024; l += 256) {
      int c = l & 63, kk = l >> 6;
      int gc = col0 + c, gk = k0 + kk;
      float v;
      if (gc < 1024) v = ldf(We, (size_t)gk * 1024 + gc, bf);
      else           v = ldf(We, (size_t)(1040 + gk) * 1024 + (gc - 1024), bf);
      Bs[kk][c] = v;
    }
    __syncthreads();
#pragma unroll
    for (int kk = 0; kk < 16; ++kk) {
      float av[4], bv[4];
#pragma unroll
      for (int i = 0; i < 4; ++i) av[i] = As[kk][ty * 4 + i];
#pragma unroll
      for (int j = 0; j < 4; ++j) bv[j] = Bs[kk][tx * 4 + j];
#pragma unroll
      for (int i = 0; i < 4; ++i)
#pragma unroll
        for (int j = 0; j < 4; ++j) acc[i][j] = fmaf(av[i], bv[j], acc[i][j]);
    }
    __syncthreads();
  }
#pragma unroll
  for (int i = 0; i < 4; ++i) {
    int r = row0 + ty * 4 + i;
#pragma unroll
    for (int j = 0; j < 4; ++j) {
      int c = col0 + tx * 4 + j;
      P[(size_t)r * 2048 + c] = f2b(acc[i][j]);
    }
  }
}

//---------------------------------------------------------------------
// GEMM 2: Q[8192,1200](bf16) = w2v[8192,300] @ [Wel[0:300] | Wel[300:600]]
//---------------------------------------------------------------------
__global__ __launch_bounds__(256)
void gnn3_gemm_Q(const void* __restrict__ w2v, const void* __restrict__ Wel,
                 bf16* __restrict__ Q, const int* __restrict__ dflag)
{
  const int bf = *dflag;
  __shared__ float As[16][68];
  __shared__ float Bs[16][68];
  const int tid = threadIdx.x;
  const int tx = tid & 15, ty = tid >> 4;
  const int row0 = blockIdx.y * 64, col0 = blockIdx.x * 64;
  const int K = 300, N = 1200;

  float acc[4][4];
#pragma unroll
  for (int i = 0; i < 4; ++i)
#pragma unroll
    for (int j = 0; j < 4; ++j) acc[i][j] = 0.f;

  for (int k0 = 0; k0 < K; k0 += 16) {
    for (int l = tid; l < 1024; l += 256) {
      int r = l >> 4, kk = l & 15;
      int gk = k0 + kk;
      As[kk][r] = (gk < K) ? ldf(w2v, (size_t)(row0 + r) * 300 + gk, bf) : 0.f;
    }
    for (int l = tid; l < 1024; l += 256) {
      int c = l & 63, kk = l >> 6;
      int gc = col0 + c, gk = k0 + kk;
      float v = 0.f;
      if (gk < K && gc < N) {
        if (gc < 600) v = ldf(Wel, (size_t)gk * 600 + gc, bf);
        else          v = ldf(Wel, (size_t)(300 + gk) * 600 + (gc - 600), bf);
      }
      Bs[kk][c] = v;
    }
    __syncthreads();
#pragma unroll
    for (int kk = 0; kk < 16; ++kk) {
      float av[4], bv[4];
#pragma unroll
      for (int i = 0; i < 4; ++i) av[i] = As[kk][ty * 4 + i];
#pragma unroll
      for (int j = 0; j < 4; ++j) bv[j] = Bs[kk][tx * 4 + j];
#pragma unroll
      for (int i = 0; i < 4; ++i)
#pragma unroll
        for (int j = 0; j < 4; ++j) acc[i][j] = fmaf(av[i], bv[j], acc[i][j]);
    }
    __syncthreads();
  }
#pragma unroll
  for (int i = 0; i < 4; ++i) {
    int r = row0 + ty * 4 + i;
#pragma unroll
    for (int j = 0; j < 4; ++j) {
      int c = col0 + tx * 4 + j;
      if (c < N) Q[(size_t)r * 1200 + c] = f2b(acc[i][j]);
    }
  }
}

//---------------------------------------------------------------------
// Edge scores. One 64-lane wave per edge, 4 edges per block.
//---------------------------------------------------------------------
__global__ __launch_bounds__(256)
void gnn3_edge_score(const int* __restrict__ src, const int* __restrict__ dst,
                     const void* __restrict__ s_f, const void* __restrict__ We,
                     const void* __restrict__ be, const void* __restrict__ Wa,
                     const void* __restrict__ ba, const void* __restrict__ bel,
                     const void* __restrict__ Wal, const void* __restrict__ bal,
                     const bf16* __restrict__ P, const bf16* __restrict__ Q,
                     float* __restrict__ af, float* __restrict__ afl,
                     const int* __restrict__ dflag)
{
  const int bf = *dflag;
  const int e = blockIdx.x * 4 + (threadIdx.x >> 6);
  const int lane = threadIdx.x & 63;
  if (e >= N_EDGES) return;
  const int s = src[e], d = dst[e];

  float sfv[16];
#pragma unroll
  for (int k = 0; k < 16; ++k) sfv[k] = ldf(s_f, (size_t)e * 16 + k, bf);

  const bf16* P1 = P + (size_t)s * 2048;
  const bf16* P2 = P + (size_t)d * 2048 + 1024;
  float acc = 0.f;
  for (int c = lane; c < 1024; c += 64) {
    float v = b2f(P1[c]) + b2f(P2[c]) + ldf(be, c, bf);
#pragma unroll
    for (int k = 0; k < 16; ++k)
      v = fmaf(sfv[k], ldf(We, (size_t)(1024 + k) * 1024 + c, bf), v);
    v = fmaxf(v, 0.f);
    acc = fmaf(v, ldf(Wa, c, bf), acc);
  }
#pragma unroll
  for (int o = 32; o > 0; o >>= 1) acc += __shfl_down(acc, o, 64);
  if (lane == 0) af[e] = acc + ldf(ba, 0, bf);

  const bf16* Q1 = Q + (size_t)s * 1200;
  const bf16* Q2 = Q + (size_t)d * 1200 + 600;
  float accl = 0.f;
  for (int c = lane; c < 600; c += 64) {
    float v = b2f(Q1[c]) + b2f(Q2[c]) + ldf(bel, c, bf);
    v = fmaxf(v, 0.f);
    accl = fmaf(v, ldf(Wal, c, bf), accl);
  }
#pragma unroll
  for (int o = 32; o > 0; o >>= 1) accl += __shfl_down(accl, o, 64);
  if (lane == 0) afl[e] = accl + ldf(bal, 0, bf);
}

//---------------------------------------------------------------------
// CSR build
//---------------------------------------------------------------------
__global__ void gnn3_count(const int* __restrict__ dst, int* __restrict__ cnt)
{
  int e = blockIdx.x * blockDim.x + threadIdx.x;
  if (e < N_EDGES) atomicAdd(&cnt[dst[e]], 1);
}

__global__ __launch_bounds__(1024)
void gnn3_scan(const int* __restrict__ cnt, int* __restrict__ off, int* __restrict__ cur)
{
  __shared__ int sh[1024];
  const int t = threadIdx.x;
  int local[8]; int sum = 0;
#pragma unroll
  for (int i = 0; i < 8; ++i) { int v = cnt[t * 8 + i]; local[i] = sum; sum += v; }
  sh[t] = sum;
  __syncthreads();
  for (int d = 1; d < 1024; d <<= 1) {
    int v = (t >= d) ? sh[t - d] : 0;
    __syncthreads();
    sh[t] += v;
    __syncthreads();
  }
  int basev = (t > 0) ? sh[t - 1] : 0;
#pragma unroll
  for (int i = 0; i < 8; ++i) { int o = basev + local[i]; off[t * 8 + i] = o; cur[t * 8 + i] = o; }
  if (t == 1023) off[8192] = sh[1023];
}

__global__ void gnn3_fill(const int* __restrict__ dst, int* __restrict__ cur,
                          int* __restrict__ elist)
{
  int e = blockIdx.x * blockDim.x + threadIdx.x;
  if (e < N_EDGES) { int p = atomicAdd(&cur[dst[e]], 1); elist[p] = e; }
}

//---------------------------------------------------------------------
// Per-node softmax + weighted accumulate. One block per node, no atomics.
//---------------------------------------------------------------------
__global__ __launch_bounds__(256)
void gnn3_node_z(const int* __restrict__ off, const int* __restrict__ elist,
                 const int* __restrict__ src, const float* __restrict__ af,
                 const float* __restrict__ afl, const void* __restrict__ n_f,
                 const void* __restrict__ w2v, const void* __restrict__ s_f,
                 const void* __restrict__ We, const void* __restrict__ be,
                 const bf16* __restrict__ P, bf16* __restrict__ zf,
                 bf16* __restrict__ zfl, const int* __restrict__ dflag)
{
  const int bf = *dflag;
  const int node = blockIdx.x;
  const int t = threadIdx.x;
  const int base = off[node];
  const int deg = off[node + 1] - base;

  float m = -1e30f, ml = -1e30f;
  for (int i = 0; i < deg; ++i) {
    int e = elist[base + i];
    m = fmaxf(m, af[e]);
    ml = fmaxf(ml, afl[e]);
  }
  float den = 0.f, denl = 0.f;
  for (int i = 0; i < deg; ++i) {
    int e = elist[base + i];
    den += expf(af[e] - m);
    denl += expf(afl[e] - ml);
  }

  float p2[4];
#pragma unroll
  for (int j = 0; j < 4; ++j) {
    int c = t + 256 * j;
    p2[j] = b2f(P[(size_t)node * 2048 + 1024 + c]) + ldf(be, c, bf);
  }
  float acc[4] = {0.f, 0.f, 0.f, 0.f};
  float accl0 = 0.f, accl1 = 0.f;
  const int cl0 = t, cl1 = t + 256;

  for (int i = 0; i < deg; ++i) {
    int e = elist[base + i];
    int s = src[e];
    float w = expf(af[e] - m) / den;
    float wl = expf(afl[e] - ml) / denl;
    float sfv[16];
#pragma unroll
    for (int k = 0; k < 16; ++k) sfv[k] = ldf(s_f, (size_t)e * 16 + k, bf);
    const bf16* P1 = P + (size_t)s * 2048;
#pragma unroll
    for (int j = 0; j < 4; ++j) {
      int c = t + 256 * j;
      float ef = b2f(P1[c]) + p2[j];
#pragma unroll
      for (int k = 0; k < 16; ++k)
        ef = fmaf(sfv[k], ldf(We, (size_t)(1024 + k) * 1024 + c, bf), ef);
      ef = fmaxf(ef, 0.f);
      acc[j] += w * (ldf(n_f, (size_t)s * 1024 + c, bf) + ef);
    }
    if (cl0 < 300) accl0 += wl * ldf(w2v, (size_t)s * 300 + cl0, bf);
    if (cl1 < 300) accl1 += wl * ldf(w2v, (size_t)s * 300 + cl1, bf);
  }
#pragma unroll
  for (int j = 0; j < 4; ++j) zf[(size_t)node * 1024 + t + 256 * j] = f2b(acc[j]);
  if (cl0 < 300) zfl[(size_t)node * 300 + cl0] = f2b(accl0);
  if (cl1 < 300) zfl[(size_t)node * 300 + cl1] = f2b(accl1);
}

//---------------------------------------------------------------------
// GEMM 3: out0 = relu([n_f | zf] @ Wn + bn)    (K=2048, N=1024)
//---------------------------------------------------------------------
__global__ __launch_bounds__(256)
void gnn3_gemm_out_n(const void* __restrict__ n_f, const bf16* __restrict__ zf,
                     const void* __restrict__ Wn, const void* __restrict__ bn,
                     void* __restrict__ out, const int* __restrict__ dflag)
{
  const int bf = *dflag;
  __shared__ float As[16][68];
  __shared__ float Bs[16][68];
  const int tid = threadIdx.x;
  const int tx = tid & 15, ty = tid >> 4;
  const int row0 = blockIdx.y * 64, col0 = blockIdx.x * 64;

  float acc[4][4];
#pragma unroll
  for (int i = 0; i < 4; ++i)
#pragma unroll
    for (int j = 0; j < 4; ++j) acc[i][j] = 0.f;

  for (int k0 = 0; k0 < 2048; k0 += 16) {
    for (int l = tid; l < 1024; l += 256) {
      int r = l >> 4, kk = l & 15;
      int gr = row0 + r, gk = k0 + kk;
      float v;
      if (gk < 1024) v = ldf(n_f, (size_t)gr * 1024 + gk, bf);
      else           v = b2f(zf[(size_t)gr * 1024 + (gk - 1024)]);
      As[kk][r] = v;
    }
    for (int l = tid; l < 1024; l += 256) {
      int c = l & 63, kk = l >> 6;
      Bs[kk][c] = ldf(Wn, (size_t)(k0 + kk) * 1024 + (col0 + c), bf);
    }
    __syncthreads();
#pragma unroll
    for (int kk = 0; kk < 16; ++kk) {
      float av[4], bv[4];
#pragma unroll
      for (int i = 0; i < 4; ++i) av[i] = As[kk][ty * 4 + i];
#pragma unroll
      for (int j = 0; j < 4; ++j) bv[j] = Bs[kk][tx * 4 + j];
#pragma unroll
      for (int i = 0; i < 4; ++i)
#pragma unroll
        for (int j = 0; j < 4; ++j) acc[i][j] = fmaf(av[i], bv[j], acc[i][j]);
    }
    __syncthreads();
  }
#pragma unroll
  for (int i = 0; i < 4; ++i) {
    int r = row0 + ty * 4 + i;
#pragma unroll
    for (int j = 0; j < 4; ++j) {
      int c = col0 + tx * 4 + j;
      float v = acc[i][j] + ldf(bn, c, bf);
      stf(out, (size_t)r * 1024 + c, fmaxf(v, 0.f), bf);
    }
  }
}

//---------------------------------------------------------------------
// GEMM 4: out1 = relu([w2v | zfl] @ Wnl + bnl)  (K=600, N=300)
//---------------------------------------------------------------------
__global__ __launch_bounds__(256)
void gnn3_gemm_out_l(const void* __restrict__ w2v, const bf16* __restrict__ zfl,
                     const void* __restrict__ Wnl, const void* __restrict__ bnl,
                     void* __restrict__ out, const int* __restrict__ dflag)
{
  const int bf = *dflag;
  __shared__ float As[16][68];
  __shared__ float Bs[16][68];
  const int tid = threadIdx.x;
  const int tx = tid & 15, ty = tid >> 4;
  const int row0 = blockIdx.y * 64, col0 = blockIdx.x * 64;
  const int K = 600, N = 300;

  float acc[4][4];
#pragma unroll
  for (int i = 0; i < 4; ++i)
#pragma unroll
    for (int j = 0; j < 4; ++j) acc[i][j] = 0.f;

  for (int k0 = 0; k0 < K; k0 += 16) {
    for (int l = tid; l < 1024; l += 256) {
      int r = l >> 4, kk = l & 15;
      int gr = row0 + r, gk = k0 + kk;
      float v = 0.f;
      if (gk < 300)      v = ldf(w2v, (size_t)gr * 300 + gk, bf);
      else if (gk < 600) v = b2f(zfl[(size_t)gr * 300 + (gk - 300)]);
      As[kk][r] = v;
    }
    for (int l = tid; l < 1024; l += 256) {
      int c = l & 63, kk = l >> 6;
      int gc = col0 + c, gk = k0 + kk;
      Bs[kk][c] = (gk < K && gc < N) ? ldf(Wnl, (size_t)gk * 300 + gc, bf) : 0.f;
    }
    __syncthreads();
#pragma unroll
    for (int kk = 0; kk < 16; ++kk) {
      float av[4], bv[4];
#pragma unroll
      for (int i = 0; i < 4; ++i) av[i] = As[kk][ty * 4 + i];
#pragma unroll
      for (int j = 0; j < 4; ++j) bv[j] = Bs[kk][tx * 4 + j];
#pragma unroll
      for (int i = 0; i < 4; ++i)
#pragma unroll
        for (int j = 0; j < 4; ++j) acc[i][j] = fmaf(av[i], bv[j], acc[i][j]);
    }
    __syncthreads();
  }
#pragma unroll
  for (int i = 0; i < 4; ++i) {
    int r = row0 + ty * 4 + i;
#pragma unroll
    for (int j = 0; j < 4; ++j) {
      int c = col0 + tx * 4 + j;
      if (c < N) {
        float v = acc[i][j] + ldf(bnl, c, bf);
        stf(out, OUT0_ELEMS + (size_t)r * 300 + c, fmaxf(v, 0.f), bf);
      }
    }
  }
}

//=====================================================================
extern "C" void kernel_launch(void* const* d_in, const int* in_sizes, int n_in,
                              void* d_out, int out_size, void* d_ws, size_t ws_size,
                              hipStream_t stream)
{
  (void)hipGetLastError();  // clear any stale error

  // sentinel: wrong input count -> 0x41 pattern (~12.1 as f32/bf16)
  if (n_in != 17) { hipMemsetAsync(d_out, 0x41, 4096, stream); return; }

  const void* n_f = d_in[0];
  const void* w2v = d_in[1];
  const void* s_f = d_in[2];
  const int*  src = (const int*)d_in[3];
  const int*  dst = (const int*)d_in[4];
  const void* We  = d_in[5];
  const void* be  = d_in[6];
  const void* Wel = d_in[7];
  const void* bel = d_in[8];
  const void* Wa  = d_in[9];
  const void* ba  = d_in[10];
  const void* Wal = d_in[11];
  const void* bal = d_in[12];
  const void* Wn  = d_in[13];
  const void* bn  = d_in[14];
  const void* Wnl = d_in[15];
  const void* bnl = d_in[16];

  // workspace carve-out (~76 MB)
  char* ws = (char*)d_ws;
  size_t o = 0;
  auto alloc = [&](size_t bytes) -> void* {
    void* p = ws + o; o += bytes; o = (o + 255) & ~(size_t)255; return p;
  };
  int* dflag  = (int*)alloc(4);
  bf16* P     = (bf16*)alloc((size_t)N_NODES * 2048 * 2);
  bf16* Q     = (bf16*)alloc((size_t)N_NODES * 1200 * 2);
  bf16* zf    = (bf16*)alloc((size_t)N_NODES * 1024 * 2);
  bf16* zfl   = (bf16*)alloc((size_t)N_NODES * 300 * 2);
  float* af   = (float*)alloc((size_t)N_EDGES * 4);
  float* afl  = (float*)alloc((size_t)N_EDGES * 4);
  int* cnt    = (int*)alloc((size_t)N_NODES * 4);
  int* offs   = (int*)alloc((size_t)(N_NODES + 1) * 4);
  int* cur    = (int*)alloc((size_t)N_NODES * 4);
  int* elist  = (int*)alloc((size_t)N_EDGES * 4);

  // sentinel: workspace too small -> 0x42 pattern (~48.5)
  if (o > ws_size) { hipMemsetAsync(d_out, 0x42, 4096, stream); return; }

  gnn3_detect<<<1, 256, 0, stream>>>((const unsigned int*)n_f, dflag);
  gnn3_zero<<<N_NODES / 256, 256, 0, stream>>>(cnt, N_NODES);

  {
    dim3 g(2048 / 64, N_NODES / 64);
    gnn3_gemm_P<<<g, 256, 0, stream>>>(n_f, We, P, dflag);
  }
  {
    dim3 g((1200 + 63) / 64, N_NODES / 64);
    gnn3_gemm_Q<<<g, 256, 0, stream>>>(w2v, Wel, Q, dflag);
  }

  gnn3_edge_score<<<N_EDGES / 4, 256, 0, stream>>>(src, dst, s_f, We, be, Wa, ba,
                                                   bel, Wal, bal, P, Q, af, afl, dflag);

  gnn3_count<<<N_EDGES / 256, 256, 0, stream>>>(dst, cnt);
  gnn3_scan<<<1, 1024, 0, stream>>>(cnt, offs, cur);
  gnn3_fill<<<N_EDGES / 256, 256, 0, stream>>>(dst, cur, elist);

  gnn3_node_z<<<N_NODES, 256, 0, stream>>>(offs, elist, src, af, afl, n_f, w2v,
                                           s_f, We, be, P, zf, zfl, dflag);

  {
    dim3 g(1024 / 64, N_NODES / 64);
    gnn3_gemm_out_n<<<g, 256, 0, stream>>>(n_f, zf, Wn, bn, d_out, dflag);
  }
  {
    dim3 g((300 + 63) / 64, N_NODES / 64);
    gnn3_gemm_out_l<<<g, 256, 0, stream>>>(w2v, zfl, Wnl, bnl, d_out, dflag);
  }

  // sentinel: any enqueue error -> 0x44 pattern (~785 as f32)
  if (hipGetLastError() != hipSuccess) hipMemsetAsync(d_out, 0x44, 4096, stream);
}

// Round 5
// 1943.784 us; speedup vs baseline: 1.5936x; 1.5936x over previous
//
#include <hip/hip_runtime.h>
#include <hip/hip_bf16.h>

#define N_NODES 8192
#define N_EDGES 65536
#define OUT0_ELEMS ((size_t)N_NODES * 1024)

using bf16 = __hip_bfloat16;

__device__ __forceinline__ float b2f(bf16 x) { return __bfloat162float(x); }
__device__ __forceinline__ bf16 f2b(float x) { return __float2bfloat16(x); }

// dual-dtype load: flag=1 -> buffer holds bf16, flag=0 -> float32
__device__ __forceinline__ float ldf(const void* p, size_t i, int bf)
{
  if (bf) {
    unsigned short u = ((const unsigned short*)p)[i];
    unsigned int x = ((unsigned int)u) << 16;
    float f; __builtin_memcpy(&f, &x, 4); return f;
  }
  return ((const float*)p)[i];
}
// dual-dtype store into the (flat) output buffer
__device__ __forceinline__ void stf(void* p, size_t i, float v, int bf)
{
  if (bf) {
    bf16 t = __float2bfloat16(v);
    unsigned short u; __builtin_memcpy(&u, &t, 2);
    ((unsigned short*)p)[i] = u;
  } else {
    ((float*)p)[i] = v;
  }
}

// Kept so any harness-side reference to the stub symbol still resolves.
__global__ void GNN_27650999451833_kernel() {}

//---------------------------------------------------------------------
// dtype probe: low 16 bits of each u32 word of N(0,1) data.
//---------------------------------------------------------------------
__global__ void gnn3_detect(const unsigned int* __restrict__ w, int* __restrict__ flag)
{
  __shared__ int cnt;
  if (threadIdx.x == 0) cnt = 0;
  __syncthreads();
  int hits = 0;
  for (int i = threadIdx.x; i < 512; i += 256) {
    unsigned lo = w[i] & 0xFFFFu;
    unsigned ex = (lo >> 7) & 0xFFu;
    if (ex >= 115 && ex <= 130) hits++;
  }
  atomicAdd(&cnt, hits);
  __syncthreads();
  if (threadIdx.x == 0) *flag = (cnt >= 256) ? 1 : 0;
}

__global__ void gnn3_zero(int* __restrict__ p, int n)
{
  int i = blockIdx.x * blockDim.x + threadIdx.x;
  if (i < n) p[i] = 0;
}

//---------------------------------------------------------------------
// GEMM 1: P[8192,2048](bf16) = n_f[8192,1024] @ [We[0:1024] | We[1040:2064]]
//---------------------------------------------------------------------
__global__ __launch_bounds__(256)
void gnn3_gemm_P(const void* __restrict__ n_f, const void* __restrict__ We,
                 bf16* __restrict__ P, const int* __restrict__ dflag)
{
  const int bf = *dflag;
  __shared__ float As[16][68];
  __shared__ float Bs[16][68];
  const int tid = threadIdx.x;
  const int tx = tid & 15, ty = tid >> 4;
  const int row0 = blockIdx.y * 64, col0 = blockIdx.x * 64;

  float acc[4][4];
#pragma unroll
  for (int i = 0; i < 4; ++i)
#pragma unroll
    for (int j = 0; j < 4; ++j) acc[i][j] = 0.f;

  for (int k0 = 0; k0 < 1024; k0 += 16) {
    for (int l = tid; l < 1024; l += 256) {
      int r = l >> 4, kk = l & 15;
      As[kk][r] = ldf(n_f, (size_t)(row0 + r) * 1024 + (k0 + kk), bf);
    }
    for (int l = tid; l < 1024; l += 256) {
      int c = l & 63, kk = l >> 6;
      int gc = col0 + c, gk = k0 + kk;
      float v;
      if (gc < 1024) v = ldf(We, (size_t)gk * 1024 + gc, bf);
      else           v = ldf(We, (size_t)(1040 + gk) * 1024 + (gc - 1024), bf);
      Bs[kk][c] = v;
    }
    __syncthreads();
#pragma unroll
    for (int kk = 0; kk < 16; ++kk) {
      float av[4], bv[4];
#pragma unroll
      for (int i = 0; i < 4; ++i) av[i] = As[kk][ty * 4 + i];
#pragma unroll
      for (int j = 0; j < 4; ++j) bv[j] = Bs[kk][tx * 4 + j];
#pragma unroll
      for (int i = 0; i < 4; ++i)
#pragma unroll
        for (int j = 0; j < 4; ++j) acc[i][j] = fmaf(av[i], bv[j], acc[i][j]);
    }
    __syncthreads();
  }
#pragma unroll
  for (int i = 0; i < 4; ++i) {
    int r = row0 + ty * 4 + i;
#pragma unroll
    for (int j = 0; j < 4; ++j) {
      int c = col0 + tx * 4 + j;
      P[(size_t)r * 2048 + c] = f2b(acc[i][j]);
    }
  }
}

//---------------------------------------------------------------------
// GEMM 2: Q[8192,1200](bf16) = w2v[8192,300] @ [Wel[0:300] | Wel[300:600]]
//---------------------------------------------------------------------
__global__ __launch_bounds__(256)
void gnn3_gemm_Q(const void* __restrict__ w2v, const void* __restrict__ Wel,
                 bf16* __restrict__ Q, const int* __restrict__ dflag)
{
  const int bf = *dflag;
  __shared__ float As[16][68];
  __shared__ float Bs[16][68];
  const int tid = threadIdx.x;
  const int tx = tid & 15, ty = tid >> 4;
  const int row0 = blockIdx.y * 64, col0 = blockIdx.x * 64;
  const int K = 300, N = 1200;

  float acc[4][4];
#pragma unroll
  for (int i = 0; i < 4; ++i)
#pragma unroll
    for (int j = 0; j < 4; ++j) acc[i][j] = 0.f;

  for (int k0 = 0; k0 < K; k0 += 16) {
    for (int l = tid; l < 1024; l += 256) {
      int r = l >> 4, kk = l & 15;
      int gk = k0 + kk;
      As[kk][r] = (gk < K) ? ldf(w2v, (size_t)(row0 + r) * 300 + gk, bf) : 0.f;
    }
    for (int l = tid; l < 1024; l += 256) {
      int c = l & 63, kk = l >> 6;
      int gc = col0 + c, gk = k0 + kk;
      float v = 0.f;
      if (gk < K && gc < N) {
        if (gc < 600) v = ldf(Wel, (size_t)gk * 600 + gc, bf);
        else          v = ldf(Wel, (size_t)(300 + gk) * 600 + (gc - 600), bf);
      }
      Bs[kk][c] = v;
    }
    __syncthreads();
#pragma unroll
    for (int kk = 0; kk < 16; ++kk) {
      float av[4], bv[4];
#pragma unroll
      for (int i = 0; i < 4; ++i) av[i] = As[kk][ty * 4 + i];
#pragma unroll
      for (int j = 0; j < 4; ++j) bv[j] = Bs[kk][tx * 4 + j];
#pragma unroll
      for (int i = 0; i < 4; ++i)
#pragma unroll
        for (int j = 0; j < 4; ++j) acc[i][j] = fmaf(av[i], bv[j], acc[i][j]);
    }
    __syncthreads();
  }
#pragma unroll
  for (int i = 0; i < 4; ++i) {
    int r = row0 + ty * 4 + i;
#pragma unroll
    for (int j = 0; j < 4; ++j) {
      int c = col0 + tx * 4 + j;
      if (c < N) Q[(size_t)r * 1200 + c] = f2b(acc[i][j]);
    }
  }
}

//---------------------------------------------------------------------
// NEW edge scores: thread t owns coalesced cols c = t+256j (f: j<4,
// lang: c=t+256jj<600). We3/Wa/be/bel/Wal hoisted; 8 edges/block.
//---------------------------------------------------------------------
__global__ __launch_bounds__(256)
void gnn5_edge_score(const int* __restrict__ src, const int* __restrict__ dst,
                     const void* __restrict__ s_f, const void* __restrict__ We,
                     const void* __restrict__ be, const void* __restrict__ Wa,
                     const void* __restrict__ ba, const void* __restrict__ bel,
                     const void* __restrict__ Wal, const void* __restrict__ bal,
                     const bf16* __restrict__ P, const bf16* __restrict__ Q,
                     float* __restrict__ af, float* __restrict__ afl,
                     const int* __restrict__ dflag)
{
  const int bf = *dflag;
  const int t = threadIdx.x;
  const int lane = t & 63, w = t >> 6;
  const int e0 = blockIdx.x * 8;

  float wef[16][4];
#pragma unroll
  for (int k = 0; k < 16; ++k)
#pragma unroll
    for (int j = 0; j < 4; ++j)
      wef[k][j] = ldf(We, (size_t)(1024 + k) * 1024 + t + 256 * j, bf);

  float bev[4], wav[4];
#pragma unroll
  for (int j = 0; j < 4; ++j) {
    bev[j] = ldf(be, t + 256 * j, bf);
    wav[j] = ldf(Wa, t + 256 * j, bf);
  }
  float belv[3] = {0.f, 0.f, 0.f}, walv[3] = {0.f, 0.f, 0.f};
#pragma unroll
  for (int jj = 0; jj < 3; ++jj) {
    int c = t + 256 * jj;
    if (c < 600) { belv[jj] = ldf(bel, c, bf); walv[jj] = ldf(Wal, c, bf); }
  }
  const float ba0 = ldf(ba, 0, bf), bal0 = ldf(bal, 0, bf);

  __shared__ float shf[4], shl[4];

  for (int i = 0; i < 8; ++i) {
    const int e = e0 + i;
    const int s = src[e], d = dst[e];

    float sfv[16];
#pragma unroll
    for (int k = 0; k < 16; ++k) sfv[k] = ldf(s_f, (size_t)e * 16 + k, bf);

    const bf16* P1 = P + (size_t)s * 2048;
    const bf16* P2 = P + (size_t)d * 2048 + 1024;
    float pf = 0.f;
#pragma unroll
    for (int j = 0; j < 4; ++j) {
      int c = t + 256 * j;
      float v = b2f(P1[c]) + b2f(P2[c]) + bev[j];
#pragma unroll
      for (int k = 0; k < 16; ++k) v = fmaf(sfv[k], wef[k][j], v);
      pf = fmaf(fmaxf(v, 0.f), wav[j], pf);
    }

    const bf16* Q1 = Q + (size_t)s * 1200;
    const bf16* Q2 = Q + (size_t)d * 1200 + 600;
    float pl = 0.f;
#pragma unroll
    for (int jj = 0; jj < 3; ++jj) {
      int c = t + 256 * jj;
      if (c < 600) {
        float v = b2f(Q1[c]) + b2f(Q2[c]) + belv[jj];
        pl = fmaf(fmaxf(v, 0.f), walv[jj], pl);
      }
    }

#pragma unroll
    for (int o = 32; o > 0; o >>= 1) {
      pf += __shfl_down(pf, o, 64);
      pl += __shfl_down(pl, o, 64);
    }
    if (lane == 0) { shf[w] = pf; shl[w] = pl; }
    __syncthreads();
    if (t == 0)  af[e]  = shf[0] + shf[1] + shf[2] + shf[3] + ba0;
    if (t == 64) afl[e] = shl[0] + shl[1] + shl[2] + shl[3] + bal0;
    __syncthreads();
  }
}

//---------------------------------------------------------------------
// CSR build
//---------------------------------------------------------------------
__global__ void gnn3_count(const int* __restrict__ dst, int* __restrict__ cnt)
{
  int e = blockIdx.x * blockDim.x + threadIdx.x;
  if (e < N_EDGES) atomicAdd(&cnt[dst[e]], 1);
}

__global__ __launch_bounds__(1024)
void gnn3_scan(const int* __restrict__ cnt, int* __restrict__ off, int* __restrict__ cur)
{
  __shared__ int sh[1024];
  const int t = threadIdx.x;
  int local[8]; int sum = 0;
#pragma unroll
  for (int i = 0; i < 8; ++i) { int v = cnt[t * 8 + i]; local[i] = sum; sum += v; }
  sh[t] = sum;
  __syncthreads();
  for (int d = 1; d < 1024; d <<= 1) {
    int v = (t >= d) ? sh[t - d] : 0;
    __syncthreads();
    sh[t] += v;
    __syncthreads();
  }
  int basev = (t > 0) ? sh[t - 1] : 0;
#pragma unroll
  for (int i = 0; i < 8; ++i) { int o = basev + local[i]; off[t * 8 + i] = o; cur[t * 8 + i] = o; }
  if (t == 1023) off[8192] = sh[1023];
}

__global__ void gnn3_fill(const int* __restrict__ dst, int* __restrict__ cur,
                          int* __restrict__ elist)
{
  int e = blockIdx.x * blockDim.x + threadIdx.x;
  if (e < N_EDGES) { int p = atomicAdd(&cur[dst[e]], 1); elist[p] = e; }
}

//---------------------------------------------------------------------
// NEW: per-node softmax -> alpha written in place into af/afl.
//---------------------------------------------------------------------
__global__ __launch_bounds__(256)
void gnn5_alpha(const int* __restrict__ off, const int* __restrict__ elist,
                float* __restrict__ af, float* __restrict__ afl)
{
  const int n = blockIdx.x * 256 + threadIdx.x;
  if (n >= N_NODES) return;
  const int base = off[n];
  const int deg = off[n + 1] - base;
  float m = -1e30f, ml = -1e30f;
  for (int i = 0; i < deg; ++i) {
    int e = elist[base + i];
    m = fmaxf(m, af[e]);
    ml = fmaxf(ml, afl[e]);
  }
  float den = 0.f, denl = 0.f;
  for (int i = 0; i < deg; ++i) {
    int e = elist[base + i];
    den += expf(af[e] - m);
    denl += expf(afl[e] - ml);
  }
  float inv = (den > 0.f) ? 1.f / den : 0.f;
  float invl = (denl > 0.f) ? 1.f / denl : 0.f;
  for (int i = 0; i < deg; ++i) {
    int e = elist[base + i];
    af[e] = expf(af[e] - m) * inv;
    afl[e] = expf(afl[e] - ml) * invl;
  }
}

//---------------------------------------------------------------------
// NEW node_z: alpha precomputed, We3 hoisted to registers; layout and
// load primitives otherwise identical to the proven round-3 kernel.
//---------------------------------------------------------------------
__global__ __launch_bounds__(256)
void gnn5_node_z(const int* __restrict__ off, const int* __restrict__ elist,
                 const int* __restrict__ src, const float* __restrict__ af,
                 const float* __restrict__ afl, const void* __restrict__ n_f,
                 const void* __restrict__ w2v, const void* __restrict__ s_f,
                 const void* __restrict__ We, const void* __restrict__ be,
                 const bf16* __restrict__ P, bf16* __restrict__ zf,
                 bf16* __restrict__ zfl, const int* __restrict__ dflag)
{
  const int bf = *dflag;
  const int node = blockIdx.x;
  const int t = threadIdx.x;
  const int base = off[node];
  const int deg = off[node + 1] - base;

  float wef[16][4];
#pragma unroll
  for (int k = 0; k < 16; ++k)
#pragma unroll
    for (int j = 0; j < 4; ++j)
      wef[k][j] = ldf(We, (size_t)(1024 + k) * 1024 + t + 256 * j, bf);

  float p2[4];
#pragma unroll
  for (int j = 0; j < 4; ++j) {
    int c = t + 256 * j;
    p2[j] = b2f(P[(size_t)node * 2048 + 1024 + c]) + ldf(be, c, bf);
  }
  float acc[4] = {0.f, 0.f, 0.f, 0.f};
  float accl0 = 0.f, accl1 = 0.f;
  const int cl0 = t, cl1 = t + 256;

  for (int i = 0; i < deg; ++i) {
    int e = elist[base + i];
    int s = src[e];
    float wgt = af[e];
    float wl = afl[e];
    float sfv[16];
#pragma unroll
    for (int k = 0; k < 16; ++k) sfv[k] = ldf(s_f, (size_t)e * 16 + k, bf);
    const bf16* P1 = P + (size_t)s * 2048;
#pragma unroll
    for (int j = 0; j < 4; ++j) {
      int c = t + 256 * j;
      float ef = b2f(P1[c]) + p2[j];
#pragma unroll
      for (int k = 0; k < 16; ++k) ef = fmaf(sfv[k], wef[k][j], ef);
      ef = fmaxf(ef, 0.f);
      acc[j] = fmaf(wgt, ldf(n_f, (size_t)s * 1024 + c, bf) + ef, acc[j]);
    }
    if (cl0 < 300) accl0 = fmaf(wl, ldf(w2v, (size_t)s * 300 + cl0, bf), accl0);
    if (cl1 < 300) accl1 = fmaf(wl, ldf(w2v, (size_t)s * 300 + cl1, bf), accl1);
  }
#pragma unroll
  for (int j = 0; j < 4; ++j) zf[(size_t)node * 1024 + t + 256 * j] = f2b(acc[j]);
  if (cl0 < 300) zfl[(size_t)node * 300 + cl0] = f2b(accl0);
  if (cl1 < 300) zfl[(size_t)node * 300 + cl1] = f2b(accl1);
}

//---------------------------------------------------------------------
// GEMM 3: out0 = relu([n_f | zf] @ Wn + bn)    (K=2048, N=1024)
//---------------------------------------------------------------------
__global__ __launch_bounds__(256)
void gnn3_gemm_out_n(const void* __restrict__ n_f, const bf16* __restrict__ zf,
                     const void* __restrict__ Wn, const void* __restrict__ bn,
                     void* __restrict__ out, const int* __restrict__ dflag)
{
  const int bf = *dflag;
  __shared__ float As[16][68];
  __shared__ float Bs[16][68];
  const int tid = threadIdx.x;
  const int tx = tid & 15, ty = tid >> 4;
  const int row0 = blockIdx.y * 64, col0 = blockIdx.x * 64;

  float acc[4][4];
#pragma unroll
  for (int i = 0; i < 4; ++i)
#pragma unroll
    for (int j = 0; j < 4; ++j) acc[i][j] = 0.f;

  for (int k0 = 0; k0 < 2048; k0 += 16) {
    for (int l = tid; l < 1024; l += 256) {
      int r = l >> 4, kk = l & 15;
      int gr = row0 + r, gk = k0 + kk;
      float v;
      if (gk < 1024) v = ldf(n_f, (size_t)gr * 1024 + gk, bf);
      else           v = b2f(zf[(size_t)gr * 1024 + (gk - 1024)]);
      As[kk][r] = v;
    }
    for (int l = tid; l < 1024; l += 256) {
      int c = l & 63, kk = l >> 6;
      Bs[kk][c] = ldf(Wn, (size_t)(k0 + kk) * 1024 + (col0 + c), bf);
    }
    __syncthreads();
#pragma unroll
    for (int kk = 0; kk < 16; ++kk) {
      float av[4], bv[4];
#pragma unroll
      for (int i = 0; i < 4; ++i) av[i] = As[kk][ty * 4 + i];
#pragma unroll
      for (int j = 0; j < 4; ++j) bv[j] = Bs[kk][tx * 4 + j];
#pragma unroll
      for (int i = 0; i < 4; ++i)
#pragma unroll
        for (int j = 0; j < 4; ++j) acc[i][j] = fmaf(av[i], bv[j], acc[i][j]);
    }
    __syncthreads();
  }
#pragma unroll
  for (int i = 0; i < 4; ++i) {
    int r = row0 + ty * 4 + i;
#pragma unroll
    for (int j = 0; j < 4; ++j) {
      int c = col0 + tx * 4 + j;
      float v = acc[i][j] + ldf(bn, c, bf);
      stf(out, (size_t)r * 1024 + c, fmaxf(v, 0.f), bf);
    }
  }
}

//---------------------------------------------------------------------
// GEMM 4: out1 = relu([w2v | zfl] @ Wnl + bnl)  (K=600, N=300)
//---------------------------------------------------------------------
__global__ __launch_bounds__(256)
void gnn3_gemm_out_l(const void* __restrict__ w2v, const bf16* __restrict__ zfl,
                     const void* __restrict__ Wnl, const void* __restrict__ bnl,
                     void* __restrict__ out, const int* __restrict__ dflag)
{
  const int bf = *dflag;
  __shared__ float As[16][68];
  __shared__ float Bs[16][68];
  const int tid = threadIdx.x;
  const int tx = tid & 15, ty = tid >> 4;
  const int row0 = blockIdx.y * 64, col0 = blockIdx.x * 64;
  const int K = 600, N = 300;

  float acc[4][4];
#pragma unroll
  for (int i = 0; i < 4; ++i)
#pragma unroll
    for (int j = 0; j < 4; ++j) acc[i][j] = 0.f;

  for (int k0 = 0; k0 < K; k0 += 16) {
    for (int l = tid; l < 1024; l += 256) {
      int r = l >> 4, kk = l & 15;
      int gr = row0 + r, gk = k0 + kk;
      float v = 0.f;
      if (gk < 300)      v = ldf(w2v, (size_t)gr * 300 + gk, bf);
      else if (gk < 600) v = b2f(zfl[(size_t)gr * 300 + (gk - 300)]);
      As[kk][r] = v;
    }
    for (int l = tid; l < 1024; l += 256) {
      int c = l & 63, kk = l >> 6;
      int gc = col0 + c, gk = k0 + kk;
      Bs[kk][c] = (gk < K && gc < N) ? ldf(Wnl, (size_t)gk * 300 + gc, bf) : 0.f;
    }
    __syncthreads();
#pragma unroll
    for (int kk = 0; kk < 16; ++kk) {
      float av[4], bv[4];
#pragma unroll
      for (int i = 0; i < 4; ++i) av[i] = As[kk][ty * 4 + i];
#pragma unroll
      for (int j = 0; j < 4; ++j) bv[j] = Bs[kk][tx * 4 + j];
#pragma unroll
      for (int i = 0; i < 4; ++i)
#pragma unroll
        for (int j = 0; j < 4; ++j) acc[i][j] = fmaf(av[i], bv[j], acc[i][j]);
    }
    __syncthreads();
  }
#pragma unroll
  for (int i = 0; i < 4; ++i) {
    int r = row0 + ty * 4 + i;
#pragma unroll
    for (int j = 0; j < 4; ++j) {
      int c = col0 + tx * 4 + j;
      if (c < N) {
        float v = acc[i][j] + ldf(bnl, c, bf);
        stf(out, OUT0_ELEMS + (size_t)r * 300 + c, fmaxf(v, 0.f), bf);
      }
    }
  }
}

//=====================================================================
extern "C" void kernel_launch(void* const* d_in, const int* in_sizes, int n_in,
                              void* d_out, int out_size, void* d_ws, size_t ws_size,
                              hipStream_t stream)
{
  (void)hipGetLastError();  // clear any stale error

  if (n_in != 17) { hipMemsetAsync(d_out, 0x41, 4096, stream); return; }

  const void* n_f = d_in[0];
  const void* w2v = d_in[1];
  const void* s_f = d_in[2];
  const int*  src = (const int*)d_in[3];
  const int*  dst = (const int*)d_in[4];
  const void* We  = d_in[5];
  const void* be  = d_in[6];
  const void* Wel = d_in[7];
  const void* bel = d_in[8];
  const void* Wa  = d_in[9];
  const void* ba  = d_in[10];
  const void* Wal = d_in[11];
  const void* bal = d_in[12];
  const void* Wn  = d_in[13];
  const void* bn  = d_in[14];
  const void* Wnl = d_in[15];
  const void* bnl = d_in[16];

  char* ws = (char*)d_ws;
  size_t o = 0;
  auto alloc = [&](size_t bytes) -> void* {
    void* p = ws + o; o += bytes; o = (o + 255) & ~(size_t)255; return p;
  };
  int* dflag  = (int*)alloc(4);
  bf16* P     = (bf16*)alloc((size_t)N_NODES * 2048 * 2);
  bf16* Q     = (bf16*)alloc((size_t)N_NODES * 1200 * 2);
  bf16* zf    = (bf16*)alloc((size_t)N_NODES * 1024 * 2);
  bf16* zfl   = (bf16*)alloc((size_t)N_NODES * 300 * 2);
  float* af   = (float*)alloc((size_t)N_EDGES * 4);
  float* afl  = (float*)alloc((size_t)N_EDGES * 4);
  int* cnt    = (int*)alloc((size_t)N_NODES * 4);
  int* offs   = (int*)alloc((size_t)(N_NODES + 1) * 4);
  int* cur    = (int*)alloc((size_t)N_NODES * 4);
  int* elist  = (int*)alloc((size_t)N_EDGES * 4);

  if (o > ws_size) { hipMemsetAsync(d_out, 0x42, 4096, stream); return; }

  gnn3_detect<<<1, 256, 0, stream>>>((const unsigned int*)n_f, dflag);
  gnn3_zero<<<N_NODES / 256, 256, 0, stream>>>(cnt, N_NODES);

  {
    dim3 g(2048 / 64, N_NODES / 64);
    gnn3_gemm_P<<<g, 256, 0, stream>>>(n_f, We, P, dflag);
  }
  {
    dim3 g((1200 + 63) / 64, N_NODES / 64);
    gnn3_gemm_Q<<<g, 256, 0, stream>>>(w2v, Wel, Q, dflag);
  }

  gnn5_edge_score<<<N_EDGES / 8, 256, 0, stream>>>(src, dst, s_f, We, be, Wa, ba,
                                                   bel, Wal, bal, P, Q, af, afl, dflag);

  gnn3_count<<<N_EDGES / 256, 256, 0, stream>>>(dst, cnt);
  gnn3_scan<<<1, 1024, 0, stream>>>(cnt, offs, cur);
  gnn3_fill<<<N_EDGES / 256, 256, 0, stream>>>(dst, cur, elist);
  gnn5_alpha<<<N_NODES / 256, 256, 0, stream>>>(offs, elist, af, afl);

  gnn5_node_z<<<N_NODES, 256, 0, stream>>>(offs, elist, src, af, afl, n_f, w2v,
                                           s_f, We, be, P, zf, zfl, dflag);

  {
    dim3 g(1024 / 64, N_NODES / 64);
    gnn3_gemm_out_n<<<g, 256, 0, stream>>>(n_f, zf, Wn, bn, d_out, dflag);
  }
  {
    dim3 g((300 + 63) / 64, N_NODES / 64);
    gnn3_gemm_out_l<<<g, 256, 0, stream>>>(w2v, zfl, Wnl, bnl, d_out, dflag);
  }

  if (hipGetLastError() != hipSuccess) hipMemsetAsync(d_out, 0x44, 4096, stream);
}

// Round 6
// 993.164 us; speedup vs baseline: 3.1189x; 1.9572x over previous
//
#include <hip/hip_runtime.h>
#include <hip/hip_bf16.h>

#define N_NODES 8192
#define N_EDGES 65536
#define OUT0_ELEMS ((size_t)N_NODES * 1024)

using bf16 = __hip_bfloat16;
typedef __attribute__((ext_vector_type(8))) short short8;
typedef __attribute__((ext_vector_type(4))) float f32x4;

__device__ __forceinline__ float b2f(bf16 x) { return __bfloat162float(x); }
__device__ __forceinline__ bf16 f2b(float x) { return __float2bfloat16(x); }
__device__ __forceinline__ unsigned short bbits(float x)
{
  union { bf16 h; unsigned short u; } v; v.h = f2b(x); return v.u;
}
__device__ __forceinline__ unsigned pack2(float a, float b)
{
  return (unsigned)bbits(a) | ((unsigned)bbits(b) << 16);
}

// Kept so any harness-side reference to the stub symbol still resolves.
__global__ void GNN_27650999451833_kernel() {}

__global__ void gnn6_zero(int* __restrict__ p, int n)
{
  int i = blockIdx.x * blockDim.x + threadIdx.x;
  if (i < n) p[i] = 0;
}

//---------------------------------------------------------------------
// MFMA GEMM 1: P[8192,2048](bf16) = n_f[8192,1024](f32) @
//              [We[0:1024] | We[1040:2064]] (f32), bf16 convert in staging.
// 64x64 tile, BK=32, 4 waves; wave w -> rows 16w..16w+15, 4 n-subtiles.
// Verified layouts (m89/m91): A[m=lane&15][k=q*8+j], B[k=q*8+j][n=lane&15],
// D: row=q*4+reg, col=lane&15.
//---------------------------------------------------------------------
__global__ __launch_bounds__(256)
void gnn6_mm_P(const float* __restrict__ n_f, const float* __restrict__ We,
               bf16* __restrict__ P)
{
  __shared__ short As[64 * 40];   // [row][k], stride 40 shorts (80 B)
  __shared__ short Bs[64 * 40];   // [n][k] (transposed)
  const int t = threadIdx.x;
  const int row0 = blockIdx.y * 64, col0 = blockIdx.x * 64;
  const int lane = t & 63, w = t >> 6, m16 = lane & 15, q = lane >> 4;

  f32x4 acc[4];
#pragma unroll
  for (int nb = 0; nb < 4; ++nb) acc[nb] = (f32x4){0.f, 0.f, 0.f, 0.f};

  const int ar = t >> 2, ah = (t & 3) * 8;       // A: 64 rows x 8 k each
  const int bk = t >> 3, bn0 = (t & 7) * 8;      // B: 32 k x 8 n each
  const float* asrc = n_f + (size_t)(row0 + ar) * 1024 + ah;
  const float* bsrc = (col0 < 1024)
      ? (We + (size_t)bk * 1024 + col0 + bn0)
      : (We + (size_t)(1040 + bk) * 1024 + (col0 - 1024) + bn0);

  for (int k0 = 0; k0 < 1024; k0 += 32) {
    float4 a0 = *(const float4*)(asrc + k0);
    float4 a1 = *(const float4*)(asrc + k0 + 4);
    uint4 ap;
    ap.x = pack2(a0.x, a0.y); ap.y = pack2(a0.z, a0.w);
    ap.z = pack2(a1.x, a1.y); ap.w = pack2(a1.z, a1.w);
    *(uint4*)&As[ar * 40 + ah] = ap;

    float4 b0 = *(const float4*)(bsrc + (size_t)k0 * 1024);
    float4 b1 = *(const float4*)(bsrc + (size_t)k0 * 1024 + 4);
    Bs[(bn0 + 0) * 40 + bk] = (short)bbits(b0.x);
    Bs[(bn0 + 1) * 40 + bk] = (short)bbits(b0.y);
    Bs[(bn0 + 2) * 40 + bk] = (short)bbits(b0.z);
    Bs[(bn0 + 3) * 40 + bk] = (short)bbits(b0.w);
    Bs[(bn0 + 4) * 40 + bk] = (short)bbits(b1.x);
    Bs[(bn0 + 5) * 40 + bk] = (short)bbits(b1.y);
    Bs[(bn0 + 6) * 40 + bk] = (short)bbits(b1.z);
    Bs[(bn0 + 7) * 40 + bk] = (short)bbits(b1.w);
    __syncthreads();

    short8 a = *(const short8*)&As[(16 * w + m16) * 40 + 8 * q];
#pragma unroll
    for (int nb = 0; nb < 4; ++nb) {
      short8 b = *(const short8*)&Bs[(16 * nb + m16) * 40 + 8 * q];
      acc[nb] = __builtin_amdgcn_mfma_f32_16x16x32_bf16(a, b, acc[nb], 0, 0, 0);
    }
    __syncthreads();
  }
#pragma unroll
  for (int nb = 0; nb < 4; ++nb)
#pragma unroll
    for (int r = 0; r < 4; ++r)
      P[(size_t)(row0 + 16 * w + 4 * q + r) * 2048 + col0 + 16 * nb + m16] =
          f2b(acc[nb][r]);
}

//---------------------------------------------------------------------
// MFMA GEMM 2: out0[8192,1024](f32) = relu([n_f(f32) | zf(bf16)] @ Wn(f32) + bn)
//---------------------------------------------------------------------
__global__ __launch_bounds__(256)
void gnn6_mm_out_n(const float* __restrict__ n_f, const bf16* __restrict__ zf,
                   const float* __restrict__ Wn, const float* __restrict__ bn,
                   float* __restrict__ out)
{
  __shared__ short As[64 * 40];
  __shared__ short Bs[64 * 40];
  const int t = threadIdx.x;
  const int row0 = blockIdx.y * 64, col0 = blockIdx.x * 64;
  const int lane = t & 63, w = t >> 6, m16 = lane & 15, q = lane >> 4;

  f32x4 acc[4];
#pragma unroll
  for (int nb = 0; nb < 4; ++nb) acc[nb] = (f32x4){0.f, 0.f, 0.f, 0.f};

  const int ar = t >> 2, ah = (t & 3) * 8;
  const int bk = t >> 3, bn0 = (t & 7) * 8;
  const float* bsrc = Wn + (size_t)bk * 1024 + col0 + bn0;

  for (int k0 = 0; k0 < 2048; k0 += 32) {
    const int gk = k0 + ah;
    uint4 ap;
    if (gk < 1024) {
      float4 a0 = *(const float4*)(n_f + (size_t)(row0 + ar) * 1024 + gk);
      float4 a1 = *(const float4*)(n_f + (size_t)(row0 + ar) * 1024 + gk + 4);
      ap.x = pack2(a0.x, a0.y); ap.y = pack2(a0.z, a0.w);
      ap.z = pack2(a1.x, a1.y); ap.w = pack2(a1.z, a1.w);
    } else {
      ap = *(const uint4*)(zf + (size_t)(row0 + ar) * 1024 + (gk - 1024));
    }
    *(uint4*)&As[ar * 40 + ah] = ap;

    float4 b0 = *(const float4*)(bsrc + (size_t)k0 * 1024);
    float4 b1 = *(const float4*)(bsrc + (size_t)k0 * 1024 + 4);
    Bs[(bn0 + 0) * 40 + bk] = (short)bbits(b0.x);
    Bs[(bn0 + 1) * 40 + bk] = (short)bbits(b0.y);
    Bs[(bn0 + 2) * 40 + bk] = (short)bbits(b0.z);
    Bs[(bn0 + 3) * 40 + bk] = (short)bbits(b0.w);
    Bs[(bn0 + 4) * 40 + bk] = (short)bbits(b1.x);
    Bs[(bn0 + 5) * 40 + bk] = (short)bbits(b1.y);
    Bs[(bn0 + 6) * 40 + bk] = (short)bbits(b1.z);
    Bs[(bn0 + 7) * 40 + bk] = (short)bbits(b1.w);
    __syncthreads();

    short8 a = *(const short8*)&As[(16 * w + m16) * 40 + 8 * q];
#pragma unroll
    for (int nb = 0; nb < 4; ++nb) {
      short8 b = *(const short8*)&Bs[(16 * nb + m16) * 40 + 8 * q];
      acc[nb] = __builtin_amdgcn_mfma_f32_16x16x32_bf16(a, b, acc[nb], 0, 0, 0);
    }
    __syncthreads();
  }
#pragma unroll
  for (int nb = 0; nb < 4; ++nb) {
    int c = col0 + 16 * nb + m16;
    float bias = bn[c];
#pragma unroll
    for (int r = 0; r < 4; ++r) {
      float v = acc[nb][r] + bias;
      out[(size_t)(row0 + 16 * w + 4 * q + r) * 1024 + c] = fmaxf(v, 0.f);
    }
  }
}

//---------------------------------------------------------------------
// VALU GEMM: Q[8192,1200](bf16) = w2v[8192,300](f32) @ [Wel[0:300]|Wel[300:600]]
//---------------------------------------------------------------------
__global__ __launch_bounds__(256)
void gnn6_gemm_Q(const float* __restrict__ w2v, const float* __restrict__ Wel,
                 bf16* __restrict__ Q)
{
  __shared__ float As[16][68];
  __shared__ float Bs[16][68];
  const int tid = threadIdx.x;
  const int tx = tid & 15, ty = tid >> 4;
  const int row0 = blockIdx.y * 64, col0 = blockIdx.x * 64;
  const int K = 300, N = 1200;

  float acc[4][4];
#pragma unroll
  for (int i = 0; i < 4; ++i)
#pragma unroll
    for (int j = 0; j < 4; ++j) acc[i][j] = 0.f;

  for (int k0 = 0; k0 < K; k0 += 16) {
    for (int l = tid; l < 1024; l += 256) {
      int r = l >> 4, kk = l & 15;
      int gk = k0 + kk;
      As[kk][r] = (gk < K) ? w2v[(size_t)(row0 + r) * 300 + gk] : 0.f;
    }
    for (int l = tid; l < 1024; l += 256) {
      int c = l & 63, kk = l >> 6;
      int gc = col0 + c, gk = k0 + kk;
      float v = 0.f;
      if (gk < K && gc < N) {
        if (gc < 600) v = Wel[(size_t)gk * 600 + gc];
        else          v = Wel[(size_t)(300 + gk) * 600 + (gc - 600)];
      }
      Bs[kk][c] = v;
    }
    __syncthreads();
#pragma unroll
    for (int kk = 0; kk < 16; ++kk) {
      float av[4], bv[4];
#pragma unroll
      for (int i = 0; i < 4; ++i) av[i] = As[kk][ty * 4 + i];
#pragma unroll
      for (int j = 0; j < 4; ++j) bv[j] = Bs[kk][tx * 4 + j];
#pragma unroll
      for (int i = 0; i < 4; ++i)
#pragma unroll
        for (int j = 0; j < 4; ++j) acc[i][j] = fmaf(av[i], bv[j], acc[i][j]);
    }
    __syncthreads();
  }
#pragma unroll
  for (int i = 0; i < 4; ++i) {
    int r = row0 + ty * 4 + i;
#pragma unroll
    for (int j = 0; j < 4; ++j) {
      int c = col0 + tx * 4 + j;
      if (c < N) Q[(size_t)r * 1200 + c] = f2b(acc[i][j]);
    }
  }
}

//---------------------------------------------------------------------
// Edge scores: thread t owns coalesced cols c = t+256j; We3/Wa/be/bel/Wal
// hoisted to registers; 8 edges per block.
//---------------------------------------------------------------------
__global__ __launch_bounds__(256)
void gnn6_edge_score(const int* __restrict__ src, const int* __restrict__ dst,
                     const float* __restrict__ s_f, const float* __restrict__ We,
                     const float* __restrict__ be, const float* __restrict__ Wa,
                     const float* __restrict__ ba, const float* __restrict__ bel,
                     const float* __restrict__ Wal, const float* __restrict__ bal,
                     const bf16* __restrict__ P, const bf16* __restrict__ Q,
                     float* __restrict__ af, float* __restrict__ afl)
{
  const int t = threadIdx.x;
  const int lane = t & 63, w = t >> 6;
  const int e0 = blockIdx.x * 8;

  float wef[16][4];
#pragma unroll
  for (int k = 0; k < 16; ++k)
#pragma unroll
    for (int j = 0; j < 4; ++j)
      wef[k][j] = We[(size_t)(1024 + k) * 1024 + t + 256 * j];

  float bev[4], wav[4];
#pragma unroll
  for (int j = 0; j < 4; ++j) {
    bev[j] = be[t + 256 * j];
    wav[j] = Wa[t + 256 * j];
  }
  float belv[3] = {0.f, 0.f, 0.f}, walv[3] = {0.f, 0.f, 0.f};
#pragma unroll
  for (int jj = 0; jj < 3; ++jj) {
    int c = t + 256 * jj;
    if (c < 600) { belv[jj] = bel[c]; walv[jj] = Wal[c]; }
  }
  const float ba0 = ba[0], bal0 = bal[0];

  __shared__ float shf[4], shl[4];

  for (int i = 0; i < 8; ++i) {
    const int e = e0 + i;
    const int s = src[e], d = dst[e];

    float sfv[16];
#pragma unroll
    for (int k = 0; k < 16; ++k) sfv[k] = s_f[(size_t)e * 16 + k];

    const bf16* P1 = P + (size_t)s * 2048;
    const bf16* P2 = P + (size_t)d * 2048 + 1024;
    float pf = 0.f;
#pragma unroll
    for (int j = 0; j < 4; ++j) {
      int c = t + 256 * j;
      float v = b2f(P1[c]) + b2f(P2[c]) + bev[j];
#pragma unroll
      for (int k = 0; k < 16; ++k) v = fmaf(sfv[k], wef[k][j], v);
      pf = fmaf(fmaxf(v, 0.f), wav[j], pf);
    }

    const bf16* Q1 = Q + (size_t)s * 1200;
    const bf16* Q2 = Q + (size_t)d * 1200 + 600;
    float pl = 0.f;
#pragma unroll
    for (int jj = 0; jj < 3; ++jj) {
      int c = t + 256 * jj;
      if (c < 600) {
        float v = b2f(Q1[c]) + b2f(Q2[c]) + belv[jj];
        pl = fmaf(fmaxf(v, 0.f), walv[jj], pl);
      }
    }

#pragma unroll
    for (int o = 32; o > 0; o >>= 1) {
      pf += __shfl_down(pf, o, 64);
      pl += __shfl_down(pl, o, 64);
    }
    if (lane == 0) { shf[w] = pf; shl[w] = pl; }
    __syncthreads();
    if (t == 0)  af[e]  = shf[0] + shf[1] + shf[2] + shf[3] + ba0;
    if (t == 64) afl[e] = shl[0] + shl[1] + shl[2] + shl[3] + bal0;
    __syncthreads();
  }
}

//---------------------------------------------------------------------
// CSR build
//---------------------------------------------------------------------
__global__ void gnn6_count(const int* __restrict__ dst, int* __restrict__ cnt)
{
  int e = blockIdx.x * blockDim.x + threadIdx.x;
  if (e < N_EDGES) atomicAdd(&cnt[dst[e]], 1);
}

__global__ __launch_bounds__(1024)
void gnn6_scan(const int* __restrict__ cnt, int* __restrict__ off, int* __restrict__ cur)
{
  __shared__ int sh[1024];
  const int t = threadIdx.x;
  int local[8]; int sum = 0;
#pragma unroll
  for (int i = 0; i < 8; ++i) { int v = cnt[t * 8 + i]; local[i] = sum; sum += v; }
  sh[t] = sum;
  __syncthreads();
  for (int d = 1; d < 1024; d <<= 1) {
    int v = (t >= d) ? sh[t - d] : 0;
    __syncthreads();
    sh[t] += v;
    __syncthreads();
  }
  int basev = (t > 0) ? sh[t - 1] : 0;
#pragma unroll
  for (int i = 0; i < 8; ++i) { int o = basev + local[i]; off[t * 8 + i] = o; cur[t * 8 + i] = o; }
  if (t == 1023) off[8192] = sh[1023];
}

__global__ void gnn6_fill(const int* __restrict__ dst, int* __restrict__ cur,
                          int* __restrict__ elist)
{
  int e = blockIdx.x * blockDim.x + threadIdx.x;
  if (e < N_EDGES) { int p = atomicAdd(&cur[dst[e]], 1); elist[p] = e; }
}

//---------------------------------------------------------------------
// Per-node softmax -> alpha written in place into af/afl.
//---------------------------------------------------------------------
__global__ __launch_bounds__(256)
void gnn6_alpha(const int* __restrict__ off, const int* __restrict__ elist,
                float* __restrict__ af, float* __restrict__ afl)
{
  const int n = blockIdx.x * 256 + threadIdx.x;
  if (n >= N_NODES) return;
  const int base = off[n];
  const int deg = off[n + 1] - base;
  float m = -1e30f, ml = -1e30f;
  for (int i = 0; i < deg; ++i) {
    int e = elist[base + i];
    m = fmaxf(m, af[e]);
    ml = fmaxf(ml, afl[e]);
  }
  float den = 0.f, denl = 0.f;
  for (int i = 0; i < deg; ++i) {
    int e = elist[base + i];
    den += expf(af[e] - m);
    denl += expf(afl[e] - ml);
  }
  float inv = (den > 0.f) ? 1.f / den : 0.f;
  float invl = (denl > 0.f) ? 1.f / denl : 0.f;
  for (int i = 0; i < deg; ++i) {
    int e = elist[base + i];
    af[e] = expf(af[e] - m) * inv;
    afl[e] = expf(afl[e] - ml) * invl;
  }
}

//---------------------------------------------------------------------
// Per-node accumulate with precomputed alpha; We3 hoisted to registers.
//---------------------------------------------------------------------
__global__ __launch_bounds__(256)
void gnn6_node_z(const int* __restrict__ off, const int* __restrict__ elist,
                 const int* __restrict__ src, const float* __restrict__ af,
                 const float* __restrict__ afl, const float* __restrict__ n_f,
                 const float* __restrict__ w2v, const float* __restrict__ s_f,
                 const float* __restrict__ We, const float* __restrict__ be,
                 const bf16* __restrict__ P, bf16* __restrict__ zf,
                 bf16* __restrict__ zfl)
{
  const int node = blockIdx.x;
  const int t = threadIdx.x;
  const int base = off[node];
  const int deg = off[node + 1] - base;

  float wef[16][4];
#pragma unroll
  for (int k = 0; k < 16; ++k)
#pragma unroll
    for (int j = 0; j < 4; ++j)
      wef[k][j] = We[(size_t)(1024 + k) * 1024 + t + 256 * j];

  float p2[4];
#pragma unroll
  for (int j = 0; j < 4; ++j) {
    int c = t + 256 * j;
    p2[j] = b2f(P[(size_t)node * 2048 + 1024 + c]) + be[c];
  }
  float acc[4] = {0.f, 0.f, 0.f, 0.f};
  float accl0 = 0.f, accl1 = 0.f;
  const int cl0 = t, cl1 = t + 256;

  for (int i = 0; i < deg; ++i) {
    int e = elist[base + i];
    int s = src[e];
    float wgt = af[e];
    float wl = afl[e];
    float sfv[16];
#pragma unroll
    for (int k = 0; k < 16; ++k) sfv[k] = s_f[(size_t)e * 16 + k];
    const bf16* P1 = P + (size_t)s * 2048;
#pragma unroll
    for (int j = 0; j < 4; ++j) {
      int c = t + 256 * j;
      float ef = b2f(P1[c]) + p2[j];
#pragma unroll
      for (int k = 0; k < 16; ++k) ef = fmaf(sfv[k], wef[k][j], ef);
      ef = fmaxf(ef, 0.f);
      acc[j] = fmaf(wgt, n_f[(size_t)s * 1024 + c] + ef, acc[j]);
    }
    if (cl0 < 300) accl0 = fmaf(wl, w2v[(size_t)s * 300 + cl0], accl0);
    if (cl1 < 300) accl1 = fmaf(wl, w2v[(size_t)s * 300 + cl1], accl1);
  }
#pragma unroll
  for (int j = 0; j < 4; ++j) zf[(size_t)node * 1024 + t + 256 * j] = f2b(acc[j]);
  if (cl0 < 300) zfl[(size_t)node * 300 + cl0] = f2b(accl0);
  if (cl1 < 300) zfl[(size_t)node * 300 + cl1] = f2b(accl1);
}

//---------------------------------------------------------------------
// VALU GEMM: out1[8192,300](f32) = relu([w2v | zfl] @ Wnl + bnl), K=600
//---------------------------------------------------------------------
__global__ __launch_bounds__(256)
void gnn6_gemm_out_l(const float* __restrict__ w2v, const bf16* __restrict__ zfl,
                     const float* __restrict__ Wnl, const float* __restrict__ bnl,
                     float* __restrict__ out2)
{
  __shared__ float As[16][68];
  __shared__ float Bs[16][68];
  const int tid = threadIdx.x;
  const int tx = tid & 15, ty = tid >> 4;
  const int row0 = blockIdx.y * 64, col0 = blockIdx.x * 64;
  const int K = 600, N = 300;

  float acc[4][4];
#pragma unroll
  for (int i = 0; i < 4; ++i)
#pragma unroll
    for (int j = 0; j < 4; ++j) acc[i][j] = 0.f;

  for (int k0 = 0; k0 < K; k0 += 16) {
    for (int l = tid; l < 1024; l += 256) {
      int r = l >> 4, kk = l & 15;
      int gr = row0 + r, gk = k0 + kk;
      float v = 0.f;
      if (gk < 300)      v = w2v[(size_t)gr * 300 + gk];
      else if (gk < 600) v = b2f(zfl[(size_t)gr * 300 + (gk - 300)]);
      As[kk][r] = v;
    }
    for (int l = tid; l < 1024; l += 256) {
      int c = l & 63, kk = l >> 6;
      int gc = col0 + c, gk = k0 + kk;
      Bs[kk][c] = (gk < K && gc < N) ? Wnl[(size_t)gk * 300 + gc] : 0.f;
    }
    __syncthreads();
#pragma unroll
    for (int kk = 0; kk < 16; ++kk) {
      float av[4], bv[4];
#pragma unroll
      for (int i = 0; i < 4; ++i) av[i] = As[kk][ty * 4 + i];
#pragma unroll
      for (int j = 0; j < 4; ++j) bv[j] = Bs[kk][tx * 4 + j];
#pragma unroll
      for (int i = 0; i < 4; ++i)
#pragma unroll
        for (int j = 0; j < 4; ++j) acc[i][j] = fmaf(av[i], bv[j], acc[i][j]);
    }
    __syncthreads();
  }
#pragma unroll
  for (int i = 0; i < 4; ++i) {
    int r = row0 + ty * 4 + i;
#pragma unroll
    for (int j = 0; j < 4; ++j) {
      int c = col0 + tx * 4 + j;
      if (c < N) {
        float v = acc[i][j] + bnl[c];
        out2[(size_t)r * 300 + c] = fmaxf(v, 0.f);
      }
    }
  }
}

//=====================================================================
extern "C" void kernel_launch(void* const* d_in, const int* in_sizes, int n_in,
                              void* d_out, int out_size, void* d_ws, size_t ws_size,
                              hipStream_t stream)
{
  (void)hipGetLastError();
  if (n_in != 17) { hipMemsetAsync(d_out, 0x41, 4096, stream); return; }

  const float* n_f = (const float*)d_in[0];
  const float* w2v = (const float*)d_in[1];
  const float* s_f = (const float*)d_in[2];
  const int*   src = (const int*)d_in[3];
  const int*   dst = (const int*)d_in[4];
  const float* We  = (const float*)d_in[5];
  const float* be  = (const float*)d_in[6];
  const float* Wel = (const float*)d_in[7];
  const float* bel = (const float*)d_in[8];
  const float* Wa  = (const float*)d_in[9];
  const float* ba  = (const float*)d_in[10];
  const float* Wal = (const float*)d_in[11];
  const float* bal = (const float*)d_in[12];
  const float* Wn  = (const float*)d_in[13];
  const float* bn  = (const float*)d_in[14];
  const float* Wnl = (const float*)d_in[15];
  const float* bnl = (const float*)d_in[16];
  float* out  = (float*)d_out;
  float* out2 = out + OUT0_ELEMS;

  char* ws = (char*)d_ws;
  size_t o = 0;
  auto alloc = [&](size_t bytes) -> void* {
    void* p = ws + o; o += bytes; o = (o + 255) & ~(size_t)255; return p;
  };
  bf16* P     = (bf16*)alloc((size_t)N_NODES * 2048 * 2);
  bf16* Q     = (bf16*)alloc((size_t)N_NODES * 1200 * 2);
  bf16* zf    = (bf16*)alloc((size_t)N_NODES * 1024 * 2);
  bf16* zfl   = (bf16*)alloc((size_t)N_NODES * 300 * 2);
  float* af   = (float*)alloc((size_t)N_EDGES * 4);
  float* afl  = (float*)alloc((size_t)N_EDGES * 4);
  int* cnt    = (int*)alloc((size_t)N_NODES * 4);
  int* offs   = (int*)alloc((size_t)(N_NODES + 1) * 4);
  int* cur    = (int*)alloc((size_t)N_NODES * 4);
  int* elist  = (int*)alloc((size_t)N_EDGES * 4);
  if (o > ws_size) { hipMemsetAsync(d_out, 0x42, 4096, stream); return; }

  gnn6_zero<<<N_NODES / 256, 256, 0, stream>>>(cnt, N_NODES);

  {
    dim3 g(2048 / 64, N_NODES / 64);
    gnn6_mm_P<<<g, 256, 0, stream>>>(n_f, We, P);
  }
  {
    dim3 g((1200 + 63) / 64, N_NODES / 64);
    gnn6_gemm_Q<<<g, 256, 0, stream>>>(w2v, Wel, Q);
  }

  gnn6_edge_score<<<N_EDGES / 8, 256, 0, stream>>>(src, dst, s_f, We, be, Wa, ba,
                                                   bel, Wal, bal, P, Q, af, afl);

  gnn6_count<<<N_EDGES / 256, 256, 0, stream>>>(dst, cnt);
  gnn6_scan<<<1, 1024, 0, stream>>>(cnt, offs, cur);
  gnn6_fill<<<N_EDGES / 256, 256, 0, stream>>>(dst, cur, elist);
  gnn6_alpha<<<N_NODES / 256, 256, 0, stream>>>(offs, elist, af, afl);

  gnn6_node_z<<<N_NODES, 256, 0, stream>>>(offs, elist, src, af, afl, n_f, w2v,
                                           s_f, We, be, P, zf, zfl);

  {
    dim3 g(1024 / 64, N_NODES / 64);
    gnn6_mm_out_n<<<g, 256, 0, stream>>>(n_f, zf, Wn, bn, out);
  }
  {
    dim3 g((300 + 63) / 64, N_NODES / 64);
    gnn6_gemm_out_l<<<g, 256, 0, stream>>>(w2v, zfl, Wnl, bnl, out2);
  }

  if (hipGetLastError() != hipSuccess) hipMemsetAsync(d_out, 0x44, 4096, stream);
}

// Round 7
// 843.871 us; speedup vs baseline: 3.6707x; 1.1769x over previous
//
#include <hip/hip_runtime.h>
#include <hip/hip_bf16.h>

#define N_NODES 8192
#define N_EDGES 65536
#define OUT0_ELEMS ((size_t)N_NODES * 1024)

using bf16 = __hip_bfloat16;
typedef __attribute__((ext_vector_type(8))) short short8;
typedef __attribute__((ext_vector_type(4))) float f32x4;

__device__ __forceinline__ float b2f(bf16 x) { return __bfloat162float(x); }
__device__ __forceinline__ bf16 f2b(float x) { return __float2bfloat16(x); }
__device__ __forceinline__ unsigned short bbits(float x)
{
  union { bf16 h; unsigned short u; } v; v.h = f2b(x); return v.u;
}
__device__ __forceinline__ unsigned pack2(float a, float b)
{
  return (unsigned)bbits(a) | ((unsigned)bbits(b) << 16);
}

// Kept so any harness-side reference to the stub symbol still resolves.
__global__ void GNN_27650999451833_kernel() {}

__global__ void gnn6_zero(int* __restrict__ p, int n)
{
  int i = blockIdx.x * blockDim.x + threadIdx.x;
  if (i < n) p[i] = 0;
}

//---------------------------------------------------------------------
// f32 -> bf16 bulk convert (8 elems/thread)
//---------------------------------------------------------------------
__global__ __launch_bounds__(256)
void gnn7_cvt(const float* __restrict__ src, bf16* __restrict__ dst, int n8)
{
  int i = blockIdx.x * blockDim.x + threadIdx.x;
  if (i < n8) {
    float4 a = ((const float4*)src)[2 * i];
    float4 b = ((const float4*)src)[2 * i + 1];
    uint4 p;
    p.x = pack2(a.x, a.y); p.y = pack2(a.z, a.w);
    p.z = pack2(b.x, b.y); p.w = pack2(b.z, b.w);
    ((uint4*)dst)[i] = p;
  }
}

//---------------------------------------------------------------------
// MFMA GEMM 1: P[8192,2048](bf16) = nf_bf[8192,1024](bf16) @
//   [We[0:1024] | We[1040:2064]](f32, converted in staging)
// 128x128 tile, BK=32, 4 waves (2x2), 4x4 16x16 subtiles per wave,
// register prefetch of next tile. Layouts verified (m89/m91 + R6 pass):
// A[m=lane&15][k=q*8+j], B[k=q*8+j][n=lane&15], D row=4q+r col=lane&15.
//---------------------------------------------------------------------
__global__ __launch_bounds__(256)
void gnn7_mm_P(const bf16* __restrict__ A, const float* __restrict__ We,
               bf16* __restrict__ P)
{
  __shared__ short As[128 * 40];
  __shared__ short Bs[128 * 40];
  const int t = threadIdx.x;
  const int col0 = blockIdx.x * 128, row0 = blockIdx.y * 128;
  const int lane = t & 63, w = t >> 6, m16 = lane & 15, q = lane >> 4;
  const int wr = w >> 1, wc = w & 1;

  f32x4 acc[4][4];
#pragma unroll
  for (int mi = 0; mi < 4; ++mi)
#pragma unroll
    for (int ni = 0; ni < 4; ++ni) acc[mi][ni] = (f32x4){0.f, 0.f, 0.f, 0.f};

  const int ar = t >> 1, ah = (t & 1) * 16;   // A: row, k-offset (16 shorts)
  const int bk = t & 31, bn0 = (t >> 5) * 16; // B: k, n-group of 16

  const bf16* aptr = A + (size_t)(row0 + ar) * 1024 + ah;
  const float* bptr = (col0 < 1024)
      ? (We + (size_t)bk * 1024 + col0 + bn0)
      : (We + (size_t)(1040 + bk) * 1024 + (col0 - 1024) + bn0);

  uint4 a0 = *(const uint4*)(aptr);
  uint4 a1 = *(const uint4*)(aptr + 8);
  float4 b0 = *(const float4*)(bptr);
  float4 b1 = *(const float4*)(bptr + 4);
  float4 b2 = *(const float4*)(bptr + 8);
  float4 b3 = *(const float4*)(bptr + 12);

  for (int k0 = 0; k0 < 1024; k0 += 32) {
    if (k0) __syncthreads();
    *(uint4*)&As[ar * 40 + ah] = a0;
    *(uint4*)&As[ar * 40 + ah + 8] = a1;
    {
      short* brow = &Bs[bn0 * 40 + bk];
      brow[0 * 40] = (short)bbits(b0.x);  brow[1 * 40] = (short)bbits(b0.y);
      brow[2 * 40] = (short)bbits(b0.z);  brow[3 * 40] = (short)bbits(b0.w);
      brow[4 * 40] = (short)bbits(b1.x);  brow[5 * 40] = (short)bbits(b1.y);
      brow[6 * 40] = (short)bbits(b1.z);  brow[7 * 40] = (short)bbits(b1.w);
      brow[8 * 40] = (short)bbits(b2.x);  brow[9 * 40] = (short)bbits(b2.y);
      brow[10 * 40] = (short)bbits(b2.z); brow[11 * 40] = (short)bbits(b2.w);
      brow[12 * 40] = (short)bbits(b3.x); brow[13 * 40] = (short)bbits(b3.y);
      brow[14 * 40] = (short)bbits(b3.z); brow[15 * 40] = (short)bbits(b3.w);
    }
    __syncthreads();
    if (k0 + 32 < 1024) {
      a0 = *(const uint4*)(aptr + k0 + 32);
      a1 = *(const uint4*)(aptr + k0 + 40);
      const float* bp = bptr + (size_t)(k0 + 32) * 1024;
      b0 = *(const float4*)(bp);
      b1 = *(const float4*)(bp + 4);
      b2 = *(const float4*)(bp + 8);
      b3 = *(const float4*)(bp + 12);
    }
    short8 af[4];
#pragma unroll
    for (int mi = 0; mi < 4; ++mi)
      af[mi] = *(const short8*)&As[(wr * 64 + mi * 16 + m16) * 40 + 8 * q];
#pragma unroll
    for (int ni = 0; ni < 4; ++ni) {
      short8 bfv = *(const short8*)&Bs[(wc * 64 + ni * 16 + m16) * 40 + 8 * q];
#pragma unroll
      for (int mi = 0; mi < 4; ++mi)
        acc[mi][ni] =
            __builtin_amdgcn_mfma_f32_16x16x32_bf16(af[mi], bfv, acc[mi][ni], 0, 0, 0);
    }
  }
#pragma unroll
  for (int mi = 0; mi < 4; ++mi)
#pragma unroll
    for (int ni = 0; ni < 4; ++ni) {
      int c = col0 + wc * 64 + ni * 16 + m16;
#pragma unroll
      for (int r = 0; r < 4; ++r)
        P[(size_t)(row0 + wr * 64 + mi * 16 + 4 * q + r) * 2048 + c] =
            f2b(acc[mi][ni][r]);
    }
}

//---------------------------------------------------------------------
// MFMA GEMM 2: out0[8192,1024](f32) = relu([nf_bf | zf](bf16) @ Wn(f32) + bn)
// Same structure, K=2048.
//---------------------------------------------------------------------
__global__ __launch_bounds__(256)
void gnn7_mm_out_n(const bf16* __restrict__ nf_bf, const bf16* __restrict__ zf,
                   const float* __restrict__ Wn, const float* __restrict__ bn,
                   float* __restrict__ out)
{
  __shared__ short As[128 * 40];
  __shared__ short Bs[128 * 40];
  const int t = threadIdx.x;
  const int col0 = blockIdx.x * 128, row0 = blockIdx.y * 128;
  const int lane = t & 63, w = t >> 6, m16 = lane & 15, q = lane >> 4;
  const int wr = w >> 1, wc = w & 1;

  f32x4 acc[4][4];
#pragma unroll
  for (int mi = 0; mi < 4; ++mi)
#pragma unroll
    for (int ni = 0; ni < 4; ++ni) acc[mi][ni] = (f32x4){0.f, 0.f, 0.f, 0.f};

  const int ar = t >> 1, ah = (t & 1) * 16;
  const int bk = t & 31, bn0 = (t >> 5) * 16;

  const bf16* ap0 = nf_bf + (size_t)(row0 + ar) * 1024 + ah;
  const bf16* ap1 = zf + (size_t)(row0 + ar) * 1024 + ah;
  const float* bptr = Wn + (size_t)bk * 1024 + col0 + bn0;

  uint4 a0 = *(const uint4*)(ap0);
  uint4 a1 = *(const uint4*)(ap0 + 8);
  float4 b0 = *(const float4*)(bptr);
  float4 b1 = *(const float4*)(bptr + 4);
  float4 b2 = *(const float4*)(bptr + 8);
  float4 b3 = *(const float4*)(bptr + 12);

  for (int k0 = 0; k0 < 2048; k0 += 32) {
    if (k0) __syncthreads();
    *(uint4*)&As[ar * 40 + ah] = a0;
    *(uint4*)&As[ar * 40 + ah + 8] = a1;
    {
      short* brow = &Bs[bn0 * 40 + bk];
      brow[0 * 40] = (short)bbits(b0.x);  brow[1 * 40] = (short)bbits(b0.y);
      brow[2 * 40] = (short)bbits(b0.z);  brow[3 * 40] = (short)bbits(b0.w);
      brow[4 * 40] = (short)bbits(b1.x);  brow[5 * 40] = (short)bbits(b1.y);
      brow[6 * 40] = (short)bbits(b1.z);  brow[7 * 40] = (short)bbits(b1.w);
      brow[8 * 40] = (short)bbits(b2.x);  brow[9 * 40] = (short)bbits(b2.y);
      brow[10 * 40] = (short)bbits(b2.z); brow[11 * 40] = (short)bbits(b2.w);
      brow[12 * 40] = (short)bbits(b3.x); brow[13 * 40] = (short)bbits(b3.y);
      brow[14 * 40] = (short)bbits(b3.z); brow[15 * 40] = (short)bbits(b3.w);
    }
    __syncthreads();
    if (k0 + 32 < 2048) {
      int kn = k0 + 32;
      if (kn + ah < 1024) {
        a0 = *(const uint4*)(ap0 + kn);
        a1 = *(const uint4*)(ap0 + kn + 8);
      } else {
        a0 = *(const uint4*)(ap1 + (kn - 1024));
        a1 = *(const uint4*)(ap1 + (kn - 1024) + 8);
      }
      const float* bp = bptr + (size_t)kn * 1024;
      b0 = *(const float4*)(bp);
      b1 = *(const float4*)(bp + 4);
      b2 = *(const float4*)(bp + 8);
      b3 = *(const float4*)(bp + 12);
    }
    short8 af[4];
#pragma unroll
    for (int mi = 0; mi < 4; ++mi)
      af[mi] = *(const short8*)&As[(wr * 64 + mi * 16 + m16) * 40 + 8 * q];
#pragma unroll
    for (int ni = 0; ni < 4; ++ni) {
      short8 bfv = *(const short8*)&Bs[(wc * 64 + ni * 16 + m16) * 40 + 8 * q];
#pragma unroll
      for (int mi = 0; mi < 4; ++mi)
        acc[mi][ni] =
            __builtin_amdgcn_mfma_f32_16x16x32_bf16(af[mi], bfv, acc[mi][ni], 0, 0, 0);
    }
  }
#pragma unroll
  for (int mi = 0; mi < 4; ++mi)
#pragma unroll
    for (int ni = 0; ni < 4; ++ni) {
      int c = col0 + wc * 64 + ni * 16 + m16;
      float bias = bn[c];
#pragma unroll
      for (int r = 0; r < 4; ++r) {
        float v = acc[mi][ni][r] + bias;
        out[(size_t)(row0 + wr * 64 + mi * 16 + 4 * q + r) * 1024 + c] =
            fmaxf(v, 0.f);
      }
    }
}

//---------------------------------------------------------------------
// VALU GEMM: Q[8192,1200](bf16) = w2v[8192,300](f32) @ [Wel[0:300]|Wel[300:600]]
//---------------------------------------------------------------------
__global__ __launch_bounds__(256)
void gnn6_gemm_Q(const float* __restrict__ w2v, const float* __restrict__ Wel,
                 bf16* __restrict__ Q)
{
  __shared__ float As[16][68];
  __shared__ float Bs[16][68];
  const int tid = threadIdx.x;
  const int tx = tid & 15, ty = tid >> 4;
  const int row0 = blockIdx.y * 64, col0 = blockIdx.x * 64;
  const int K = 300, N = 1200;

  float acc[4][4];
#pragma unroll
  for (int i = 0; i < 4; ++i)
#pragma unroll
    for (int j = 0; j < 4; ++j) acc[i][j] = 0.f;

  for (int k0 = 0; k0 < K; k0 += 16) {
    for (int l = tid; l < 1024; l += 256) {
      int r = l >> 4, kk = l & 15;
      int gk = k0 + kk;
      As[kk][r] = (gk < K) ? w2v[(size_t)(row0 + r) * 300 + gk] : 0.f;
    }
    for (int l = tid; l < 1024; l += 256) {
      int c = l & 63, kk = l >> 6;
      int gc = col0 + c, gk = k0 + kk;
      float v = 0.f;
      if (gk < K && gc < N) {
        if (gc < 600) v = Wel[(size_t)gk * 600 + gc];
        else          v = Wel[(size_t)(300 + gk) * 600 + (gc - 600)];
      }
      Bs[kk][c] = v;
    }
    __syncthreads();
#pragma unroll
    for (int kk = 0; kk < 16; ++kk) {
      float av[4], bv[4];
#pragma unroll
      for (int i = 0; i < 4; ++i) av[i] = As[kk][ty * 4 + i];
#pragma unroll
      for (int j = 0; j < 4; ++j) bv[j] = Bs[kk][tx * 4 + j];
#pragma unroll
      for (int i = 0; i < 4; ++i)
#pragma unroll
        for (int j = 0; j < 4; ++j) acc[i][j] = fmaf(av[i], bv[j], acc[i][j]);
    }
    __syncthreads();
  }
#pragma unroll
  for (int i = 0; i < 4; ++i) {
    int r = row0 + ty * 4 + i;
#pragma unroll
    for (int j = 0; j < 4; ++j) {
      int c = col0 + tx * 4 + j;
      if (c < N) Q[(size_t)r * 1200 + c] = f2b(acc[i][j]);
    }
  }
}

//---------------------------------------------------------------------
// Edge scores: thread t owns coalesced cols c = t+256j; weights hoisted.
//---------------------------------------------------------------------
__global__ __launch_bounds__(256)
void gnn6_edge_score(const int* __restrict__ src, const int* __restrict__ dst,
                     const float* __restrict__ s_f, const float* __restrict__ We,
                     const float* __restrict__ be, const float* __restrict__ Wa,
                     const float* __restrict__ ba, const float* __restrict__ bel,
                     const float* __restrict__ Wal, const float* __restrict__ bal,
                     const bf16* __restrict__ P, const bf16* __restrict__ Q,
                     float* __restrict__ af, float* __restrict__ afl)
{
  const int t = threadIdx.x;
  const int lane = t & 63, w = t >> 6;
  const int e0 = blockIdx.x * 8;

  float wef[16][4];
#pragma unroll
  for (int k = 0; k < 16; ++k)
#pragma unroll
    for (int j = 0; j < 4; ++j)
      wef[k][j] = We[(size_t)(1024 + k) * 1024 + t + 256 * j];

  float bev[4], wav[4];
#pragma unroll
  for (int j = 0; j < 4; ++j) {
    bev[j] = be[t + 256 * j];
    wav[j] = Wa[t + 256 * j];
  }
  float belv[3] = {0.f, 0.f, 0.f}, walv[3] = {0.f, 0.f, 0.f};
#pragma unroll
  for (int jj = 0; jj < 3; ++jj) {
    int c = t + 256 * jj;
    if (c < 600) { belv[jj] = bel[c]; walv[jj] = Wal[c]; }
  }
  const float ba0 = ba[0], bal0 = bal[0];

  __shared__ float shf[4], shl[4];

  for (int i = 0; i < 8; ++i) {
    const int e = e0 + i;
    const int s = src[e], d = dst[e];

    float sfv[16];
#pragma unroll
    for (int k = 0; k < 16; ++k) sfv[k] = s_f[(size_t)e * 16 + k];

    const bf16* P1 = P + (size_t)s * 2048;
    const bf16* P2 = P + (size_t)d * 2048 + 1024;
    float pf = 0.f;
#pragma unroll
    for (int j = 0; j < 4; ++j) {
      int c = t + 256 * j;
      float v = b2f(P1[c]) + b2f(P2[c]) + bev[j];
#pragma unroll
      for (int k = 0; k < 16; ++k) v = fmaf(sfv[k], wef[k][j], v);
      pf = fmaf(fmaxf(v, 0.f), wav[j], pf);
    }

    const bf16* Q1 = Q + (size_t)s * 1200;
    const bf16* Q2 = Q + (size_t)d * 1200 + 600;
    float pl = 0.f;
#pragma unroll
    for (int jj = 0; jj < 3; ++jj) {
      int c = t + 256 * jj;
      if (c < 600) {
        float v = b2f(Q1[c]) + b2f(Q2[c]) + belv[jj];
        pl = fmaf(fmaxf(v, 0.f), walv[jj], pl);
      }
    }

#pragma unroll
    for (int o = 32; o > 0; o >>= 1) {
      pf += __shfl_down(pf, o, 64);
      pl += __shfl_down(pl, o, 64);
    }
    if (lane == 0) { shf[w] = pf; shl[w] = pl; }
    __syncthreads();
    if (t == 0)  af[e]  = shf[0] + shf[1] + shf[2] + shf[3] + ba0;
    if (t == 64) afl[e] = shl[0] + shl[1] + shl[2] + shl[3] + bal0;
    __syncthreads();
  }
}

//---------------------------------------------------------------------
// CSR build
//---------------------------------------------------------------------
__global__ void gnn6_count(const int* __restrict__ dst, int* __restrict__ cnt)
{
  int e = blockIdx.x * blockDim.x + threadIdx.x;
  if (e < N_EDGES) atomicAdd(&cnt[dst[e]], 1);
}

__global__ __launch_bounds__(1024)
void gnn6_scan(const int* __restrict__ cnt, int* __restrict__ off, int* __restrict__ cur)
{
  __shared__ int sh[1024];
  const int t = threadIdx.x;
  int local[8]; int sum = 0;
#pragma unroll
  for (int i = 0; i < 8; ++i) { int v = cnt[t * 8 + i]; local[i] = sum; sum += v; }
  sh[t] = sum;
  __syncthreads();
  for (int d = 1; d < 1024; d <<= 1) {
    int v = (t >= d) ? sh[t - d] : 0;
    __syncthreads();
    sh[t] += v;
    __syncthreads();
  }
  int basev = (t > 0) ? sh[t - 1] : 0;
#pragma unroll
  for (int i = 0; i < 8; ++i) { int o = basev + local[i]; off[t * 8 + i] = o; cur[t * 8 + i] = o; }
  if (t == 1023) off[8192] = sh[1023];
}

__global__ void gnn6_fill(const int* __restrict__ dst, int* __restrict__ cur,
                          int* __restrict__ elist)
{
  int e = blockIdx.x * blockDim.x + threadIdx.x;
  if (e < N_EDGES) { int p = atomicAdd(&cur[dst[e]], 1); elist[p] = e; }
}

//---------------------------------------------------------------------
// Per-node softmax -> alpha written in place into af/afl.
//---------------------------------------------------------------------
__global__ __launch_bounds__(256)
void gnn6_alpha(const int* __restrict__ off, const int* __restrict__ elist,
                float* __restrict__ af, float* __restrict__ afl)
{
  const int n = blockIdx.x * 256 + threadIdx.x;
  if (n >= N_NODES) return;
  const int base = off[n];
  const int deg = off[n + 1] - base;
  float m = -1e30f, ml = -1e30f;
  for (int i = 0; i < deg; ++i) {
    int e = elist[base + i];
    m = fmaxf(m, af[e]);
    ml = fmaxf(ml, afl[e]);
  }
  float den = 0.f, denl = 0.f;
  for (int i = 0; i < deg; ++i) {
    int e = elist[base + i];
    den += expf(af[e] - m);
    denl += expf(afl[e] - ml);
  }
  float inv = (den > 0.f) ? 1.f / den : 0.f;
  float invl = (denl > 0.f) ? 1.f / denl : 0.f;
  for (int i = 0; i < deg; ++i) {
    int e = elist[base + i];
    af[e] = expf(af[e] - m) * inv;
    afl[e] = expf(afl[e] - ml) * invl;
  }
}

//---------------------------------------------------------------------
// Per-node accumulate; gathers in bf16 (nf_bf/w2v_bf), We3 in registers.
//---------------------------------------------------------------------
__global__ __launch_bounds__(256)
void gnn7_node_z(const int* __restrict__ off, const int* __restrict__ elist,
                 const int* __restrict__ src, const float* __restrict__ af,
                 const float* __restrict__ afl, const bf16* __restrict__ nf_bf,
                 const bf16* __restrict__ w2v_bf, const float* __restrict__ s_f,
                 const float* __restrict__ We, const float* __restrict__ be,
                 const bf16* __restrict__ P, bf16* __restrict__ zf,
                 bf16* __restrict__ zfl)
{
  const int node = blockIdx.x;
  const int t = threadIdx.x;
  const int base = off[node];
  const int deg = off[node + 1] - base;

  float wef[16][4];
#pragma unroll
  for (int k = 0; k < 16; ++k)
#pragma unroll
    for (int j = 0; j < 4; ++j)
      wef[k][j] = We[(size_t)(1024 + k) * 1024 + t + 256 * j];

  float p2[4];
#pragma unroll
  for (int j = 0; j < 4; ++j) {
    int c = t + 256 * j;
    p2[j] = b2f(P[(size_t)node * 2048 + 1024 + c]) + be[c];
  }
  float acc[4] = {0.f, 0.f, 0.f, 0.f};
  float accl0 = 0.f, accl1 = 0.f;
  const int cl0 = t, cl1 = t + 256;

  for (int i = 0; i < deg; ++i) {
    int e = elist[base + i];
    int s = src[e];
    float wgt = af[e];
    float wl = afl[e];
    float sfv[16];
#pragma unroll
    for (int k = 0; k < 16; ++k) sfv[k] = s_f[(size_t)e * 16 + k];
    const bf16* P1 = P + (size_t)s * 2048;
    const bf16* nfs = nf_bf + (size_t)s * 1024;
#pragma unroll
    for (int j = 0; j < 4; ++j) {
      int c = t + 256 * j;
      float ef = b2f(P1[c]) + p2[j];
#pragma unroll
      for (int k = 0; k < 16; ++k) ef = fmaf(sfv[k], wef[k][j], ef);
      ef = fmaxf(ef, 0.f);
      acc[j] = fmaf(wgt, b2f(nfs[c]) + ef, acc[j]);
    }
    if (cl0 < 300) accl0 = fmaf(wl, b2f(w2v_bf[(size_t)s * 300 + cl0]), accl0);
    if (cl1 < 300) accl1 = fmaf(wl, b2f(w2v_bf[(size_t)s * 300 + cl1]), accl1);
  }
#pragma unroll
  for (int j = 0; j < 4; ++j) zf[(size_t)node * 1024 + t + 256 * j] = f2b(acc[j]);
  if (cl0 < 300) zfl[(size_t)node * 300 + cl0] = f2b(accl0);
  if (cl1 < 300) zfl[(size_t)node * 300 + cl1] = f2b(accl1);
}

//---------------------------------------------------------------------
// VALU GEMM: out1[8192,300](f32) = relu([w2v | zfl] @ Wnl + bnl), K=600
//---------------------------------------------------------------------
__global__ __launch_bounds__(256)
void gnn6_gemm_out_l(const float* __restrict__ w2v, const bf16* __restrict__ zfl,
                     const float* __restrict__ Wnl, const float* __restrict__ bnl,
                     float* __restrict__ out2)
{
  __shared__ float As[16][68];
  __shared__ float Bs[16][68];
  const int tid = threadIdx.x;
  const int tx = tid & 15, ty = tid >> 4;
  const int row0 = blockIdx.y * 64, col0 = blockIdx.x * 64;
  const int K = 600, N = 300;

  float acc[4][4];
#pragma unroll
  for (int i = 0; i < 4; ++i)
#pragma unroll
    for (int j = 0; j < 4; ++j) acc[i][j] = 0.f;

  for (int k0 = 0; k0 < K; k0 += 16) {
    for (int l = tid; l < 1024; l += 256) {
      int r = l >> 4, kk = l & 15;
      int gr = row0 + r, gk = k0 + kk;
      float v = 0.f;
      if (gk < 300)      v = w2v[(size_t)gr * 300 + gk];
      else if (gk < 600) v = b2f(zfl[(size_t)gr * 300 + (gk - 300)]);
      As[kk][r] = v;
    }
    for (int l = tid; l < 1024; l += 256) {
      int c = l & 63, kk = l >> 6;
      int gc = col0 + c, gk = k0 + kk;
      Bs[kk][c] = (gk < K && gc < N) ? Wnl[(size_t)gk * 300 + gc] : 0.f;
    }
    __syncthreads();
#pragma unroll
    for (int kk = 0; kk < 16; ++kk) {
      float av[4], bv[4];
#pragma unroll
      for (int i = 0; i < 4; ++i) av[i] = As[kk][ty * 4 + i];
#pragma unroll
      for (int j = 0; j < 4; ++j) bv[j] = Bs[kk][tx * 4 + j];
#pragma unroll
      for (int i = 0; i < 4; ++i)
#pragma unroll
        for (int j = 0; j < 4; ++j) acc[i][j] = fmaf(av[i], bv[j], acc[i][j]);
    }
    __syncthreads();
  }
#pragma unroll
  for (int i = 0; i < 4; ++i) {
    int r = row0 + ty * 4 + i;
#pragma unroll
    for (int j = 0; j < 4; ++j) {
      int c = col0 + tx * 4 + j;
      if (c < N) {
        float v = acc[i][j] + bnl[c];
        out2[(size_t)r * 300 + c] = fmaxf(v, 0.f);
      }
    }
  }
}

//=====================================================================
extern "C" void kernel_launch(void* const* d_in, const int* in_sizes, int n_in,
                              void* d_out, int out_size, void* d_ws, size_t ws_size,
                              hipStream_t stream)
{
  (void)hipGetLastError();
  if (n_in != 17) { hipMemsetAsync(d_out, 0x41, 4096, stream); return; }

  const float* n_f = (const float*)d_in[0];
  const float* w2v = (const float*)d_in[1];
  const float* s_f = (const float*)d_in[2];
  const int*   src = (const int*)d_in[3];
  const int*   dst = (const int*)d_in[4];
  const float* We  = (const float*)d_in[5];
  const float* be  = (const float*)d_in[6];
  const float* Wel = (const float*)d_in[7];
  const float* bel = (const float*)d_in[8];
  const float* Wa  = (const float*)d_in[9];
  const float* ba  = (const float*)d_in[10];
  const float* Wal = (const float*)d_in[11];
  const float* bal = (const float*)d_in[12];
  const float* Wn  = (const float*)d_in[13];
  const float* bn  = (const float*)d_in[14];
  const float* Wnl = (const float*)d_in[15];
  const float* bnl = (const float*)d_in[16];
  float* out  = (float*)d_out;
  float* out2 = out + OUT0_ELEMS;

  char* ws = (char*)d_ws;
  size_t o = 0;
  auto alloc = [&](size_t bytes) -> void* {
    void* p = ws + o; o += bytes; o = (o + 255) & ~(size_t)255; return p;
  };
  bf16* P      = (bf16*)alloc((size_t)N_NODES * 2048 * 2);
  bf16* Q      = (bf16*)alloc((size_t)N_NODES * 1200 * 2);
  bf16* zf     = (bf16*)alloc((size_t)N_NODES * 1024 * 2);
  bf16* zfl    = (bf16*)alloc((size_t)N_NODES * 300 * 2);
  bf16* nf_bf  = (bf16*)alloc((size_t)N_NODES * 1024 * 2);
  bf16* w2v_bf = (bf16*)alloc((size_t)N_NODES * 300 * 2);
  float* af    = (float*)alloc((size_t)N_EDGES * 4);
  float* afl   = (float*)alloc((size_t)N_EDGES * 4);
  int* cnt     = (int*)alloc((size_t)N_NODES * 4);
  int* offs    = (int*)alloc((size_t)(N_NODES + 1) * 4);
  int* cur     = (int*)alloc((size_t)N_NODES * 4);
  int* elist   = (int*)alloc((size_t)N_EDGES * 4);
  if (o > ws_size) { hipMemsetAsync(d_out, 0x42, 4096, stream); return; }

  gnn6_zero<<<N_NODES / 256, 256, 0, stream>>>(cnt, N_NODES);
  gnn7_cvt<<<(N_NODES * 1024 / 8 + 255) / 256, 256, 0, stream>>>(n_f, nf_bf,
                                                                 N_NODES * 1024 / 8);
  gnn7_cvt<<<(N_NODES * 300 / 8 + 255) / 256, 256, 0, stream>>>(w2v, w2v_bf,
                                                                N_NODES * 300 / 8);

  {
    dim3 g(2048 / 128, N_NODES / 128);
    gnn7_mm_P<<<g, 256, 0, stream>>>(nf_bf, We, P);
  }
  {
    dim3 g((1200 + 63) / 64, N_NODES / 64);
    gnn6_gemm_Q<<<g, 256, 0, stream>>>(w2v, Wel, Q);
  }

  gnn6_edge_score<<<N_EDGES / 8, 256, 0, stream>>>(src, dst, s_f, We, be, Wa, ba,
                                                   bel, Wal, bal, P, Q, af, afl);

  gnn6_count<<<N_EDGES / 256, 256, 0, stream>>>(dst, cnt);
  gnn6_scan<<<1, 1024, 0, stream>>>(cnt, offs, cur);
  gnn6_fill<<<N_EDGES / 256, 256, 0, stream>>>(dst, cur, elist);
  gnn6_alpha<<<N_NODES / 256, 256, 0, stream>>>(offs, elist, af, afl);

  gnn7_node_z<<<N_NODES, 256, 0, stream>>>(offs, elist, src, af, afl, nf_bf,
                                           w2v_bf, s_f, We, be, P, zf, zfl);

  {
    dim3 g(1024 / 128, N_NODES / 128);
    gnn7_mm_out_n<<<g, 256, 0, stream>>>(nf_bf, zf, Wn, bn, out);
  }
  {
    dim3 g((300 + 63) / 64, N_NODES / 64);
    gnn6_gemm_out_l<<<g, 256, 0, stream>>>(w2v, zfl, Wnl, bnl, out2);
  }

  if (hipGetLastError() != hipSuccess) hipMemsetAsync(d_out, 0x44, 4096, stream);
}

// Round 8
// 612.239 us; speedup vs baseline: 5.0595x; 1.3783x over previous
//
#include <hip/hip_runtime.h>
#include <hip/hip_bf16.h>

#define N_NODES 8192
#define N_EDGES 65536
#define OUT0_ELEMS ((size_t)N_NODES * 1024)

using bf16 = __hip_bfloat16;
typedef __attribute__((ext_vector_type(8))) short short8;
typedef __attribute__((ext_vector_type(4))) float f32x4;

__device__ __forceinline__ float b2f(bf16 x) { return __bfloat162float(x); }
__device__ __forceinline__ bf16 f2b(float x) { return __float2bfloat16(x); }
__device__ __forceinline__ unsigned short bbits(float x)
{
  union { bf16 h; unsigned short u; } v; v.h = f2b(x); return v.u;
}
__device__ __forceinline__ unsigned pack2(float a, float b)
{
  return (unsigned)bbits(a) | ((unsigned)bbits(b) << 16);
}

// Kept so any harness-side reference to the stub symbol still resolves.
__global__ void GNN_27650999451833_kernel() {}

__global__ void gnn6_zero(int* __restrict__ p, int n)
{
  int i = blockIdx.x * blockDim.x + threadIdx.x;
  if (i < n) p[i] = 0;
}

//---------------------------------------------------------------------
// f32 -> bf16 bulk convert (8 elems/thread), for n_f (stride 1024)
//---------------------------------------------------------------------
__global__ __launch_bounds__(256)
void gnn7_cvt(const float* __restrict__ src, bf16* __restrict__ dst, int n8)
{
  int i = blockIdx.x * blockDim.x + threadIdx.x;
  if (i < n8) {
    float4 a = ((const float4*)src)[2 * i];
    float4 b = ((const float4*)src)[2 * i + 1];
    uint4 p;
    p.x = pack2(a.x, a.y); p.y = pack2(a.z, a.w);
    p.z = pack2(b.x, b.y); p.w = pack2(b.z, b.w);
    ((uint4*)dst)[i] = p;
  }
}

//---------------------------------------------------------------------
// w2v[8192,300](f32) -> w2v_pad[8192,320](bf16, cols>=300 zero)
// 4 cols per thread
//---------------------------------------------------------------------
__global__ __launch_bounds__(256)
void gnn8_pad_w2v(const float* __restrict__ src, bf16* __restrict__ dst)
{
  int idx = blockIdx.x * blockDim.x + threadIdx.x;   // 8192*80
  if (idx >= N_NODES * 80) return;
  int r = idx / 80, c0 = (idx % 80) * 4;
  float v[4];
#pragma unroll
  for (int j = 0; j < 4; ++j) {
    int c = c0 + j;
    v[j] = (c < 300) ? src[(size_t)r * 300 + c] : 0.f;
  }
  uint2 p; p.x = pack2(v[0], v[1]); p.y = pack2(v[2], v[3]);
  *(uint2*)(dst + (size_t)r * 320 + c0) = p;
}

//---------------------------------------------------------------------
// Wel[600,600](f32) -> Wel_pad[320,1280](bf16):
//   row k<300: c<600 -> Wel[k,c]; 600<=c<1200 -> Wel[300+k,c-600]; else 0
//---------------------------------------------------------------------
__global__ __launch_bounds__(256)
void gnn8_pad_Wel(const float* __restrict__ src, bf16* __restrict__ dst)
{
  int idx = blockIdx.x * blockDim.x + threadIdx.x;   // 320*320 quads
  if (idx >= 320 * 320) return;
  int k = idx / 320, c0 = (idx % 320) * 4;
  float v[4];
#pragma unroll
  for (int j = 0; j < 4; ++j) {
    int c = c0 + j;
    float x = 0.f;
    if (k < 300) {
      if (c < 600)       x = src[(size_t)k * 600 + c];
      else if (c < 1200) x = src[(size_t)(300 + k) * 600 + (c - 600)];
    }
    v[j] = x;
  }
  uint2 p; p.x = pack2(v[0], v[1]); p.y = pack2(v[2], v[3]);
  *(uint2*)(dst + (size_t)k * 1280 + c0) = p;
}

//---------------------------------------------------------------------
// Wnl[600,300](f32) -> Wnl_pad[640,384](bf16):
//   k<300 -> Wnl[k]; 320<=k<620 -> Wnl[k-20]; else 0; c>=300 -> 0
//---------------------------------------------------------------------
__global__ __launch_bounds__(256)
void gnn8_pad_Wnl(const float* __restrict__ src, bf16* __restrict__ dst)
{
  int idx = blockIdx.x * blockDim.x + threadIdx.x;   // 640*96 quads
  if (idx >= 640 * 96) return;
  int k = idx / 96, c0 = (idx % 96) * 4;
  int kr = -1;
  if (k < 300) kr = k;
  else if (k >= 320 && k < 620) kr = k - 20;
  float v[4];
#pragma unroll
  for (int j = 0; j < 4; ++j) {
    int c = c0 + j;
    v[j] = (kr >= 0 && c < 300) ? src[(size_t)kr * 300 + c] : 0.f;
  }
  uint2 p; p.x = pack2(v[0], v[1]); p.y = pack2(v[2], v[3]);
  *(uint2*)(dst + (size_t)k * 384 + c0) = p;
}

//---------------------------------------------------------------------
// MFMA GEMM 1: P[8192,2048](bf16) = nf_bf @ [We[0:1024]|We[1040:2064]](f32)
// 128x128 tile, BK=32, 4 waves (2x2), register prefetch. (proven R7)
//---------------------------------------------------------------------
__global__ __launch_bounds__(256)
void gnn7_mm_P(const bf16* __restrict__ A, const float* __restrict__ We,
               bf16* __restrict__ P)
{
  __shared__ short As[128 * 40];
  __shared__ short Bs[128 * 40];
  const int t = threadIdx.x;
  const int col0 = blockIdx.x * 128, row0 = blockIdx.y * 128;
  const int lane = t & 63, w = t >> 6, m16 = lane & 15, q = lane >> 4;
  const int wr = w >> 1, wc = w & 1;

  f32x4 acc[4][4];
#pragma unroll
  for (int mi = 0; mi < 4; ++mi)
#pragma unroll
    for (int ni = 0; ni < 4; ++ni) acc[mi][ni] = (f32x4){0.f, 0.f, 0.f, 0.f};

  const int ar = t >> 1, ah = (t & 1) * 16;
  const int bk = t & 31, bn0 = (t >> 5) * 16;

  const bf16* aptr = A + (size_t)(row0 + ar) * 1024 + ah;
  const float* bptr = (col0 < 1024)
      ? (We + (size_t)bk * 1024 + col0 + bn0)
      : (We + (size_t)(1040 + bk) * 1024 + (col0 - 1024) + bn0);

  uint4 a0 = *(const uint4*)(aptr);
  uint4 a1 = *(const uint4*)(aptr + 8);
  float4 b0 = *(const float4*)(bptr);
  float4 b1 = *(const float4*)(bptr + 4);
  float4 b2 = *(const float4*)(bptr + 8);
  float4 b3 = *(const float4*)(bptr + 12);

  for (int k0 = 0; k0 < 1024; k0 += 32) {
    if (k0) __syncthreads();
    *(uint4*)&As[ar * 40 + ah] = a0;
    *(uint4*)&As[ar * 40 + ah + 8] = a1;
    {
      short* brow = &Bs[bn0 * 40 + bk];
      brow[0 * 40] = (short)bbits(b0.x);  brow[1 * 40] = (short)bbits(b0.y);
      brow[2 * 40] = (short)bbits(b0.z);  brow[3 * 40] = (short)bbits(b0.w);
      brow[4 * 40] = (short)bbits(b1.x);  brow[5 * 40] = (short)bbits(b1.y);
      brow[6 * 40] = (short)bbits(b1.z);  brow[7 * 40] = (short)bbits(b1.w);
      brow[8 * 40] = (short)bbits(b2.x);  brow[9 * 40] = (short)bbits(b2.y);
      brow[10 * 40] = (short)bbits(b2.z); brow[11 * 40] = (short)bbits(b2.w);
      brow[12 * 40] = (short)bbits(b3.x); brow[13 * 40] = (short)bbits(b3.y);
      brow[14 * 40] = (short)bbits(b3.z); brow[15 * 40] = (short)bbits(b3.w);
    }
    __syncthreads();
    if (k0 + 32 < 1024) {
      a0 = *(const uint4*)(aptr + k0 + 32);
      a1 = *(const uint4*)(aptr + k0 + 40);
      const float* bp = bptr + (size_t)(k0 + 32) * 1024;
      b0 = *(const float4*)(bp);
      b1 = *(const float4*)(bp + 4);
      b2 = *(const float4*)(bp + 8);
      b3 = *(const float4*)(bp + 12);
    }
    short8 af[4];
#pragma unroll
    for (int mi = 0; mi < 4; ++mi)
      af[mi] = *(const short8*)&As[(wr * 64 + mi * 16 + m16) * 40 + 8 * q];
#pragma unroll
    for (int ni = 0; ni < 4; ++ni) {
      short8 bfv = *(const short8*)&Bs[(wc * 64 + ni * 16 + m16) * 40 + 8 * q];
#pragma unroll
      for (int mi = 0; mi < 4; ++mi)
        acc[mi][ni] =
            __builtin_amdgcn_mfma_f32_16x16x32_bf16(af[mi], bfv, acc[mi][ni], 0, 0, 0);
    }
  }
#pragma unroll
  for (int mi = 0; mi < 4; ++mi)
#pragma unroll
    for (int ni = 0; ni < 4; ++ni) {
      int c = col0 + wc * 64 + ni * 16 + m16;
#pragma unroll
      for (int r = 0; r < 4; ++r)
        P[(size_t)(row0 + wr * 64 + mi * 16 + 4 * q + r) * 2048 + c] =
            f2b(acc[mi][ni][r]);
    }
}

//---------------------------------------------------------------------
// MFMA GEMM 2: out0[8192,1024](f32) = relu([nf_bf | zf](bf16) @ Wn(f32) + bn)
//---------------------------------------------------------------------
__global__ __launch_bounds__(256)
void gnn7_mm_out_n(const bf16* __restrict__ nf_bf, const bf16* __restrict__ zf,
                   const float* __restrict__ Wn, const float* __restrict__ bn,
                   float* __restrict__ out)
{
  __shared__ short As[128 * 40];
  __shared__ short Bs[128 * 40];
  const int t = threadIdx.x;
  const int col0 = blockIdx.x * 128, row0 = blockIdx.y * 128;
  const int lane = t & 63, w = t >> 6, m16 = lane & 15, q = lane >> 4;
  const int wr = w >> 1, wc = w & 1;

  f32x4 acc[4][4];
#pragma unroll
  for (int mi = 0; mi < 4; ++mi)
#pragma unroll
    for (int ni = 0; ni < 4; ++ni) acc[mi][ni] = (f32x4){0.f, 0.f, 0.f, 0.f};

  const int ar = t >> 1, ah = (t & 1) * 16;
  const int bk = t & 31, bn0 = (t >> 5) * 16;

  const bf16* ap0 = nf_bf + (size_t)(row0 + ar) * 1024 + ah;
  const bf16* ap1 = zf + (size_t)(row0 + ar) * 1024 + ah;
  const float* bptr = Wn + (size_t)bk * 1024 + col0 + bn0;

  uint4 a0 = *(const uint4*)(ap0);
  uint4 a1 = *(const uint4*)(ap0 + 8);
  float4 b0 = *(const float4*)(bptr);
  float4 b1 = *(const float4*)(bptr + 4);
  float4 b2 = *(const float4*)(bptr + 8);
  float4 b3 = *(const float4*)(bptr + 12);

  for (int k0 = 0; k0 < 2048; k0 += 32) {
    if (k0) __syncthreads();
    *(uint4*)&As[ar * 40 + ah] = a0;
    *(uint4*)&As[ar * 40 + ah + 8] = a1;
    {
      short* brow = &Bs[bn0 * 40 + bk];
      brow[0 * 40] = (short)bbits(b0.x);  brow[1 * 40] = (short)bbits(b0.y);
      brow[2 * 40] = (short)bbits(b0.z);  brow[3 * 40] = (short)bbits(b0.w);
      brow[4 * 40] = (short)bbits(b1.x);  brow[5 * 40] = (short)bbits(b1.y);
      brow[6 * 40] = (short)bbits(b1.z);  brow[7 * 40] = (short)bbits(b1.w);
      brow[8 * 40] = (short)bbits(b2.x);  brow[9 * 40] = (short)bbits(b2.y);
      brow[10 * 40] = (short)bbits(b2.z); brow[11 * 40] = (short)bbits(b2.w);
      brow[12 * 40] = (short)bbits(b3.x); brow[13 * 40] = (short)bbits(b3.y);
      brow[14 * 40] = (short)bbits(b3.z); brow[15 * 40] = (short)bbits(b3.w);
    }
    __syncthreads();
    if (k0 + 32 < 2048) {
      int kn = k0 + 32;
      if (kn + ah < 1024) {
        a0 = *(const uint4*)(ap0 + kn);
        a1 = *(const uint4*)(ap0 + kn + 8);
      } else {
        a0 = *(const uint4*)(ap1 + (kn - 1024));
        a1 = *(const uint4*)(ap1 + (kn - 1024) + 8);
      }
      const float* bp = bptr + (size_t)kn * 1024;
      b0 = *(const float4*)(bp);
      b1 = *(const float4*)(bp + 4);
      b2 = *(const float4*)(bp + 8);
      b3 = *(const float4*)(bp + 12);
    }
    short8 af[4];
#pragma unroll
    for (int mi = 0; mi < 4; ++mi)
      af[mi] = *(const short8*)&As[(wr * 64 + mi * 16 + m16) * 40 + 8 * q];
#pragma unroll
    for (int ni = 0; ni < 4; ++ni) {
      short8 bfv = *(const short8*)&Bs[(wc * 64 + ni * 16 + m16) * 40 + 8 * q];
#pragma unroll
      for (int mi = 0; mi < 4; ++mi)
        acc[mi][ni] =
            __builtin_amdgcn_mfma_f32_16x16x32_bf16(af[mi], bfv, acc[mi][ni], 0, 0, 0);
    }
  }
#pragma unroll
  for (int mi = 0; mi < 4; ++mi)
#pragma unroll
    for (int ni = 0; ni < 4; ++ni) {
      int c = col0 + wc * 64 + ni * 16 + m16;
      float bias = bn[c];
#pragma unroll
      for (int r = 0; r < 4; ++r) {
        float v = acc[mi][ni][r] + bias;
        out[(size_t)(row0 + wr * 64 + mi * 16 + 4 * q + r) * 1024 + c] =
            fmaxf(v, 0.f);
      }
    }
}

//---------------------------------------------------------------------
// MFMA GEMM Q: Q[8192,1280](bf16) = w2v_pad[8192,320] @ Wel_pad[320,1280]
// All-bf16, fully padded -> no guards.
//---------------------------------------------------------------------
__global__ __launch_bounds__(256)
void gnn8_mm_Q(const bf16* __restrict__ A, const bf16* __restrict__ B,
               bf16* __restrict__ Q)
{
  __shared__ short As[128 * 40];
  __shared__ short Bs[128 * 40];
  const int t = threadIdx.x;
  const int col0 = blockIdx.x * 128, row0 = blockIdx.y * 128;
  const int lane = t & 63, w = t >> 6, m16 = lane & 15, q = lane >> 4;
  const int wr = w >> 1, wc = w & 1;

  f32x4 acc[4][4];
#pragma unroll
  for (int mi = 0; mi < 4; ++mi)
#pragma unroll
    for (int ni = 0; ni < 4; ++ni) acc[mi][ni] = (f32x4){0.f, 0.f, 0.f, 0.f};

  const int ar = t >> 1, ah = (t & 1) * 16;
  const int bk = t & 31, bn0 = (t >> 5) * 16;

  const bf16* aptr = A + (size_t)(row0 + ar) * 320 + ah;
  const bf16* bptr = B + (size_t)bk * 1280 + col0 + bn0;

  uint4 a0 = *(const uint4*)(aptr);
  uint4 a1 = *(const uint4*)(aptr + 8);
  uint4 b0 = *(const uint4*)(bptr);
  uint4 b1 = *(const uint4*)(bptr + 8);

  for (int k0 = 0; k0 < 320; k0 += 32) {
    if (k0) __syncthreads();
    *(uint4*)&As[ar * 40 + ah] = a0;
    *(uint4*)&As[ar * 40 + ah + 8] = a1;
    {
      const short* bs0 = (const short*)&b0;
      const short* bs1 = (const short*)&b1;
      short* brow = &Bs[bn0 * 40 + bk];
#pragma unroll
      for (int j = 0; j < 8; ++j) brow[j * 40] = bs0[j];
#pragma unroll
      for (int j = 0; j < 8; ++j) brow[(8 + j) * 40] = bs1[j];
    }
    __syncthreads();
    if (k0 + 32 < 320) {
      a0 = *(const uint4*)(aptr + k0 + 32);
      a1 = *(const uint4*)(aptr + k0 + 40);
      const bf16* bp = bptr + (size_t)(k0 + 32) * 1280;
      b0 = *(const uint4*)(bp);
      b1 = *(const uint4*)(bp + 8);
    }
    short8 af[4];
#pragma unroll
    for (int mi = 0; mi < 4; ++mi)
      af[mi] = *(const short8*)&As[(wr * 64 + mi * 16 + m16) * 40 + 8 * q];
#pragma unroll
    for (int ni = 0; ni < 4; ++ni) {
      short8 bfv = *(const short8*)&Bs[(wc * 64 + ni * 16 + m16) * 40 + 8 * q];
#pragma unroll
      for (int mi = 0; mi < 4; ++mi)
        acc[mi][ni] =
            __builtin_amdgcn_mfma_f32_16x16x32_bf16(af[mi], bfv, acc[mi][ni], 0, 0, 0);
    }
  }
#pragma unroll
  for (int mi = 0; mi < 4; ++mi)
#pragma unroll
    for (int ni = 0; ni < 4; ++ni) {
      int c = col0 + wc * 64 + ni * 16 + m16;
#pragma unroll
      for (int r = 0; r < 4; ++r)
        Q[(size_t)(row0 + wr * 64 + mi * 16 + 4 * q + r) * 1280 + c] =
            f2b(acc[mi][ni][r]);
    }
}

//---------------------------------------------------------------------
// MFMA GEMM out_l: out1[8192,300](f32) =
//   relu([w2v_pad | zfl_pad](K=640) @ Wnl_pad[640,384] + bnl), store c<300
//---------------------------------------------------------------------
__global__ __launch_bounds__(256)
void gnn8_mm_out_l(const bf16* __restrict__ A0, const bf16* __restrict__ A1,
                   const bf16* __restrict__ B, const float* __restrict__ bnl,
                   float* __restrict__ out2)
{
  __shared__ short As[128 * 40];
  __shared__ short Bs[128 * 40];
  const int t = threadIdx.x;
  const int col0 = blockIdx.x * 128, row0 = blockIdx.y * 128;
  const int lane = t & 63, w = t >> 6, m16 = lane & 15, q = lane >> 4;
  const int wr = w >> 1, wc = w & 1;

  f32x4 acc[4][4];
#pragma unroll
  for (int mi = 0; mi < 4; ++mi)
#pragma unroll
    for (int ni = 0; ni < 4; ++ni) acc[mi][ni] = (f32x4){0.f, 0.f, 0.f, 0.f};

  const int ar = t >> 1, ah = (t & 1) * 16;
  const int bk = t & 31, bn0 = (t >> 5) * 16;

  const bf16* ap0 = A0 + (size_t)(row0 + ar) * 320 + ah;
  const bf16* ap1 = A1 + (size_t)(row0 + ar) * 320 + ah;
  const bf16* bptr = B + (size_t)bk * 384 + col0 + bn0;

  uint4 a0 = *(const uint4*)(ap0);
  uint4 a1 = *(const uint4*)(ap0 + 8);
  uint4 b0 = *(const uint4*)(bptr);
  uint4 b1 = *(const uint4*)(bptr + 8);

  for (int k0 = 0; k0 < 640; k0 += 32) {
    if (k0) __syncthreads();
    *(uint4*)&As[ar * 40 + ah] = a0;
    *(uint4*)&As[ar * 40 + ah + 8] = a1;
    {
      const short* bs0 = (const short*)&b0;
      const short* bs1 = (const short*)&b1;
      short* brow = &Bs[bn0 * 40 + bk];
#pragma unroll
      for (int j = 0; j < 8; ++j) brow[j * 40] = bs0[j];
#pragma unroll
      for (int j = 0; j < 8; ++j) brow[(8 + j) * 40] = bs1[j];
    }
    __syncthreads();
    if (k0 + 32 < 640) {
      int kn = k0 + 32;
      const bf16* ap = (kn < 320) ? (ap0 + kn) : (ap1 + (kn - 320));
      a0 = *(const uint4*)(ap);
      a1 = *(const uint4*)(ap + 8);
      const bf16* bp = bptr + (size_t)kn * 384;
      b0 = *(const uint4*)(bp);
      b1 = *(const uint4*)(bp + 8);
    }
    short8 af[4];
#pragma unroll
    for (int mi = 0; mi < 4; ++mi)
      af[mi] = *(const short8*)&As[(wr * 64 + mi * 16 + m16) * 40 + 8 * q];
#pragma unroll
    for (int ni = 0; ni < 4; ++ni) {
      short8 bfv = *(const short8*)&Bs[(wc * 64 + ni * 16 + m16) * 40 + 8 * q];
#pragma unroll
      for (int mi = 0; mi < 4; ++mi)
        acc[mi][ni] =
            __builtin_amdgcn_mfma_f32_16x16x32_bf16(af[mi], bfv, acc[mi][ni], 0, 0, 0);
    }
  }
#pragma unroll
  for (int mi = 0; mi < 4; ++mi)
#pragma unroll
    for (int ni = 0; ni < 4; ++ni) {
      int c = col0 + wc * 64 + ni * 16 + m16;
      if (c < 300) {
        float bias = bnl[c];
#pragma unroll
        for (int r = 0; r < 4; ++r) {
          float v = acc[mi][ni][r] + bias;
          out2[(size_t)(row0 + wr * 64 + mi * 16 + 4 * q + r) * 300 + c] =
              fmaxf(v, 0.f);
        }
      }
    }
}

//---------------------------------------------------------------------
// Edge scores: thread t owns coalesced cols c = t+256j; weights hoisted.
// Q stride is now 1280.
//---------------------------------------------------------------------
__global__ __launch_bounds__(256)
void gnn8_edge_score(const int* __restrict__ src, const int* __restrict__ dst,
                     const float* __restrict__ s_f, const float* __restrict__ We,
                     const float* __restrict__ be, const float* __restrict__ Wa,
                     const float* __restrict__ ba, const float* __restrict__ bel,
                     const float* __restrict__ Wal, const float* __restrict__ bal,
                     const bf16* __restrict__ P, const bf16* __restrict__ Q,
                     float* __restrict__ af, float* __restrict__ afl)
{
  const int t = threadIdx.x;
  const int lane = t & 63, w = t >> 6;
  const int e0 = blockIdx.x * 8;

  float wef[16][4];
#pragma unroll
  for (int k = 0; k < 16; ++k)
#pragma unroll
    for (int j = 0; j < 4; ++j)
      wef[k][j] = We[(size_t)(1024 + k) * 1024 + t + 256 * j];

  float bev[4], wav[4];
#pragma unroll
  for (int j = 0; j < 4; ++j) {
    bev[j] = be[t + 256 * j];
    wav[j] = Wa[t + 256 * j];
  }
  float belv[3] = {0.f, 0.f, 0.f}, walv[3] = {0.f, 0.f, 0.f};
#pragma unroll
  for (int jj = 0; jj < 3; ++jj) {
    int c = t + 256 * jj;
    if (c < 600) { belv[jj] = bel[c]; walv[jj] = Wal[c]; }
  }
  const float ba0 = ba[0], bal0 = bal[0];

  __shared__ float shf[4], shl[4];

  for (int i = 0; i < 8; ++i) {
    const int e = e0 + i;
    const int s = src[e], d = dst[e];

    float sfv[16];
#pragma unroll
    for (int k = 0; k < 16; ++k) sfv[k] = s_f[(size_t)e * 16 + k];

    const bf16* P1 = P + (size_t)s * 2048;
    const bf16* P2 = P + (size_t)d * 2048 + 1024;
    float pf = 0.f;
#pragma unroll
    for (int j = 0; j < 4; ++j) {
      int c = t + 256 * j;
      float v = b2f(P1[c]) + b2f(P2[c]) + bev[j];
#pragma unroll
      for (int k = 0; k < 16; ++k) v = fmaf(sfv[k], wef[k][j], v);
      pf = fmaf(fmaxf(v, 0.f), wav[j], pf);
    }

    const bf16* Q1 = Q + (size_t)s * 1280;
    const bf16* Q2 = Q + (size_t)d * 1280 + 600;
    float pl = 0.f;
#pragma unroll
    for (int jj = 0; jj < 3; ++jj) {
      int c = t + 256 * jj;
      if (c < 600) {
        float v = b2f(Q1[c]) + b2f(Q2[c]) + belv[jj];
        pl = fmaf(fmaxf(v, 0.f), walv[jj], pl);
      }
    }

#pragma unroll
    for (int o = 32; o > 0; o >>= 1) {
      pf += __shfl_down(pf, o, 64);
      pl += __shfl_down(pl, o, 64);
    }
    if (lane == 0) { shf[w] = pf; shl[w] = pl; }
    __syncthreads();
    if (t == 0)  af[e]  = shf[0] + shf[1] + shf[2] + shf[3] + ba0;
    if (t == 64) afl[e] = shl[0] + shl[1] + shl[2] + shl[3] + bal0;
    __syncthreads();
  }
}

//---------------------------------------------------------------------
// CSR build
//---------------------------------------------------------------------
__global__ void gnn6_count(const int* __restrict__ dst, int* __restrict__ cnt)
{
  int e = blockIdx.x * blockDim.x + threadIdx.x;
  if (e < N_EDGES) atomicAdd(&cnt[dst[e]], 1);
}

__global__ __launch_bounds__(1024)
void gnn6_scan(const int* __restrict__ cnt, int* __restrict__ off, int* __restrict__ cur)
{
  __shared__ int sh[1024];
  const int t = threadIdx.x;
  int local[8]; int sum = 0;
#pragma unroll
  for (int i = 0; i < 8; ++i) { int v = cnt[t * 8 + i]; local[i] = sum; sum += v; }
  sh[t] = sum;
  __syncthreads();
  for (int d = 1; d < 1024; d <<= 1) {
    int v = (t >= d) ? sh[t - d] : 0;
    __syncthreads();
    sh[t] += v;
    __syncthreads();
  }
  int basev = (t > 0) ? sh[t - 1] : 0;
#pragma unroll
  for (int i = 0; i < 8; ++i) { int o = basev + local[i]; off[t * 8 + i] = o; cur[t * 8 + i] = o; }
  if (t == 1023) off[8192] = sh[1023];
}

__global__ void gnn6_fill(const int* __restrict__ dst, int* __restrict__ cur,
                          int* __restrict__ elist)
{
  int e = blockIdx.x * blockDim.x + threadIdx.x;
  if (e < N_EDGES) { int p = atomicAdd(&cur[dst[e]], 1); elist[p] = e; }
}

//---------------------------------------------------------------------
// Per-node softmax -> alpha written in place into af/afl.
//---------------------------------------------------------------------
__global__ __launch_bounds__(256)
void gnn6_alpha(const int* __restrict__ off, const int* __restrict__ elist,
                float* __restrict__ af, float* __restrict__ afl)
{
  const int n = blockIdx.x * 256 + threadIdx.x;
  if (n >= N_NODES) return;
  const int base = off[n];
  const int deg = off[n + 1] - base;
  float m = -1e30f, ml = -1e30f;
  for (int i = 0; i < deg; ++i) {
    int e = elist[base + i];
    m = fmaxf(m, af[e]);
    ml = fmaxf(ml, afl[e]);
  }
  float den = 0.f, denl = 0.f;
  for (int i = 0; i < deg; ++i) {
    int e = elist[base + i];
    den += expf(af[e] - m);
    denl += expf(afl[e] - ml);
  }
  float inv = (den > 0.f) ? 1.f / den : 0.f;
  float invl = (denl > 0.f) ? 1.f / denl : 0.f;
  for (int i = 0; i < deg; ++i) {
    int e = elist[base + i];
    af[e] = expf(af[e] - m) * inv;
    afl[e] = expf(afl[e] - ml) * invl;
  }
}

//---------------------------------------------------------------------
// Per-node accumulate; bf16 gathers; zfl_pad stride 320 with zeroed pad.
//---------------------------------------------------------------------
__global__ __launch_bounds__(256)
void gnn8_node_z(const int* __restrict__ off, const int* __restrict__ elist,
                 const int* __restrict__ src, const float* __restrict__ af,
                 const float* __restrict__ afl, const bf16* __restrict__ nf_bf,
                 const bf16* __restrict__ w2v_pad, const float* __restrict__ s_f,
                 const float* __restrict__ We, const float* __restrict__ be,
                 const bf16* __restrict__ P, bf16* __restrict__ zf,
                 bf16* __restrict__ zfl_pad)
{
  const int node = blockIdx.x;
  const int t = threadIdx.x;
  const int base = off[node];
  const int deg = off[node + 1] - base;

  float wef[16][4];
#pragma unroll
  for (int k = 0; k < 16; ++k)
#pragma unroll
    for (int j = 0; j < 4; ++j)
      wef[k][j] = We[(size_t)(1024 + k) * 1024 + t + 256 * j];

  float p2[4];
#pragma unroll
  for (int j = 0; j < 4; ++j) {
    int c = t + 256 * j;
    p2[j] = b2f(P[(size_t)node * 2048 + 1024 + c]) + be[c];
  }
  float acc[4] = {0.f, 0.f, 0.f, 0.f};
  float accl0 = 0.f, accl1 = 0.f;
  const int cl0 = t, cl1 = t + 256;

  for (int i = 0; i < deg; ++i) {
    int e = elist[base + i];
    int s = src[e];
    float wgt = af[e];
    float wl = afl[e];
    float sfv[16];
#pragma unroll
    for (int k = 0; k < 16; ++k) sfv[k] = s_f[(size_t)e * 16 + k];
    const bf16* P1 = P + (size_t)s * 2048;
    const bf16* nfs = nf_bf + (size_t)s * 1024;
#pragma unroll
    for (int j = 0; j < 4; ++j) {
      int c = t + 256 * j;
      float ef = b2f(P1[c]) + p2[j];
#pragma unroll
      for (int k = 0; k < 16; ++k) ef = fmaf(sfv[k], wef[k][j], ef);
      ef = fmaxf(ef, 0.f);
      acc[j] = fmaf(wgt, b2f(nfs[c]) + ef, acc[j]);
    }
    accl0 = fmaf(wl, b2f(w2v_pad[(size_t)s * 320 + cl0]), accl0);
    if (cl1 < 300) accl1 = fmaf(wl, b2f(w2v_pad[(size_t)s * 320 + cl1]), accl1);
  }
#pragma unroll
  for (int j = 0; j < 4; ++j) zf[(size_t)node * 1024 + t + 256 * j] = f2b(acc[j]);
  zfl_pad[(size_t)node * 320 + cl0] = f2b(accl0);          // cl0 < 256 always
  if (cl1 < 300)      zfl_pad[(size_t)node * 320 + cl1] = f2b(accl1);
  else if (cl1 < 320) zfl_pad[(size_t)node * 320 + cl1] = f2b(0.f);
}

//=====================================================================
extern "C" void kernel_launch(void* const* d_in, const int* in_sizes, int n_in,
                              void* d_out, int out_size, void* d_ws, size_t ws_size,
                              hipStream_t stream)
{
  (void)hipGetLastError();
  if (n_in != 17) { hipMemsetAsync(d_out, 0x41, 4096, stream); return; }

  const float* n_f = (const float*)d_in[0];
  const float* w2v = (const float*)d_in[1];
  const float* s_f = (const float*)d_in[2];
  const int*   src = (const int*)d_in[3];
  const int*   dst = (const int*)d_in[4];
  const float* We  = (const float*)d_in[5];
  const float* be  = (const float*)d_in[6];
  const float* Wel = (const float*)d_in[7];
  const float* bel = (const float*)d_in[8];
  const float* Wa  = (const float*)d_in[9];
  const float* ba  = (const float*)d_in[10];
  const float* Wal = (const float*)d_in[11];
  const float* bal = (const float*)d_in[12];
  const float* Wn  = (const float*)d_in[13];
  const float* bn  = (const float*)d_in[14];
  const float* Wnl = (const float*)d_in[15];
  const float* bnl = (const float*)d_in[16];
  float* out  = (float*)d_out;
  float* out2 = out + OUT0_ELEMS;

  char* ws = (char*)d_ws;
  size_t o = 0;
  auto alloc = [&](size_t bytes) -> void* {
    void* p = ws + o; o += bytes; o = (o + 255) & ~(size_t)255; return p;
  };
  bf16* P       = (bf16*)alloc((size_t)N_NODES * 2048 * 2);
  bf16* Q       = (bf16*)alloc((size_t)N_NODES * 1280 * 2);
  bf16* zf      = (bf16*)alloc((size_t)N_NODES * 1024 * 2);
  bf16* zfl_pad = (bf16*)alloc((size_t)N_NODES * 320 * 2);
  bf16* nf_bf   = (bf16*)alloc((size_t)N_NODES * 1024 * 2);
  bf16* w2v_pad = (bf16*)alloc((size_t)N_NODES * 320 * 2);
  bf16* Wel_pad = (bf16*)alloc((size_t)320 * 1280 * 2);
  bf16* Wnl_pad = (bf16*)alloc((size_t)640 * 384 * 2);
  float* af     = (float*)alloc((size_t)N_EDGES * 4);
  float* afl    = (float*)alloc((size_t)N_EDGES * 4);
  int* cnt      = (int*)alloc((size_t)N_NODES * 4);
  int* offs     = (int*)alloc((size_t)(N_NODES + 1) * 4);
  int* cur      = (int*)alloc((size_t)N_NODES * 4);
  int* elist    = (int*)alloc((size_t)N_EDGES * 4);
  if (o > ws_size) { hipMemsetAsync(d_out, 0x42, 4096, stream); return; }

  gnn6_zero<<<N_NODES / 256, 256, 0, stream>>>(cnt, N_NODES);
  gnn7_cvt<<<(N_NODES * 1024 / 8 + 255) / 256, 256, 0, stream>>>(n_f, nf_bf,
                                                                 N_NODES * 1024 / 8);
  gnn8_pad_w2v<<<(N_NODES * 80 + 255) / 256, 256, 0, stream>>>(w2v, w2v_pad);
  gnn8_pad_Wel<<<(320 * 320 + 255) / 256, 256, 0, stream>>>(Wel, Wel_pad);
  gnn8_pad_Wnl<<<(640 * 96 + 255) / 256, 256, 0, stream>>>(Wnl, Wnl_pad);

  {
    dim3 g(2048 / 128, N_NODES / 128);
    gnn7_mm_P<<<g, 256, 0, stream>>>(nf_bf, We, P);
  }
  {
    dim3 g(1280 / 128, N_NODES / 128);
    gnn8_mm_Q<<<g, 256, 0, stream>>>(w2v_pad, Wel_pad, Q);
  }

  gnn8_edge_score<<<N_EDGES / 8, 256, 0, stream>>>(src, dst, s_f, We, be, Wa, ba,
                                                   bel, Wal, bal, P, Q, af, afl);

  gnn6_count<<<N_EDGES / 256, 256, 0, stream>>>(dst, cnt);
  gnn6_scan<<<1, 1024, 0, stream>>>(cnt, offs, cur);
  gnn6_fill<<<N_EDGES / 256, 256, 0, stream>>>(dst, cur, elist);
  gnn6_alpha<<<N_NODES / 256, 256, 0, stream>>>(offs, elist, af, afl);

  gnn8_node_z<<<N_NODES, 256, 0, stream>>>(offs, elist, src, af, afl, nf_bf,
                                           w2v_pad, s_f, We, be, P, zf, zfl_pad);

  {
    dim3 g(1024 / 128, N_NODES / 128);
    gnn7_mm_out_n<<<g, 256, 0, stream>>>(nf_bf, zf, Wn, bn, out);
  }
  {
    dim3 g(384 / 128, N_NODES / 128);
    gnn8_mm_out_l<<<g, 256, 0, stream>>>(w2v_pad, zfl_pad, Wnl_pad, bnl, out2);
  }

  if (hipGetLastError() != hipSuccess) hipMemsetAsync(d_out, 0x44, 4096, stream);
}

// Round 9
// 578.441 us; speedup vs baseline: 5.3551x; 1.0584x over previous
//
#include <hip/hip_runtime.h>
#include <hip/hip_bf16.h>

#define N_NODES 8192
#define N_EDGES 65536
#define OUT0_ELEMS ((size_t)N_NODES * 1024)

using bf16 = __hip_bfloat16;
typedef __attribute__((ext_vector_type(8))) short short8;
typedef __attribute__((ext_vector_type(4))) float f32x4;

__device__ __forceinline__ float b2f(bf16 x) { return __bfloat162float(x); }
__device__ __forceinline__ bf16 f2b(float x) { return __float2bfloat16(x); }
__device__ __forceinline__ unsigned short bbits(float x)
{
  union { bf16 h; unsigned short u; } v; v.h = f2b(x); return v.u;
}
__device__ __forceinline__ unsigned pack2(float a, float b)
{
  return (unsigned)bbits(a) | ((unsigned)bbits(b) << 16);
}
// load 4 consecutive bf16 (8B aligned) -> float4
__device__ __forceinline__ float4 ld4b(const bf16* p)
{
  uint2 u = *(const uint2*)p;
  float4 r;
  r.x = __uint_as_float(u.x << 16);
  r.y = __uint_as_float(u.x & 0xffff0000u);
  r.z = __uint_as_float(u.y << 16);
  r.w = __uint_as_float(u.y & 0xffff0000u);
  return r;
}
__device__ __forceinline__ void st4b(bf16* p, float a, float b, float c, float d)
{
  uint2 v; v.x = pack2(a, b); v.y = pack2(c, d);
  *(uint2*)p = v;
}

// Kept so any harness-side reference to the stub symbol still resolves.
__global__ void GNN_27650999451833_kernel() {}

__global__ void gnn6_zero(int* __restrict__ p, int n)
{
  int i = blockIdx.x * blockDim.x + threadIdx.x;
  if (i < n) p[i] = 0;
}

//---------------------------------------------------------------------
// f32 -> bf16 bulk convert (8 elems/thread)
//---------------------------------------------------------------------
__global__ __launch_bounds__(256)
void gnn7_cvt(const float* __restrict__ src, bf16* __restrict__ dst, int n8)
{
  int i = blockIdx.x * blockDim.x + threadIdx.x;
  if (i < n8) {
    float4 a = ((const float4*)src)[2 * i];
    float4 b = ((const float4*)src)[2 * i + 1];
    uint4 p;
    p.x = pack2(a.x, a.y); p.y = pack2(a.z, a.w);
    p.z = pack2(b.x, b.y); p.w = pack2(b.z, b.w);
    ((uint4*)dst)[i] = p;
  }
}

//---------------------------------------------------------------------
// w2v[8192,300](f32) -> w2v_pad[8192,320](bf16, cols>=300 zero)
//---------------------------------------------------------------------
__global__ __launch_bounds__(256)
void gnn8_pad_w2v(const float* __restrict__ src, bf16* __restrict__ dst)
{
  int idx = blockIdx.x * blockDim.x + threadIdx.x;
  if (idx >= N_NODES * 80) return;
  int r = idx / 80, c0 = (idx % 80) * 4;
  float v[4];
#pragma unroll
  for (int j = 0; j < 4; ++j) {
    int c = c0 + j;
    v[j] = (c < 300) ? src[(size_t)r * 300 + c] : 0.f;
  }
  uint2 p; p.x = pack2(v[0], v[1]); p.y = pack2(v[2], v[3]);
  *(uint2*)(dst + (size_t)r * 320 + c0) = p;
}

//---------------------------------------------------------------------
// Wel[600,600](f32) -> Wel_pad[320,1280](bf16)
//---------------------------------------------------------------------
__global__ __launch_bounds__(256)
void gnn8_pad_Wel(const float* __restrict__ src, bf16* __restrict__ dst)
{
  int idx = blockIdx.x * blockDim.x + threadIdx.x;
  if (idx >= 320 * 320) return;
  int k = idx / 320, c0 = (idx % 320) * 4;
  float v[4];
#pragma unroll
  for (int j = 0; j < 4; ++j) {
    int c = c0 + j;
    float x = 0.f;
    if (k < 300) {
      if (c < 600)       x = src[(size_t)k * 600 + c];
      else if (c < 1200) x = src[(size_t)(300 + k) * 600 + (c - 600)];
    }
    v[j] = x;
  }
  uint2 p; p.x = pack2(v[0], v[1]); p.y = pack2(v[2], v[3]);
  *(uint2*)(dst + (size_t)k * 1280 + c0) = p;
}

//---------------------------------------------------------------------
// Wnl[600,300](f32) -> Wnl_pad[640,384](bf16)
//---------------------------------------------------------------------
__global__ __launch_bounds__(256)
void gnn8_pad_Wnl(const float* __restrict__ src, bf16* __restrict__ dst)
{
  int idx = blockIdx.x * blockDim.x + threadIdx.x;
  if (idx >= 640 * 96) return;
  int k = idx / 96, c0 = (idx % 96) * 4;
  int kr = -1;
  if (k < 300) kr = k;
  else if (k >= 320 && k < 620) kr = k - 20;
  float v[4];
#pragma unroll
  for (int j = 0; j < 4; ++j) {
    int c = c0 + j;
    v[j] = (kr >= 0 && c < 300) ? src[(size_t)kr * 300 + c] : 0.f;
  }
  uint2 p; p.x = pack2(v[0], v[1]); p.y = pack2(v[2], v[3]);
  *(uint2*)(dst + (size_t)k * 384 + c0) = p;
}

//---------------------------------------------------------------------
// MFMA GEMM 1: P[8192,2048](bf16) = nf_bf @ [We[0:1024]|We[1040:2064]](f32)
//---------------------------------------------------------------------
__global__ __launch_bounds__(256)
void gnn7_mm_P(const bf16* __restrict__ A, const float* __restrict__ We,
               bf16* __restrict__ P)
{
  __shared__ short As[128 * 40];
  __shared__ short Bs[128 * 40];
  const int t = threadIdx.x;
  const int col0 = blockIdx.x * 128, row0 = blockIdx.y * 128;
  const int lane = t & 63, w = t >> 6, m16 = lane & 15, q = lane >> 4;
  const int wr = w >> 1, wc = w & 1;

  f32x4 acc[4][4];
#pragma unroll
  for (int mi = 0; mi < 4; ++mi)
#pragma unroll
    for (int ni = 0; ni < 4; ++ni) acc[mi][ni] = (f32x4){0.f, 0.f, 0.f, 0.f};

  const int ar = t >> 1, ah = (t & 1) * 16;
  const int bk = t & 31, bn0 = (t >> 5) * 16;

  const bf16* aptr = A + (size_t)(row0 + ar) * 1024 + ah;
  const float* bptr = (col0 < 1024)
      ? (We + (size_t)bk * 1024 + col0 + bn0)
      : (We + (size_t)(1040 + bk) * 1024 + (col0 - 1024) + bn0);

  uint4 a0 = *(const uint4*)(aptr);
  uint4 a1 = *(const uint4*)(aptr + 8);
  float4 b0 = *(const float4*)(bptr);
  float4 b1 = *(const float4*)(bptr + 4);
  float4 b2 = *(const float4*)(bptr + 8);
  float4 b3 = *(const float4*)(bptr + 12);

  for (int k0 = 0; k0 < 1024; k0 += 32) {
    if (k0) __syncthreads();
    *(uint4*)&As[ar * 40 + ah] = a0;
    *(uint4*)&As[ar * 40 + ah + 8] = a1;
    {
      short* brow = &Bs[bn0 * 40 + bk];
      brow[0 * 40] = (short)bbits(b0.x);  brow[1 * 40] = (short)bbits(b0.y);
      brow[2 * 40] = (short)bbits(b0.z);  brow[3 * 40] = (short)bbits(b0.w);
      brow[4 * 40] = (short)bbits(b1.x);  brow[5 * 40] = (short)bbits(b1.y);
      brow[6 * 40] = (short)bbits(b1.z);  brow[7 * 40] = (short)bbits(b1.w);
      brow[8 * 40] = (short)bbits(b2.x);  brow[9 * 40] = (short)bbits(b2.y);
      brow[10 * 40] = (short)bbits(b2.z); brow[11 * 40] = (short)bbits(b2.w);
      brow[12 * 40] = (short)bbits(b3.x); brow[13 * 40] = (short)bbits(b3.y);
      brow[14 * 40] = (short)bbits(b3.z); brow[15 * 40] = (short)bbits(b3.w);
    }
    __syncthreads();
    if (k0 + 32 < 1024) {
      a0 = *(const uint4*)(aptr + k0 + 32);
      a1 = *(const uint4*)(aptr + k0 + 40);
      const float* bp = bptr + (size_t)(k0 + 32) * 1024;
      b0 = *(const float4*)(bp);
      b1 = *(const float4*)(bp + 4);
      b2 = *(const float4*)(bp + 8);
      b3 = *(const float4*)(bp + 12);
    }
    short8 af[4];
#pragma unroll
    for (int mi = 0; mi < 4; ++mi)
      af[mi] = *(const short8*)&As[(wr * 64 + mi * 16 + m16) * 40 + 8 * q];
#pragma unroll
    for (int ni = 0; ni < 4; ++ni) {
      short8 bfv = *(const short8*)&Bs[(wc * 64 + ni * 16 + m16) * 40 + 8 * q];
#pragma unroll
      for (int mi = 0; mi < 4; ++mi)
        acc[mi][ni] =
            __builtin_amdgcn_mfma_f32_16x16x32_bf16(af[mi], bfv, acc[mi][ni], 0, 0, 0);
    }
  }
#pragma unroll
  for (int mi = 0; mi < 4; ++mi)
#pragma unroll
    for (int ni = 0; ni < 4; ++ni) {
      int c = col0 + wc * 64 + ni * 16 + m16;
#pragma unroll
      for (int r = 0; r < 4; ++r)
        P[(size_t)(row0 + wr * 64 + mi * 16 + 4 * q + r) * 2048 + c] =
            f2b(acc[mi][ni][r]);
    }
}

//---------------------------------------------------------------------
// MFMA GEMM 2: out0[8192,1024](f32) = relu([nf_bf | zf](bf16) @ Wn(f32) + bn)
//---------------------------------------------------------------------
__global__ __launch_bounds__(256)
void gnn7_mm_out_n(const bf16* __restrict__ nf_bf, const bf16* __restrict__ zf,
                   const float* __restrict__ Wn, const float* __restrict__ bn,
                   float* __restrict__ out)
{
  __shared__ short As[128 * 40];
  __shared__ short Bs[128 * 40];
  const int t = threadIdx.x;
  const int col0 = blockIdx.x * 128, row0 = blockIdx.y * 128;
  const int lane = t & 63, w = t >> 6, m16 = lane & 15, q = lane >> 4;
  const int wr = w >> 1, wc = w & 1;

  f32x4 acc[4][4];
#pragma unroll
  for (int mi = 0; mi < 4; ++mi)
#pragma unroll
    for (int ni = 0; ni < 4; ++ni) acc[mi][ni] = (f32x4){0.f, 0.f, 0.f, 0.f};

  const int ar = t >> 1, ah = (t & 1) * 16;
  const int bk = t & 31, bn0 = (t >> 5) * 16;

  const bf16* ap0 = nf_bf + (size_t)(row0 + ar) * 1024 + ah;
  const bf16* ap1 = zf + (size_t)(row0 + ar) * 1024 + ah;
  const float* bptr = Wn + (size_t)bk * 1024 + col0 + bn0;

  uint4 a0 = *(const uint4*)(ap0);
  uint4 a1 = *(const uint4*)(ap0 + 8);
  float4 b0 = *(const float4*)(bptr);
  float4 b1 = *(const float4*)(bptr + 4);
  float4 b2 = *(const float4*)(bptr + 8);
  float4 b3 = *(const float4*)(bptr + 12);

  for (int k0 = 0; k0 < 2048; k0 += 32) {
    if (k0) __syncthreads();
    *(uint4*)&As[ar * 40 + ah] = a0;
    *(uint4*)&As[ar * 40 + ah + 8] = a1;
    {
      short* brow = &Bs[bn0 * 40 + bk];
      brow[0 * 40] = (short)bbits(b0.x);  brow[1 * 40] = (short)bbits(b0.y);
      brow[2 * 40] = (short)bbits(b0.z);  brow[3 * 40] = (short)bbits(b0.w);
      brow[4 * 40] = (short)bbits(b1.x);  brow[5 * 40] = (short)bbits(b1.y);
      brow[6 * 40] = (short)bbits(b1.z);  brow[7 * 40] = (short)bbits(b1.w);
      brow[8 * 40] = (short)bbits(b2.x);  brow[9 * 40] = (short)bbits(b2.y);
      brow[10 * 40] = (short)bbits(b2.z); brow[11 * 40] = (short)bbits(b2.w);
      brow[12 * 40] = (short)bbits(b3.x); brow[13 * 40] = (short)bbits(b3.y);
      brow[14 * 40] = (short)bbits(b3.z); brow[15 * 40] = (short)bbits(b3.w);
    }
    __syncthreads();
    if (k0 + 32 < 2048) {
      int kn = k0 + 32;
      if (kn + ah < 1024) {
        a0 = *(const uint4*)(ap0 + kn);
        a1 = *(const uint4*)(ap0 + kn + 8);
      } else {
        a0 = *(const uint4*)(ap1 + (kn - 1024));
        a1 = *(const uint4*)(ap1 + (kn - 1024) + 8);
      }
      const float* bp = bptr + (size_t)kn * 1024;
      b0 = *(const float4*)(bp);
      b1 = *(const float4*)(bp + 4);
      b2 = *(const float4*)(bp + 8);
      b3 = *(const float4*)(bp + 12);
    }
    short8 af[4];
#pragma unroll
    for (int mi = 0; mi < 4; ++mi)
      af[mi] = *(const short8*)&As[(wr * 64 + mi * 16 + m16) * 40 + 8 * q];
#pragma unroll
    for (int ni = 0; ni < 4; ++ni) {
      short8 bfv = *(const short8*)&Bs[(wc * 64 + ni * 16 + m16) * 40 + 8 * q];
#pragma unroll
      for (int mi = 0; mi < 4; ++mi)
        acc[mi][ni] =
            __builtin_amdgcn_mfma_f32_16x16x32_bf16(af[mi], bfv, acc[mi][ni], 0, 0, 0);
    }
  }
#pragma unroll
  for (int mi = 0; mi < 4; ++mi)
#pragma unroll
    for (int ni = 0; ni < 4; ++ni) {
      int c = col0 + wc * 64 + ni * 16 + m16;
      float bias = bn[c];
#pragma unroll
      for (int r = 0; r < 4; ++r) {
        float v = acc[mi][ni][r] + bias;
        out[(size_t)(row0 + wr * 64 + mi * 16 + 4 * q + r) * 1024 + c] =
            fmaxf(v, 0.f);
      }
    }
}

//---------------------------------------------------------------------
// MFMA GEMM Q: Q[8192,1280](bf16) = w2v_pad[8192,320] @ Wel_pad[320,1280]
//---------------------------------------------------------------------
__global__ __launch_bounds__(256)
void gnn8_mm_Q(const bf16* __restrict__ A, const bf16* __restrict__ B,
               bf16* __restrict__ Q)
{
  __shared__ short As[128 * 40];
  __shared__ short Bs[128 * 40];
  const int t = threadIdx.x;
  const int col0 = blockIdx.x * 128, row0 = blockIdx.y * 128;
  const int lane = t & 63, w = t >> 6, m16 = lane & 15, q = lane >> 4;
  const int wr = w >> 1, wc = w & 1;

  f32x4 acc[4][4];
#pragma unroll
  for (int mi = 0; mi < 4; ++mi)
#pragma unroll
    for (int ni = 0; ni < 4; ++ni) acc[mi][ni] = (f32x4){0.f, 0.f, 0.f, 0.f};

  const int ar = t >> 1, ah = (t & 1) * 16;
  const int bk = t & 31, bn0 = (t >> 5) * 16;

  const bf16* aptr = A + (size_t)(row0 + ar) * 320 + ah;
  const bf16* bptr = B + (size_t)bk * 1280 + col0 + bn0;

  uint4 a0 = *(const uint4*)(aptr);
  uint4 a1 = *(const uint4*)(aptr + 8);
  uint4 b0 = *(const uint4*)(bptr);
  uint4 b1 = *(const uint4*)(bptr + 8);

  for (int k0 = 0; k0 < 320; k0 += 32) {
    if (k0) __syncthreads();
    *(uint4*)&As[ar * 40 + ah] = a0;
    *(uint4*)&As[ar * 40 + ah + 8] = a1;
    {
      const short* bs0 = (const short*)&b0;
      const short* bs1 = (const short*)&b1;
      short* brow = &Bs[bn0 * 40 + bk];
#pragma unroll
      for (int j = 0; j < 8; ++j) brow[j * 40] = bs0[j];
#pragma unroll
      for (int j = 0; j < 8; ++j) brow[(8 + j) * 40] = bs1[j];
    }
    __syncthreads();
    if (k0 + 32 < 320) {
      a0 = *(const uint4*)(aptr + k0 + 32);
      a1 = *(const uint4*)(aptr + k0 + 40);
      const bf16* bp = bptr + (size_t)(k0 + 32) * 1280;
      b0 = *(const uint4*)(bp);
      b1 = *(const uint4*)(bp + 8);
    }
    short8 af[4];
#pragma unroll
    for (int mi = 0; mi < 4; ++mi)
      af[mi] = *(const short8*)&As[(wr * 64 + mi * 16 + m16) * 40 + 8 * q];
#pragma unroll
    for (int ni = 0; ni < 4; ++ni) {
      short8 bfv = *(const short8*)&Bs[(wc * 64 + ni * 16 + m16) * 40 + 8 * q];
#pragma unroll
      for (int mi = 0; mi < 4; ++mi)
        acc[mi][ni] =
            __builtin_amdgcn_mfma_f32_16x16x32_bf16(af[mi], bfv, acc[mi][ni], 0, 0, 0);
    }
  }
#pragma unroll
  for (int mi = 0; mi < 4; ++mi)
#pragma unroll
    for (int ni = 0; ni < 4; ++ni) {
      int c = col0 + wc * 64 + ni * 16 + m16;
#pragma unroll
      for (int r = 0; r < 4; ++r)
        Q[(size_t)(row0 + wr * 64 + mi * 16 + 4 * q + r) * 1280 + c] =
            f2b(acc[mi][ni][r]);
    }
}

//---------------------------------------------------------------------
// MFMA GEMM out_l: out1[8192,300](f32) =
//   relu([w2v_pad | zfl_pad](K=640) @ Wnl_pad[640,384] + bnl), store c<300
//---------------------------------------------------------------------
__global__ __launch_bounds__(256)
void gnn8_mm_out_l(const bf16* __restrict__ A0, const bf16* __restrict__ A1,
                   const bf16* __restrict__ B, const float* __restrict__ bnl,
                   float* __restrict__ out2)
{
  __shared__ short As[128 * 40];
  __shared__ short Bs[128 * 40];
  const int t = threadIdx.x;
  const int col0 = blockIdx.x * 128, row0 = blockIdx.y * 128;
  const int lane = t & 63, w = t >> 6, m16 = lane & 15, q = lane >> 4;
  const int wr = w >> 1, wc = w & 1;

  f32x4 acc[4][4];
#pragma unroll
  for (int mi = 0; mi < 4; ++mi)
#pragma unroll
    for (int ni = 0; ni < 4; ++ni) acc[mi][ni] = (f32x4){0.f, 0.f, 0.f, 0.f};

  const int ar = t >> 1, ah = (t & 1) * 16;
  const int bk = t & 31, bn0 = (t >> 5) * 16;

  const bf16* ap0 = A0 + (size_t)(row0 + ar) * 320 + ah;
  const bf16* ap1 = A1 + (size_t)(row0 + ar) * 320 + ah;
  const bf16* bptr = B + (size_t)bk * 384 + col0 + bn0;

  uint4 a0 = *(const uint4*)(ap0);
  uint4 a1 = *(const uint4*)(ap0 + 8);
  uint4 b0 = *(const uint4*)(bptr);
  uint4 b1 = *(const uint4*)(bptr + 8);

  for (int k0 = 0; k0 < 640; k0 += 32) {
    if (k0) __syncthreads();
    *(uint4*)&As[ar * 40 + ah] = a0;
    *(uint4*)&As[ar * 40 + ah + 8] = a1;
    {
      const short* bs0 = (const short*)&b0;
      const short* bs1 = (const short*)&b1;
      short* brow = &Bs[bn0 * 40 + bk];
#pragma unroll
      for (int j = 0; j < 8; ++j) brow[j * 40] = bs0[j];
#pragma unroll
      for (int j = 0; j < 8; ++j) brow[(8 + j) * 40] = bs1[j];
    }
    __syncthreads();
    if (k0 + 32 < 640) {
      int kn = k0 + 32;
      const bf16* ap = (kn < 320) ? (ap0 + kn) : (ap1 + (kn - 320));
      a0 = *(const uint4*)(ap);
      a1 = *(const uint4*)(ap + 8);
      const bf16* bp = bptr + (size_t)kn * 384;
      b0 = *(const uint4*)(bp);
      b1 = *(const uint4*)(bp + 8);
    }
    short8 af[4];
#pragma unroll
    for (int mi = 0; mi < 4; ++mi)
      af[mi] = *(const short8*)&As[(wr * 64 + mi * 16 + m16) * 40 + 8 * q];
#pragma unroll
    for (int ni = 0; ni < 4; ++ni) {
      short8 bfv = *(const short8*)&Bs[(wc * 64 + ni * 16 + m16) * 40 + 8 * q];
#pragma unroll
      for (int mi = 0; mi < 4; ++mi)
        acc[mi][ni] =
            __builtin_amdgcn_mfma_f32_16x16x32_bf16(af[mi], bfv, acc[mi][ni], 0, 0, 0);
    }
  }
#pragma unroll
  for (int mi = 0; mi < 4; ++mi)
#pragma unroll
    for (int ni = 0; ni < 4; ++ni) {
      int c = col0 + wc * 64 + ni * 16 + m16;
      if (c < 300) {
        float bias = bnl[c];
#pragma unroll
        for (int r = 0; r < 4; ++r) {
          float v = acc[mi][ni][r] + bias;
          out2[(size_t)(row0 + wr * 64 + mi * 16 + 4 * q + r) * 300 + c] =
              fmaxf(v, 0.f);
        }
      }
    }
}

//---------------------------------------------------------------------
// Edge scores v9: thread t owns CONTIGUOUS cols 4t..4t+3.
// All P/Q gathers are uint2 (4xbf16); We/Wa/be are float4. 8 edges/block.
//---------------------------------------------------------------------
__global__ __launch_bounds__(256)
void gnn9_edge_score(const int* __restrict__ src, const int* __restrict__ dst,
                     const float* __restrict__ s_f, const float* __restrict__ We,
                     const float* __restrict__ be, const float* __restrict__ Wa,
                     const float* __restrict__ ba, const float* __restrict__ bel,
                     const float* __restrict__ Wal, const float* __restrict__ bal,
                     const bf16* __restrict__ P, const bf16* __restrict__ Q,
                     float* __restrict__ af, float* __restrict__ afl)
{
  const int t = threadIdx.x;
  const int lane = t & 63, w = t >> 6;
  const int c0 = 4 * t;
  const int e0 = blockIdx.x * 8;

  float wef[16][4];
#pragma unroll
  for (int k = 0; k < 16; ++k) {
    float4 v = *(const float4*)(We + (size_t)(1024 + k) * 1024 + c0);
    wef[k][0] = v.x; wef[k][1] = v.y; wef[k][2] = v.z; wef[k][3] = v.w;
  }
  float4 bev = *(const float4*)(be + c0);
  float4 wav = *(const float4*)(Wa + c0);
  const bool lact = (t < 150);
  float4 belv = {0, 0, 0, 0}, walv = {0, 0, 0, 0};
  if (lact) { belv = *(const float4*)(bel + c0); walv = *(const float4*)(Wal + c0); }
  const float ba0 = ba[0], bal0 = bal[0];

  __shared__ float shf[4], shl[4];

  for (int i = 0; i < 8; ++i) {
    const int e = e0 + i;
    const int s = src[e], d = dst[e];

    float sfv[16];
    {
      const float4* sp = (const float4*)(s_f + (size_t)e * 16);
      float4 s0 = sp[0], s1 = sp[1], s2 = sp[2], s3 = sp[3];
      sfv[0] = s0.x; sfv[1] = s0.y; sfv[2] = s0.z; sfv[3] = s0.w;
      sfv[4] = s1.x; sfv[5] = s1.y; sfv[6] = s1.z; sfv[7] = s1.w;
      sfv[8] = s2.x; sfv[9] = s2.y; sfv[10] = s2.z; sfv[11] = s2.w;
      sfv[12] = s3.x; sfv[13] = s3.y; sfv[14] = s3.z; sfv[15] = s3.w;
    }

    float4 p1 = ld4b(P + (size_t)s * 2048 + c0);
    float4 p2 = ld4b(P + (size_t)d * 2048 + 1024 + c0);
    float pv[4] = {p1.x + p2.x + bev.x, p1.y + p2.y + bev.y,
                   p1.z + p2.z + bev.z, p1.w + p2.w + bev.w};
    float pf = 0.f;
#pragma unroll
    for (int j = 0; j < 4; ++j) {
      float v = pv[j];
#pragma unroll
      for (int k = 0; k < 16; ++k) v = fmaf(sfv[k], wef[k][j], v);
      pf = fmaf(fmaxf(v, 0.f), (&wav.x)[j], pf);
    }

    float pl = 0.f;
    if (lact) {
      float4 q1 = ld4b(Q + (size_t)s * 1280 + c0);
      float4 q2 = ld4b(Q + (size_t)d * 1280 + 600 + c0);
      float qv[4] = {q1.x + q2.x + belv.x, q1.y + q2.y + belv.y,
                     q1.z + q2.z + belv.z, q1.w + q2.w + belv.w};
#pragma unroll
      for (int j = 0; j < 4; ++j)
        pl = fmaf(fmaxf(qv[j], 0.f), (&walv.x)[j], pl);
    }

#pragma unroll
    for (int o = 32; o > 0; o >>= 1) {
      pf += __shfl_down(pf, o, 64);
      pl += __shfl_down(pl, o, 64);
    }
    if (lane == 0) { shf[w] = pf; shl[w] = pl; }
    __syncthreads();
    if (t == 0)  af[e]  = shf[0] + shf[1] + shf[2] + shf[3] + ba0;
    if (t == 64) afl[e] = shl[0] + shl[1] + shl[2] + shl[3] + bal0;
    __syncthreads();
  }
}

//---------------------------------------------------------------------
// CSR build
//---------------------------------------------------------------------
__global__ void gnn6_count(const int* __restrict__ dst, int* __restrict__ cnt)
{
  int e = blockIdx.x * blockDim.x + threadIdx.x;
  if (e < N_EDGES) atomicAdd(&cnt[dst[e]], 1);
}

__global__ __launch_bounds__(1024)
void gnn6_scan(const int* __restrict__ cnt, int* __restrict__ off, int* __restrict__ cur)
{
  __shared__ int sh[1024];
  const int t = threadIdx.x;
  int local[8]; int sum = 0;
#pragma unroll
  for (int i = 0; i < 8; ++i) { int v = cnt[t * 8 + i]; local[i] = sum; sum += v; }
  sh[t] = sum;
  __syncthreads();
  for (int d = 1; d < 1024; d <<= 1) {
    int v = (t >= d) ? sh[t - d] : 0;
    __syncthreads();
    sh[t] += v;
    __syncthreads();
  }
  int basev = (t > 0) ? sh[t - 1] : 0;
#pragma unroll
  for (int i = 0; i < 8; ++i) { int o = basev + local[i]; off[t * 8 + i] = o; cur[t * 8 + i] = o; }
  if (t == 1023) off[8192] = sh[1023];
}

__global__ void gnn6_fill(const int* __restrict__ dst, int* __restrict__ cur,
                          int* __restrict__ elist)
{
  int e = blockIdx.x * blockDim.x + threadIdx.x;
  if (e < N_EDGES) { int p = atomicAdd(&cur[dst[e]], 1); elist[p] = e; }
}

//---------------------------------------------------------------------
// Per-node softmax -> alpha written in place into af/afl.
//---------------------------------------------------------------------
__global__ __launch_bounds__(256)
void gnn6_alpha(const int* __restrict__ off, const int* __restrict__ elist,
                float* __restrict__ af, float* __restrict__ afl)
{
  const int n = blockIdx.x * 256 + threadIdx.x;
  if (n >= N_NODES) return;
  const int base = off[n];
  const int deg = off[n + 1] - base;
  float m = -1e30f, ml = -1e30f;
  for (int i = 0; i < deg; ++i) {
    int e = elist[base + i];
    m = fmaxf(m, af[e]);
    ml = fmaxf(ml, afl[e]);
  }
  float den = 0.f, denl = 0.f;
  for (int i = 0; i < deg; ++i) {
    int e = elist[base + i];
    den += expf(af[e] - m);
    denl += expf(afl[e] - ml);
  }
  float inv = (den > 0.f) ? 1.f / den : 0.f;
  float invl = (denl > 0.f) ? 1.f / denl : 0.f;
  for (int i = 0; i < deg; ++i) {
    int e = elist[base + i];
    af[e] = expf(af[e] - m) * inv;
    afl[e] = expf(afl[e] - ml) * invl;
  }
}

//---------------------------------------------------------------------
// node_z v9: thread t owns CONTIGUOUS cols 4t..4t+3; all gathers uint2.
//---------------------------------------------------------------------
__global__ __launch_bounds__(256)
void gnn9_node_z(const int* __restrict__ off, const int* __restrict__ elist,
                 const int* __restrict__ src, const float* __restrict__ af,
                 const float* __restrict__ afl, const bf16* __restrict__ nf_bf,
                 const bf16* __restrict__ w2v_pad, const float* __restrict__ s_f,
                 const float* __restrict__ We, const float* __restrict__ be,
                 const bf16* __restrict__ P, bf16* __restrict__ zf,
                 bf16* __restrict__ zfl_pad)
{
  const int node = blockIdx.x;
  const int t = threadIdx.x;
  const int c0 = 4 * t;
  const int base = off[node];
  const int deg = off[node + 1] - base;

  float wef[16][4];
#pragma unroll
  for (int k = 0; k < 16; ++k) {
    float4 v = *(const float4*)(We + (size_t)(1024 + k) * 1024 + c0);
    wef[k][0] = v.x; wef[k][1] = v.y; wef[k][2] = v.z; wef[k][3] = v.w;
  }
  float4 p2v = ld4b(P + (size_t)node * 2048 + 1024 + c0);
  float4 bev = *(const float4*)(be + c0);
  const float p2[4] = {p2v.x + bev.x, p2v.y + bev.y, p2v.z + bev.z, p2v.w + bev.w};

  float acc[4] = {0.f, 0.f, 0.f, 0.f};
  float accl[4] = {0.f, 0.f, 0.f, 0.f};
  const bool lact = (t < 75);      // cols 0..299

  for (int i = 0; i < deg; ++i) {
    const int e = elist[base + i];
    const int s = src[e];
    const float wgt = af[e];
    const float wl = afl[e];

    float sfv[16];
    {
      const float4* sp = (const float4*)(s_f + (size_t)e * 16);
      float4 s0 = sp[0], s1 = sp[1], s2 = sp[2], s3 = sp[3];
      sfv[0] = s0.x; sfv[1] = s0.y; sfv[2] = s0.z; sfv[3] = s0.w;
      sfv[4] = s1.x; sfv[5] = s1.y; sfv[6] = s1.z; sfv[7] = s1.w;
      sfv[8] = s2.x; sfv[9] = s2.y; sfv[10] = s2.z; sfv[11] = s2.w;
      sfv[12] = s3.x; sfv[13] = s3.y; sfv[14] = s3.z; sfv[15] = s3.w;
    }

    float4 p1 = ld4b(P + (size_t)s * 2048 + c0);
    float4 nf4 = ld4b(nf_bf + (size_t)s * 1024 + c0);
    const float p1a[4] = {p1.x, p1.y, p1.z, p1.w};
    const float nfa[4] = {nf4.x, nf4.y, nf4.z, nf4.w};
#pragma unroll
    for (int j = 0; j < 4; ++j) {
      float ef = p1a[j] + p2[j];
#pragma unroll
      for (int k = 0; k < 16; ++k) ef = fmaf(sfv[k], wef[k][j], ef);
      ef = fmaxf(ef, 0.f);
      acc[j] = fmaf(wgt, nfa[j] + ef, acc[j]);
    }
    if (lact) {
      float4 wv = ld4b(w2v_pad + (size_t)s * 320 + c0);
      accl[0] = fmaf(wl, wv.x, accl[0]);
      accl[1] = fmaf(wl, wv.y, accl[1]);
      accl[2] = fmaf(wl, wv.z, accl[2]);
      accl[3] = fmaf(wl, wv.w, accl[3]);
    }
  }
  st4b(zf + (size_t)node * 1024 + c0, acc[0], acc[1], acc[2], acc[3]);
  if (lact)
    st4b(zfl_pad + (size_t)node * 320 + c0, accl[0], accl[1], accl[2], accl[3]);
  else if (t < 80)   // cols 300..319 zero (thread 75 covers 300..303, ..., 79 -> 316..319)
    st4b(zfl_pad + (size_t)node * 320 + c0, 0.f, 0.f, 0.f, 0.f);
}

//=====================================================================
extern "C" void kernel_launch(void* const* d_in, const int* in_sizes, int n_in,
                              void* d_out, int out_size, void* d_ws, size_t ws_size,
                              hipStream_t stream)
{
  (void)hipGetLastError();
  if (n_in != 17) { hipMemsetAsync(d_out, 0x41, 4096, stream); return; }

  const float* n_f = (const float*)d_in[0];
  const float* w2v = (const float*)d_in[1];
  const float* s_f = (const float*)d_in[2];
  const int*   src = (const int*)d_in[3];
  const int*   dst = (const int*)d_in[4];
  const float* We  = (const float*)d_in[5];
  const float* be  = (const float*)d_in[6];
  const float* Wel = (const float*)d_in[7];
  const float* bel = (const float*)d_in[8];
  const float* Wa  = (const float*)d_in[9];
  const float* ba  = (const float*)d_in[10];
  const float* Wal = (const float*)d_in[11];
  const float* bal = (const float*)d_in[12];
  const float* Wn  = (const float*)d_in[13];
  const float* bn  = (const float*)d_in[14];
  const float* Wnl = (const float*)d_in[15];
  const float* bnl = (const float*)d_in[16];
  float* out  = (float*)d_out;
  float* out2 = out + OUT0_ELEMS;

  char* ws = (char*)d_ws;
  size_t o = 0;
  auto alloc = [&](size_t bytes) -> void* {
    void* p = ws + o; o += bytes; o = (o + 255) & ~(size_t)255; return p;
  };
  bf16* P       = (bf16*)alloc((size_t)N_NODES * 2048 * 2);
  bf16* Q       = (bf16*)alloc((size_t)N_NODES * 1280 * 2);
  bf16* zf      = (bf16*)alloc((size_t)N_NODES * 1024 * 2);
  bf16* zfl_pad = (bf16*)alloc((size_t)N_NODES * 320 * 2);
  bf16* nf_bf   = (bf16*)alloc((size_t)N_NODES * 1024 * 2);
  bf16* w2v_pad = (bf16*)alloc((size_t)N_NODES * 320 * 2);
  bf16* Wel_pad = (bf16*)alloc((size_t)320 * 1280 * 2);
  bf16* Wnl_pad = (bf16*)alloc((size_t)640 * 384 * 2);
  float* af     = (float*)alloc((size_t)N_EDGES * 4);
  float* afl    = (float*)alloc((size_t)N_EDGES * 4);
  int* cnt      = (int*)alloc((size_t)N_NODES * 4);
  int* offs     = (int*)alloc((size_t)(N_NODES + 1) * 4);
  int* cur      = (int*)alloc((size_t)N_NODES * 4);
  int* elist    = (int*)alloc((size_t)N_EDGES * 4);
  if (o > ws_size) { hipMemsetAsync(d_out, 0x42, 4096, stream); return; }

  gnn6_zero<<<N_NODES / 256, 256, 0, stream>>>(cnt, N_NODES);
  gnn7_cvt<<<(N_NODES * 1024 / 8 + 255) / 256, 256, 0, stream>>>(n_f, nf_bf,
                                                                 N_NODES * 1024 / 8);
  gnn8_pad_w2v<<<(N_NODES * 80 + 255) / 256, 256, 0, stream>>>(w2v, w2v_pad);
  gnn8_pad_Wel<<<(320 * 320 + 255) / 256, 256, 0, stream>>>(Wel, Wel_pad);
  gnn8_pad_Wnl<<<(640 * 96 + 255) / 256, 256, 0, stream>>>(Wnl, Wnl_pad);

  {
    dim3 g(2048 / 128, N_NODES / 128);
    gnn7_mm_P<<<g, 256, 0, stream>>>(nf_bf, We, P);
  }
  {
    dim3 g(1280 / 128, N_NODES / 128);
    gnn8_mm_Q<<<g, 256, 0, stream>>>(w2v_pad, Wel_pad, Q);
  }

  gnn9_edge_score<<<N_EDGES / 8, 256, 0, stream>>>(src, dst, s_f, We, be, Wa, ba,
                                                   bel, Wal, bal, P, Q, af, afl);

  gnn6_count<<<N_EDGES / 256, 256, 0, stream>>>(dst, cnt);
  gnn6_scan<<<1, 1024, 0, stream>>>(cnt, offs, cur);
  gnn6_fill<<<N_EDGES / 256, 256, 0, stream>>>(dst, cur, elist);
  gnn6_alpha<<<N_NODES / 256, 256, 0, stream>>>(offs, elist, af, afl);

  gnn9_node_z<<<N_NODES, 256, 0, stream>>>(offs, elist, src, af, afl, nf_bf,
                                           w2v_pad, s_f, We, be, P, zf, zfl_pad);

  {
    dim3 g(1024 / 128, N_NODES / 128);
    gnn7_mm_out_n<<<g, 256, 0, stream>>>(nf_bf, zf, Wn, bn, out);
  }
  {
    dim3 g(384 / 128, N_NODES / 128);
    gnn8_mm_out_l<<<g, 256, 0, stream>>>(w2v_pad, zfl_pad, Wnl_pad, bnl, out2);
  }

  if (hipGetLastError() != hipSuccess) hipMemsetAsync(d_out, 0x44, 4096, stream);
}

// Round 10
// 498.610 us; speedup vs baseline: 6.2125x; 1.1601x over previous
//
#include <hip/hip_runtime.h>
#include <hip/hip_bf16.h>

#define N_NODES 8192
#define N_EDGES 65536
#define OUT0_ELEMS ((size_t)N_NODES * 1024)

using bf16 = __hip_bfloat16;
typedef __attribute__((ext_vector_type(8))) short short8;
typedef __attribute__((ext_vector_type(4))) float f32x4;

__device__ __forceinline__ float b2f(bf16 x) { return __bfloat162float(x); }
__device__ __forceinline__ bf16 f2b(float x) { return __float2bfloat16(x); }
__device__ __forceinline__ unsigned short bbits(float x)
{
  union { bf16 h; unsigned short u; } v; v.h = f2b(x); return v.u;
}
__device__ __forceinline__ unsigned pack2(float a, float b)
{
  return (unsigned)bbits(a) | ((unsigned)bbits(b) << 16);
}
__device__ __forceinline__ float4 ld4b(const bf16* p)
{
  uint2 u = *(const uint2*)p;
  float4 r;
  r.x = __uint_as_float(u.x << 16);
  r.y = __uint_as_float(u.x & 0xffff0000u);
  r.z = __uint_as_float(u.y << 16);
  r.w = __uint_as_float(u.y & 0xffff0000u);
  return r;
}
__device__ __forceinline__ void st4b(bf16* p, float a, float b, float c, float d)
{
  uint2 v; v.x = pack2(a, b); v.y = pack2(c, d);
  *(uint2*)p = v;
}

// Kept so any harness-side reference to the stub symbol still resolves.
__global__ void GNN_27650999451833_kernel() {}

__global__ void gnn6_zero(int* __restrict__ p, int n)
{
  int i = blockIdx.x * blockDim.x + threadIdx.x;
  if (i < n) p[i] = 0;
}

//---------------------------------------------------------------------
// f32 -> bf16 bulk convert (8 elems/thread)
//---------------------------------------------------------------------
__global__ __launch_bounds__(256)
void gnn7_cvt(const float* __restrict__ src, bf16* __restrict__ dst, int n8)
{
  int i = blockIdx.x * blockDim.x + threadIdx.x;
  if (i < n8) {
    float4 a = ((const float4*)src)[2 * i];
    float4 b = ((const float4*)src)[2 * i + 1];
    uint4 p;
    p.x = pack2(a.x, a.y); p.y = pack2(a.z, a.w);
    p.z = pack2(b.x, b.y); p.w = pack2(b.z, b.w);
    ((uint4*)dst)[i] = p;
  }
}

//---------------------------------------------------------------------
// w2v[8192,300](f32) -> w2v_pad[8192,320](bf16, cols>=300 zero)
//---------------------------------------------------------------------
__global__ __launch_bounds__(256)
void gnn8_pad_w2v(const float* __restrict__ src, bf16* __restrict__ dst)
{
  int idx = blockIdx.x * blockDim.x + threadIdx.x;
  if (idx >= N_NODES * 80) return;
  int r = idx / 80, c0 = (idx % 80) * 4;
  float v[4];
#pragma unroll
  for (int j = 0; j < 4; ++j) {
    int c = c0 + j;
    v[j] = (c < 300) ? src[(size_t)r * 300 + c] : 0.f;
  }
  uint2 p; p.x = pack2(v[0], v[1]); p.y = pack2(v[2], v[3]);
  *(uint2*)(dst + (size_t)r * 320 + c0) = p;
}

//---------------------------------------------------------------------
// Transposed weight prepacks (LDS 32x32 tile transpose, 256 thr = 32x8)
//---------------------------------------------------------------------
// WeT[2048][1024] <- We_eff[k][n] = n<1024 ? We[k][n] : We[1040+k][n-1024]
__global__ __launch_bounds__(256)
void gnn10_t_We(const float* __restrict__ src, bf16* __restrict__ dst)
{
  __shared__ float tile[32][33];
  const int kb = blockIdx.x * 32, nb = blockIdx.y * 32;
  const int tx = threadIdx.x & 31, ty = threadIdx.x >> 5;
  const int n = nb + tx;
#pragma unroll
  for (int i = ty; i < 32; i += 8)
    tile[i][tx] = (n < 1024)
        ? src[(size_t)(kb + i) * 1024 + n]
        : src[(size_t)(1040 + kb + i) * 1024 + (n - 1024)];
  __syncthreads();
#pragma unroll
  for (int i = ty; i < 32; i += 8)
    dst[(size_t)(nb + i) * 1024 + kb + tx] = f2b(tile[tx][i]);
}

// WnT[1024][2048] <- Wn[k][n], k<2048, n<1024
__global__ __launch_bounds__(256)
void gnn10_t_Wn(const float* __restrict__ src, bf16* __restrict__ dst)
{
  __shared__ float tile[32][33];
  const int kb = blockIdx.x * 32, nb = blockIdx.y * 32;
  const int tx = threadIdx.x & 31, ty = threadIdx.x >> 5;
#pragma unroll
  for (int i = ty; i < 32; i += 8)
    tile[i][tx] = src[(size_t)(kb + i) * 1024 + nb + tx];
  __syncthreads();
#pragma unroll
  for (int i = ty; i < 32; i += 8)
    dst[(size_t)(nb + i) * 2048 + kb + tx] = f2b(tile[tx][i]);
}

// WelT_pad[1280][320] <- k<300 ? (n<600?Wel[k][n] : n<1200?Wel[300+k][n-600]:0):0
__global__ __launch_bounds__(256)
void gnn10_t_Wel(const float* __restrict__ src, bf16* __restrict__ dst)
{
  __shared__ float tile[32][33];
  const int kb = blockIdx.x * 32, nb = blockIdx.y * 32;
  const int tx = threadIdx.x & 31, ty = threadIdx.x >> 5;
  const int n = nb + tx;
#pragma unroll
  for (int i = ty; i < 32; i += 8) {
    int k = kb + i;
    float v = 0.f;
    if (k < 300) {
      if (n < 600)       v = src[(size_t)k * 600 + n];
      else if (n < 1200) v = src[(size_t)(300 + k) * 600 + (n - 600)];
    }
    tile[i][tx] = v;
  }
  __syncthreads();
#pragma unroll
  for (int i = ty; i < 32; i += 8)
    dst[(size_t)(nb + i) * 320 + kb + tx] = f2b(tile[tx][i]);
}

// WnlT_pad[384][640] <- kr(k)=k<300?k : 320<=k<620?k-20 : -1 ; n<300
__global__ __launch_bounds__(256)
void gnn10_t_Wnl(const float* __restrict__ src, bf16* __restrict__ dst)
{
  __shared__ float tile[32][33];
  const int kb = blockIdx.x * 32, nb = blockIdx.y * 32;
  const int tx = threadIdx.x & 31, ty = threadIdx.x >> 5;
  const int n = nb + tx;
#pragma unroll
  for (int i = ty; i < 32; i += 8) {
    int k = kb + i;
    int kr = (k < 300) ? k : ((k >= 320 && k < 620) ? (k - 20) : -1);
    tile[i][tx] = (kr >= 0 && n < 300) ? src[(size_t)kr * 300 + n] : 0.f;
  }
  __syncthreads();
#pragma unroll
  for (int i = ty; i < 32; i += 8)
    dst[(size_t)(nb + i) * 640 + kb + tx] = f2b(tile[tx][i]);
}

//---------------------------------------------------------------------
// MFMA GEMM v10: both operands bf16, B pre-transposed (row = out col).
// 128x128 tile, BK=32, 4 waves (2x2), b128-only staging, reg prefetch.
//---------------------------------------------------------------------
// P[8192,2048] = nf_bf[8192,1024] @ WeT^T
__global__ __launch_bounds__(256)
void gnn10_mm_P(const bf16* __restrict__ A, const bf16* __restrict__ BT,
                bf16* __restrict__ P)
{
  __shared__ short As[128 * 40];
  __shared__ short Bs[128 * 40];
  const int t = threadIdx.x;
  const int col0 = blockIdx.x * 128, row0 = blockIdx.y * 128;
  const int lane = t & 63, w = t >> 6, m16 = lane & 15, q = lane >> 4;
  const int wr = w >> 1, wc = w & 1;

  f32x4 acc[4][4];
#pragma unroll
  for (int mi = 0; mi < 4; ++mi)
#pragma unroll
    for (int ni = 0; ni < 4; ++ni) acc[mi][ni] = (f32x4){0.f, 0.f, 0.f, 0.f};

  const int ar = t >> 1, ah = (t & 1) * 16;
  const bf16* aptr = A + (size_t)(row0 + ar) * 1024 + ah;
  const bf16* bptr = BT + (size_t)(col0 + ar) * 1024 + ah;

  uint4 a0 = *(const uint4*)(aptr);
  uint4 a1 = *(const uint4*)(aptr + 8);
  uint4 b0 = *(const uint4*)(bptr);
  uint4 b1 = *(const uint4*)(bptr + 8);

  for (int k0 = 0; k0 < 1024; k0 += 32) {
    if (k0) __syncthreads();
    *(uint4*)&As[ar * 40 + ah] = a0;
    *(uint4*)&As[ar * 40 + ah + 8] = a1;
    *(uint4*)&Bs[ar * 40 + ah] = b0;
    *(uint4*)&Bs[ar * 40 + ah + 8] = b1;
    __syncthreads();
    if (k0 + 32 < 1024) {
      a0 = *(const uint4*)(aptr + k0 + 32);
      a1 = *(const uint4*)(aptr + k0 + 40);
      b0 = *(const uint4*)(bptr + k0 + 32);
      b1 = *(const uint4*)(bptr + k0 + 40);
    }
    short8 af[4];
#pragma unroll
    for (int mi = 0; mi < 4; ++mi)
      af[mi] = *(const short8*)&As[(wr * 64 + mi * 16 + m16) * 40 + 8 * q];
#pragma unroll
    for (int ni = 0; ni < 4; ++ni) {
      short8 bfv = *(const short8*)&Bs[(wc * 64 + ni * 16 + m16) * 40 + 8 * q];
#pragma unroll
      for (int mi = 0; mi < 4; ++mi)
        acc[mi][ni] =
            __builtin_amdgcn_mfma_f32_16x16x32_bf16(af[mi], bfv, acc[mi][ni], 0, 0, 0);
    }
  }
#pragma unroll
  for (int mi = 0; mi < 4; ++mi)
#pragma unroll
    for (int ni = 0; ni < 4; ++ni) {
      int c = col0 + wc * 64 + ni * 16 + m16;
#pragma unroll
      for (int r = 0; r < 4; ++r)
        P[(size_t)(row0 + wr * 64 + mi * 16 + 4 * q + r) * 2048 + c] =
            f2b(acc[mi][ni][r]);
    }
}

// out0[8192,1024](f32) = relu([nf_bf | zf] @ WnT^T + bn), K=2048
__global__ __launch_bounds__(256)
void gnn10_mm_out_n(const bf16* __restrict__ A0, const bf16* __restrict__ A1,
                    const bf16* __restrict__ BT, const float* __restrict__ bn,
                    float* __restrict__ out)
{
  __shared__ short As[128 * 40];
  __shared__ short Bs[128 * 40];
  const int t = threadIdx.x;
  const int col0 = blockIdx.x * 128, row0 = blockIdx.y * 128;
  const int lane = t & 63, w = t >> 6, m16 = lane & 15, q = lane >> 4;
  const int wr = w >> 1, wc = w & 1;

  f32x4 acc[4][4];
#pragma unroll
  for (int mi = 0; mi < 4; ++mi)
#pragma unroll
    for (int ni = 0; ni < 4; ++ni) acc[mi][ni] = (f32x4){0.f, 0.f, 0.f, 0.f};

  const int ar = t >> 1, ah = (t & 1) * 16;
  const bf16* ap0 = A0 + (size_t)(row0 + ar) * 1024 + ah;
  const bf16* ap1 = A1 + (size_t)(row0 + ar) * 1024 + ah;
  const bf16* bptr = BT + (size_t)(col0 + ar) * 2048 + ah;

  uint4 a0 = *(const uint4*)(ap0);
  uint4 a1 = *(const uint4*)(ap0 + 8);
  uint4 b0 = *(const uint4*)(bptr);
  uint4 b1 = *(const uint4*)(bptr + 8);

  for (int k0 = 0; k0 < 2048; k0 += 32) {
    if (k0) __syncthreads();
    *(uint4*)&As[ar * 40 + ah] = a0;
    *(uint4*)&As[ar * 40 + ah + 8] = a1;
    *(uint4*)&Bs[ar * 40 + ah] = b0;
    *(uint4*)&Bs[ar * 40 + ah + 8] = b1;
    __syncthreads();
    if (k0 + 32 < 2048) {
      int kn = k0 + 32;
      const bf16* ap = (kn < 1024) ? (ap0 + kn) : (ap1 + (kn - 1024));
      a0 = *(const uint4*)(ap);
      a1 = *(const uint4*)(ap + 8);
      b0 = *(const uint4*)(bptr + kn);
      b1 = *(const uint4*)(bptr + kn + 8);
    }
    short8 af[4];
#pragma unroll
    for (int mi = 0; mi < 4; ++mi)
      af[mi] = *(const short8*)&As[(wr * 64 + mi * 16 + m16) * 40 + 8 * q];
#pragma unroll
    for (int ni = 0; ni < 4; ++ni) {
      short8 bfv = *(const short8*)&Bs[(wc * 64 + ni * 16 + m16) * 40 + 8 * q];
#pragma unroll
      for (int mi = 0; mi < 4; ++mi)
        acc[mi][ni] =
            __builtin_amdgcn_mfma_f32_16x16x32_bf16(af[mi], bfv, acc[mi][ni], 0, 0, 0);
    }
  }
#pragma unroll
  for (int mi = 0; mi < 4; ++mi)
#pragma unroll
    for (int ni = 0; ni < 4; ++ni) {
      int c = col0 + wc * 64 + ni * 16 + m16;
      float bias = bn[c];
#pragma unroll
      for (int r = 0; r < 4; ++r) {
        float v = acc[mi][ni][r] + bias;
        out[(size_t)(row0 + wr * 64 + mi * 16 + 4 * q + r) * 1024 + c] =
            fmaxf(v, 0.f);
      }
    }
}

// Q[8192,1280](bf16) = w2v_pad[8192,320] @ WelT^T, K=320
__global__ __launch_bounds__(256)
void gnn10_mm_Q(const bf16* __restrict__ A, const bf16* __restrict__ BT,
                bf16* __restrict__ Q)
{
  __shared__ short As[128 * 40];
  __shared__ short Bs[128 * 40];
  const int t = threadIdx.x;
  const int col0 = blockIdx.x * 128, row0 = blockIdx.y * 128;
  const int lane = t & 63, w = t >> 6, m16 = lane & 15, q = lane >> 4;
  const int wr = w >> 1, wc = w & 1;

  f32x4 acc[4][4];
#pragma unroll
  for (int mi = 0; mi < 4; ++mi)
#pragma unroll
    for (int ni = 0; ni < 4; ++ni) acc[mi][ni] = (f32x4){0.f, 0.f, 0.f, 0.f};

  const int ar = t >> 1, ah = (t & 1) * 16;
  const bf16* aptr = A + (size_t)(row0 + ar) * 320 + ah;
  const bf16* bptr = BT + (size_t)(col0 + ar) * 320 + ah;

  uint4 a0 = *(const uint4*)(aptr);
  uint4 a1 = *(const uint4*)(aptr + 8);
  uint4 b0 = *(const uint4*)(bptr);
  uint4 b1 = *(const uint4*)(bptr + 8);

  for (int k0 = 0; k0 < 320; k0 += 32) {
    if (k0) __syncthreads();
    *(uint4*)&As[ar * 40 + ah] = a0;
    *(uint4*)&As[ar * 40 + ah + 8] = a1;
    *(uint4*)&Bs[ar * 40 + ah] = b0;
    *(uint4*)&Bs[ar * 40 + ah + 8] = b1;
    __syncthreads();
    if (k0 + 32 < 320) {
      a0 = *(const uint4*)(aptr + k0 + 32);
      a1 = *(const uint4*)(aptr + k0 + 40);
      b0 = *(const uint4*)(bptr + k0 + 32);
      b1 = *(const uint4*)(bptr + k0 + 40);
    }
    short8 af[4];
#pragma unroll
    for (int mi = 0; mi < 4; ++mi)
      af[mi] = *(const short8*)&As[(wr * 64 + mi * 16 + m16) * 40 + 8 * q];
#pragma unroll
    for (int ni = 0; ni < 4; ++ni) {
      short8 bfv = *(const short8*)&Bs[(wc * 64 + ni * 16 + m16) * 40 + 8 * q];
#pragma unroll
      for (int mi = 0; mi < 4; ++mi)
        acc[mi][ni] =
            __builtin_amdgcn_mfma_f32_16x16x32_bf16(af[mi], bfv, acc[mi][ni], 0, 0, 0);
    }
  }
#pragma unroll
  for (int mi = 0; mi < 4; ++mi)
#pragma unroll
    for (int ni = 0; ni < 4; ++ni) {
      int c = col0 + wc * 64 + ni * 16 + m16;
#pragma unroll
      for (int r = 0; r < 4; ++r)
        Q[(size_t)(row0 + wr * 64 + mi * 16 + 4 * q + r) * 1280 + c] =
            f2b(acc[mi][ni][r]);
    }
}

// out1[8192,300](f32) = relu([w2v_pad | zfl_pad] @ WnlT^T + bnl), K=640
__global__ __launch_bounds__(256)
void gnn10_mm_out_l(const bf16* __restrict__ A0, const bf16* __restrict__ A1,
                    const bf16* __restrict__ BT, const float* __restrict__ bnl,
                    float* __restrict__ out2)
{
  __shared__ short As[128 * 40];
  __shared__ short Bs[128 * 40];
  const int t = threadIdx.x;
  const int col0 = blockIdx.x * 128, row0 = blockIdx.y * 128;
  const int lane = t & 63, w = t >> 6, m16 = lane & 15, q = lane >> 4;
  const int wr = w >> 1, wc = w & 1;

  f32x4 acc[4][4];
#pragma unroll
  for (int mi = 0; mi < 4; ++mi)
#pragma unroll
    for (int ni = 0; ni < 4; ++ni) acc[mi][ni] = (f32x4){0.f, 0.f, 0.f, 0.f};

  const int ar = t >> 1, ah = (t & 1) * 16;
  const bf16* ap0 = A0 + (size_t)(row0 + ar) * 320 + ah;
  const bf16* ap1 = A1 + (size_t)(row0 + ar) * 320 + ah;
  const bf16* bptr = BT + (size_t)(col0 + ar) * 640 + ah;

  uint4 a0 = *(const uint4*)(ap0);
  uint4 a1 = *(const uint4*)(ap0 + 8);
  uint4 b0 = *(const uint4*)(bptr);
  uint4 b1 = *(const uint4*)(bptr + 8);

  for (int k0 = 0; k0 < 640; k0 += 32) {
    if (k0) __syncthreads();
    *(uint4*)&As[ar * 40 + ah] = a0;
    *(uint4*)&As[ar * 40 + ah + 8] = a1;
    *(uint4*)&Bs[ar * 40 + ah] = b0;
    *(uint4*)&Bs[ar * 40 + ah + 8] = b1;
    __syncthreads();
    if (k0 + 32 < 640) {
      int kn = k0 + 32;
      const bf16* ap = (kn < 320) ? (ap0 + kn) : (ap1 + (kn - 320));
      a0 = *(const uint4*)(ap);
      a1 = *(const uint4*)(ap + 8);
      b0 = *(const uint4*)(bptr + kn);
      b1 = *(const uint4*)(bptr + kn + 8);
    }
    short8 af[4];
#pragma unroll
    for (int mi = 0; mi < 4; ++mi)
      af[mi] = *(const short8*)&As[(wr * 64 + mi * 16 + m16) * 40 + 8 * q];
#pragma unroll
    for (int ni = 0; ni < 4; ++ni) {
      short8 bfv = *(const short8*)&Bs[(wc * 64 + ni * 16 + m16) * 40 + 8 * q];
#pragma unroll
      for (int mi = 0; mi < 4; ++mi)
        acc[mi][ni] =
            __builtin_amdgcn_mfma_f32_16x16x32_bf16(af[mi], bfv, acc[mi][ni], 0, 0, 0);
    }
  }
#pragma unroll
  for (int mi = 0; mi < 4; ++mi)
#pragma unroll
    for (int ni = 0; ni < 4; ++ni) {
      int c = col0 + wc * 64 + ni * 16 + m16;
      if (c < 300) {
        float bias = bnl[c];
#pragma unroll
        for (int r = 0; r < 4; ++r) {
          float v = acc[mi][ni][r] + bias;
          out2[(size_t)(row0 + wr * 64 + mi * 16 + 4 * q + r) * 300 + c] =
              fmaxf(v, 0.f);
        }
      }
    }
}

//---------------------------------------------------------------------
// Edge scores: thread t owns CONTIGUOUS cols 4t..4t+3 (proven R9).
//---------------------------------------------------------------------
__global__ __launch_bounds__(256)
void gnn9_edge_score(const int* __restrict__ src, const int* __restrict__ dst,
                     const float* __restrict__ s_f, const float* __restrict__ We,
                     const float* __restrict__ be, const float* __restrict__ Wa,
                     const float* __restrict__ ba, const float* __restrict__ bel,
                     const float* __restrict__ Wal, const float* __restrict__ bal,
                     const bf16* __restrict__ P, const bf16* __restrict__ Q,
                     float* __restrict__ af, float* __restrict__ afl)
{
  const int t = threadIdx.x;
  const int lane = t & 63, w = t >> 6;
  const int c0 = 4 * t;
  const int e0 = blockIdx.x * 8;

  float wef[16][4];
#pragma unroll
  for (int k = 0; k < 16; ++k) {
    float4 v = *(const float4*)(We + (size_t)(1024 + k) * 1024 + c0);
    wef[k][0] = v.x; wef[k][1] = v.y; wef[k][2] = v.z; wef[k][3] = v.w;
  }
  float4 bev = *(const float4*)(be + c0);
  float4 wav = *(const float4*)(Wa + c0);
  const bool lact = (t < 150);
  float4 belv = {0, 0, 0, 0}, walv = {0, 0, 0, 0};
  if (lact) { belv = *(const float4*)(bel + c0); walv = *(const float4*)(Wal + c0); }
  const float ba0 = ba[0], bal0 = bal[0];

  __shared__ float shf[4], shl[4];

  for (int i = 0; i < 8; ++i) {
    const int e = e0 + i;
    const int s = src[e], d = dst[e];

    float sfv[16];
    {
      const float4* sp = (const float4*)(s_f + (size_t)e * 16);
      float4 s0 = sp[0], s1 = sp[1], s2 = sp[2], s3 = sp[3];
      sfv[0] = s0.x; sfv[1] = s0.y; sfv[2] = s0.z; sfv[3] = s0.w;
      sfv[4] = s1.x; sfv[5] = s1.y; sfv[6] = s1.z; sfv[7] = s1.w;
      sfv[8] = s2.x; sfv[9] = s2.y; sfv[10] = s2.z; sfv[11] = s2.w;
      sfv[12] = s3.x; sfv[13] = s3.y; sfv[14] = s3.z; sfv[15] = s3.w;
    }

    float4 p1 = ld4b(P + (size_t)s * 2048 + c0);
    float4 p2 = ld4b(P + (size_t)d * 2048 + 1024 + c0);
    float pv[4] = {p1.x + p2.x + bev.x, p1.y + p2.y + bev.y,
                   p1.z + p2.z + bev.z, p1.w + p2.w + bev.w};
    float pf = 0.f;
#pragma unroll
    for (int j = 0; j < 4; ++j) {
      float v = pv[j];
#pragma unroll
      for (int k = 0; k < 16; ++k) v = fmaf(sfv[k], wef[k][j], v);
      pf = fmaf(fmaxf(v, 0.f), (&wav.x)[j], pf);
    }

    float pl = 0.f;
    if (lact) {
      float4 q1 = ld4b(Q + (size_t)s * 1280 + c0);
      float4 q2 = ld4b(Q + (size_t)d * 1280 + 600 + c0);
      float qv[4] = {q1.x + q2.x + belv.x, q1.y + q2.y + belv.y,
                     q1.z + q2.z + belv.z, q1.w + q2.w + belv.w};
#pragma unroll
      for (int j = 0; j < 4; ++j)
        pl = fmaf(fmaxf(qv[j], 0.f), (&walv.x)[j], pl);
    }

#pragma unroll
    for (int o = 32; o > 0; o >>= 1) {
      pf += __shfl_down(pf, o, 64);
      pl += __shfl_down(pl, o, 64);
    }
    if (lane == 0) { shf[w] = pf; shl[w] = pl; }
    __syncthreads();
    if (t == 0)  af[e]  = shf[0] + shf[1] + shf[2] + shf[3] + ba0;
    if (t == 64) afl[e] = shl[0] + shl[1] + shl[2] + shl[3] + bal0;
    __syncthreads();
  }
}

//---------------------------------------------------------------------
// CSR build
//---------------------------------------------------------------------
__global__ void gnn6_count(const int* __restrict__ dst, int* __restrict__ cnt)
{
  int e = blockIdx.x * blockDim.x + threadIdx.x;
  if (e < N_EDGES) atomicAdd(&cnt[dst[e]], 1);
}

__global__ __launch_bounds__(1024)
void gnn6_scan(const int* __restrict__ cnt, int* __restrict__ off, int* __restrict__ cur)
{
  __shared__ int sh[1024];
  const int t = threadIdx.x;
  int local[8]; int sum = 0;
#pragma unroll
  for (int i = 0; i < 8; ++i) { int v = cnt[t * 8 + i]; local[i] = sum; sum += v; }
  sh[t] = sum;
  __syncthreads();
  for (int d = 1; d < 1024; d <<= 1) {
    int v = (t >= d) ? sh[t - d] : 0;
    __syncthreads();
    sh[t] += v;
    __syncthreads();
  }
  int basev = (t > 0) ? sh[t - 1] : 0;
#pragma unroll
  for (int i = 0; i < 8; ++i) { int o = basev + local[i]; off[t * 8 + i] = o; cur[t * 8 + i] = o; }
  if (t == 1023) off[8192] = sh[1023];
}

__global__ void gnn6_fill(const int* __restrict__ dst, int* __restrict__ cur,
                          int* __restrict__ elist)
{
  int e = blockIdx.x * blockDim.x + threadIdx.x;
  if (e < N_EDGES) { int p = atomicAdd(&cur[dst[e]], 1); elist[p] = e; }
}

//---------------------------------------------------------------------
// Per-node softmax -> alpha written in place into af/afl.
//---------------------------------------------------------------------
__global__ __launch_bounds__(256)
void gnn6_alpha(const int* __restrict__ off, const int* __restrict__ elist,
                float* __restrict__ af, float* __restrict__ afl)
{
  const int n = blockIdx.x * 256 + threadIdx.x;
  if (n >= N_NODES) return;
  const int base = off[n];
  const int deg = off[n + 1] - base;
  float m = -1e30f, ml = -1e30f;
  for (int i = 0; i < deg; ++i) {
    int e = elist[base + i];
    m = fmaxf(m, af[e]);
    ml = fmaxf(ml, afl[e]);
  }
  float den = 0.f, denl = 0.f;
  for (int i = 0; i < deg; ++i) {
    int e = elist[base + i];
    den += expf(af[e] - m);
    denl += expf(afl[e] - ml);
  }
  float inv = (den > 0.f) ? 1.f / den : 0.f;
  float invl = (denl > 0.f) ? 1.f / denl : 0.f;
  for (int i = 0; i < deg; ++i) {
    int e = elist[base + i];
    af[e] = expf(af[e] - m) * inv;
    afl[e] = expf(afl[e] - ml) * invl;
  }
}

//---------------------------------------------------------------------
// node_z: thread t owns CONTIGUOUS cols 4t..4t+3 (proven R9).
//---------------------------------------------------------------------
__global__ __launch_bounds__(256)
void gnn9_node_z(const int* __restrict__ off, const int* __restrict__ elist,
                 const int* __restrict__ src, const float* __restrict__ af,
                 const float* __restrict__ afl, const bf16* __restrict__ nf_bf,
                 const bf16* __restrict__ w2v_pad, const float* __restrict__ s_f,
                 const float* __restrict__ We, const float* __restrict__ be,
                 const bf16* __restrict__ P, bf16* __restrict__ zf,
                 bf16* __restrict__ zfl_pad)
{
  const int node = blockIdx.x;
  const int t = threadIdx.x;
  const int c0 = 4 * t;
  const int base = off[node];
  const int deg = off[node + 1] - base;

  float wef[16][4];
#pragma unroll
  for (int k = 0; k < 16; ++k) {
    float4 v = *(const float4*)(We + (size_t)(1024 + k) * 1024 + c0);
    wef[k][0] = v.x; wef[k][1] = v.y; wef[k][2] = v.z; wef[k][3] = v.w;
  }
  float4 p2v = ld4b(P + (size_t)node * 2048 + 1024 + c0);
  float4 bev = *(const float4*)(be + c0);
  const float p2[4] = {p2v.x + bev.x, p2v.y + bev.y, p2v.z + bev.z, p2v.w + bev.w};

  float acc[4] = {0.f, 0.f, 0.f, 0.f};
  float accl[4] = {0.f, 0.f, 0.f, 0.f};
  const bool lact = (t < 75);

  for (int i = 0; i < deg; ++i) {
    const int e = elist[base + i];
    const int s = src[e];
    const float wgt = af[e];
    const float wl = afl[e];

    float sfv[16];
    {
      const float4* sp = (const float4*)(s_f + (size_t)e * 16);
      float4 s0 = sp[0], s1 = sp[1], s2 = sp[2], s3 = sp[3];
      sfv[0] = s0.x; sfv[1] = s0.y; sfv[2] = s0.z; sfv[3] = s0.w;
      sfv[4] = s1.x; sfv[5] = s1.y; sfv[6] = s1.z; sfv[7] = s1.w;
      sfv[8] = s2.x; sfv[9] = s2.y; sfv[10] = s2.z; sfv[11] = s2.w;
      sfv[12] = s3.x; sfv[13] = s3.y; sfv[14] = s3.z; sfv[15] = s3.w;
    }

    float4 p1 = ld4b(P + (size_t)s * 2048 + c0);
    float4 nf4 = ld4b(nf_bf + (size_t)s * 1024 + c0);
    const float p1a[4] = {p1.x, p1.y, p1.z, p1.w};
    const float nfa[4] = {nf4.x, nf4.y, nf4.z, nf4.w};
#pragma unroll
    for (int j = 0; j < 4; ++j) {
      float ef = p1a[j] + p2[j];
#pragma unroll
      for (int k = 0; k < 16; ++k) ef = fmaf(sfv[k], wef[k][j], ef);
      ef = fmaxf(ef, 0.f);
      acc[j] = fmaf(wgt, nfa[j] + ef, acc[j]);
    }
    if (lact) {
      float4 wv = ld4b(w2v_pad + (size_t)s * 320 + c0);
      accl[0] = fmaf(wl, wv.x, accl[0]);
      accl[1] = fmaf(wl, wv.y, accl[1]);
      accl[2] = fmaf(wl, wv.z, accl[2]);
      accl[3] = fmaf(wl, wv.w, accl[3]);
    }
  }
  st4b(zf + (size_t)node * 1024 + c0, acc[0], acc[1], acc[2], acc[3]);
  if (lact)
    st4b(zfl_pad + (size_t)node * 320 + c0, accl[0], accl[1], accl[2], accl[3]);
  else if (t < 80)
    st4b(zfl_pad + (size_t)node * 320 + c0, 0.f, 0.f, 0.f, 0.f);
}

//=====================================================================
extern "C" void kernel_launch(void* const* d_in, const int* in_sizes, int n_in,
                              void* d_out, int out_size, void* d_ws, size_t ws_size,
                              hipStream_t stream)
{
  (void)hipGetLastError();
  if (n_in != 17) { hipMemsetAsync(d_out, 0x41, 4096, stream); return; }

  const float* n_f = (const float*)d_in[0];
  const float* w2v = (const float*)d_in[1];
  const float* s_f = (const float*)d_in[2];
  const int*   src = (const int*)d_in[3];
  const int*   dst = (const int*)d_in[4];
  const float* We  = (const float*)d_in[5];
  const float* be  = (const float*)d_in[6];
  const float* Wel = (const float*)d_in[7];
  const float* bel = (const float*)d_in[8];
  const float* Wa  = (const float*)d_in[9];
  const float* ba  = (const float*)d_in[10];
  const float* Wal = (const float*)d_in[11];
  const float* bal = (const float*)d_in[12];
  const float* Wn  = (const float*)d_in[13];
  const float* bn  = (const float*)d_in[14];
  const float* Wnl = (const float*)d_in[15];
  const float* bnl = (const float*)d_in[16];
  float* out  = (float*)d_out;
  float* out2 = out + OUT0_ELEMS;

  char* ws = (char*)d_ws;
  size_t o = 0;
  auto alloc = [&](size_t bytes) -> void* {
    void* p = ws + o; o += bytes; o = (o + 255) & ~(size_t)255; return p;
  };
  bf16* P        = (bf16*)alloc((size_t)N_NODES * 2048 * 2);
  bf16* Q        = (bf16*)alloc((size_t)N_NODES * 1280 * 2);
  bf16* zf       = (bf16*)alloc((size_t)N_NODES * 1024 * 2);
  bf16* zfl_pad  = (bf16*)alloc((size_t)N_NODES * 320 * 2);
  bf16* nf_bf    = (bf16*)alloc((size_t)N_NODES * 1024 * 2);
  bf16* w2v_pad  = (bf16*)alloc((size_t)N_NODES * 320 * 2);
  bf16* WeT      = (bf16*)alloc((size_t)2048 * 1024 * 2);
  bf16* WnT      = (bf16*)alloc((size_t)1024 * 2048 * 2);
  bf16* WelT     = (bf16*)alloc((size_t)1280 * 320 * 2);
  bf16* WnlT     = (bf16*)alloc((size_t)384 * 640 * 2);
  float* af      = (float*)alloc((size_t)N_EDGES * 4);
  float* afl     = (float*)alloc((size_t)N_EDGES * 4);
  int* cnt       = (int*)alloc((size_t)N_NODES * 4);
  int* offs      = (int*)alloc((size_t)(N_NODES + 1) * 4);
  int* cur       = (int*)alloc((size_t)N_NODES * 4);
  int* elist     = (int*)alloc((size_t)N_EDGES * 4);
  if (o > ws_size) { hipMemsetAsync(d_out, 0x42, 4096, stream); return; }

  gnn6_zero<<<N_NODES / 256, 256, 0, stream>>>(cnt, N_NODES);
  gnn7_cvt<<<(N_NODES * 1024 / 8 + 255) / 256, 256, 0, stream>>>(n_f, nf_bf,
                                                                 N_NODES * 1024 / 8);
  gnn8_pad_w2v<<<(N_NODES * 80 + 255) / 256, 256, 0, stream>>>(w2v, w2v_pad);
  { dim3 g(32, 64); gnn10_t_We<<<g, 256, 0, stream>>>(We, WeT); }
  { dim3 g(64, 32); gnn10_t_Wn<<<g, 256, 0, stream>>>(Wn, WnT); }
  { dim3 g(10, 40); gnn10_t_Wel<<<g, 256, 0, stream>>>(Wel, WelT); }
  { dim3 g(20, 12); gnn10_t_Wnl<<<g, 256, 0, stream>>>(Wnl, WnlT); }

  {
    dim3 g(2048 / 128, N_NODES / 128);
    gnn10_mm_P<<<g, 256, 0, stream>>>(nf_bf, WeT, P);
  }
  {
    dim3 g(1280 / 128, N_NODES / 128);
    gnn10_mm_Q<<<g, 256, 0, stream>>>(w2v_pad, WelT, Q);
  }

  gnn9_edge_score<<<N_EDGES / 8, 256, 0, stream>>>(src, dst, s_f, We, be, Wa, ba,
                                                   bel, Wal, bal, P, Q, af, afl);

  gnn6_count<<<N_EDGES / 256, 256, 0, stream>>>(dst, cnt);
  gnn6_scan<<<1, 1024, 0, stream>>>(cnt, offs, cur);
  gnn6_fill<<<N_EDGES / 256, 256, 0, stream>>>(dst, cur, elist);
  gnn6_alpha<<<N_NODES / 256, 256, 0, stream>>>(offs, elist, af, afl);

  gnn9_node_z<<<N_NODES, 256, 0, stream>>>(offs, elist, src, af, afl, nf_bf,
                                           w2v_pad, s_f, We, be, P, zf, zfl_pad);

  {
    dim3 g(1024 / 128, N_NODES / 128);
    gnn10_mm_out_n<<<g, 256, 0, stream>>>(nf_bf, zf, WnT, bn, out);
  }
  {
    dim3 g(384 / 128, N_NODES / 128);
    gnn10_mm_out_l<<<g, 256, 0, stream>>>(w2v_pad, zfl_pad, WnlT, bnl, out2);
  }

  if (hipGetLastError() != hipSuccess) hipMemsetAsync(d_out, 0x44, 4096, stream);
}